// Round 18
// baseline (791.665 us; speedup 1.0000x reference)
//
#include <hip/hip_runtime.h>
#include <cstdint>
#include <cstddef>

#define BN_EPS 1e-5f
#define K1CAP 1024
#define KPCAP 512

typedef short short8 __attribute__((ext_vector_type(8)));
typedef float f32x4 __attribute__((ext_vector_type(4)));
typedef unsigned long long ull;

// ---------------- helpers ----------------
__device__ __forceinline__ unsigned int ordf(float d) {
  unsigned int u = __float_as_uint(d);
  return (u >> 31) ? ~u : (u | 0x80000000u);
}
__device__ __forceinline__ unsigned short f2bf(float f) {
  unsigned u = __float_as_uint(f);
  u += 0x7fffu + ((u >> 16) & 1u);
  return (unsigned short)(u >> 16);
}
__device__ __forceinline__ float bf2f(unsigned short h) {
  return __uint_as_float(((unsigned)h) << 16);
}

// ---------------- MFMA bf16x3 GEMM (K_STEP=64, reg-staged pipeline) ----------------
// flags: 1=ACC, 2=RELU, 8=stats epilogue (slotted), 16=maxmin epilogue (NO C
// write), 32=EDGE1-A (v=relu(A[i][k]+src[j][k])), 64=BF16OUT (write Ch/Cl),
// 128=TILEMIN (knn keys: per-row min over tile cols -> u32 C[gr*ldc+blockIdx.y];
//   key = ordf(src[gr]+src[gc]-2v), diag -> ~0u),
// 256=KEYPUSH (push (key,gc) with key<=Trow[gr] into per-row buf; Trow=gidx,
//   cnt=mxp, buf=mnp).
// A-source priority: A8h/A8l (bf16 hi/lo [M][lda]) -> flags&32 -> fp32 A [M][lda]
// (+optional bnA affine: bnA[k]*v + bnA[1024+k]). W: bf16 hi/lo n-major
// [N][ldk], k index = koff+k. Requires M%64==0, N%64==0, K%64==0.
#define BPAD 72

__global__ __launch_bounds__(256)
void mk_gemm_mfma(const float* __restrict__ A,
                  const short* __restrict__ A8h, const short* __restrict__ A8l,
                  const float* __restrict__ src, const int* __restrict__ gidx, int srcC,
                  const float* __restrict__ bnA,
                  const short* __restrict__ Wh, const short* __restrict__ Wl,
                  int ldk, int koff, int lda,
                  const float* __restrict__ bias,
                  float* __restrict__ C, short* __restrict__ Ch, short* __restrict__ Cl,
                  int ldc,
                  int M, int N, int K, int flags,
                  float* __restrict__ statsP,
                  float* __restrict__ mxp, float* __restrict__ mnp) {
  __shared__ short Ah[64][BPAD], Al[64][BPAD], Bh[64][BPAD], Bl[64][BPAD];
  __shared__ float ssum[64], ssq[64];
  int tid = threadIdx.x, lane = tid & 63, wid = tid >> 6;
  int wr = wid >> 1, wc = wid & 1;
  int r0 = blockIdx.x * 64, n0 = blockIdx.y * 64;
  int sr = tid >> 2, sc = (tid & 3) * 16;
  f32x4 zero4 = {0.f, 0.f, 0.f, 0.f};
  f32x4 acc[2][2] = {{zero4, zero4}, {zero4, zero4}};
  short8 rAh[2], rAl[2], rBh[2], rBl[2];

  auto stage = [&](int kt) {
    const short* bh = &Wh[(size_t)(n0 + sr) * ldk + koff + kt + sc];
    const short* bl = &Wl[(size_t)(n0 + sr) * ldk + koff + kt + sc];
    rBh[0] = *(const short8*)bh; rBh[1] = *(const short8*)(bh + 8);
    rBl[0] = *(const short8*)bl; rBl[1] = *(const short8*)(bl + 8);
    if (A8h) {
      const short* ah = &A8h[(size_t)(r0 + sr) * lda + kt + sc];
      const short* al = &A8l[(size_t)(r0 + sr) * lda + kt + sc];
      rAh[0] = *(const short8*)ah; rAh[1] = *(const short8*)(ah + 8);
      rAl[0] = *(const short8*)al; rAl[1] = *(const short8*)(al + 8);
    } else {
      float v[16];
      if (flags & 32) {
        int gr = r0 + sr;
        int i = gr >> 5; int j = gidx[gr];
        const float* pi = &A[(size_t)i * srcC + kt + sc];
        const float* pj = &src[(size_t)j * srcC + kt + sc];
        float va[16], vb[16];
        *(float4*)&va[0]  = *(const float4*)&pi[0];
        *(float4*)&va[4]  = *(const float4*)&pi[4];
        *(float4*)&va[8]  = *(const float4*)&pi[8];
        *(float4*)&va[12] = *(const float4*)&pi[12];
        *(float4*)&vb[0]  = *(const float4*)&pj[0];
        *(float4*)&vb[4]  = *(const float4*)&pj[4];
        *(float4*)&vb[8]  = *(const float4*)&pj[8];
        *(float4*)&vb[12] = *(const float4*)&pj[12];
#pragma unroll
        for (int e = 0; e < 16; ++e) v[e] = fmaxf(va[e] + vb[e], 0.f);
      } else {
        const float* ap = &A[(size_t)(r0 + sr) * lda + kt + sc];
        *(float4*)&v[0]  = *(const float4*)&ap[0];
        *(float4*)&v[4]  = *(const float4*)&ap[4];
        *(float4*)&v[8]  = *(const float4*)&ap[8];
        *(float4*)&v[12] = *(const float4*)&ap[12];
      }
      if (bnA) {
#pragma unroll
        for (int e = 0; e < 16; ++e) {
          int gk = kt + sc + e;
          v[e] = fmaf(bnA[gk], v[e], bnA[1024 + gk]);
        }
      }
#pragma unroll
      for (int e = 0; e < 16; ++e) {
        unsigned short h = f2bf(v[e]);
        rAh[e >> 3][e & 7] = (short)h;
        rAl[e >> 3][e & 7] = (short)f2bf(v[e] - bf2f(h));
      }
    }
  };

  stage(0);
  for (int kt = 0; kt < K; kt += 64) {
    *(short8*)&Ah[sr][sc]     = rAh[0];
    *(short8*)&Ah[sr][sc + 8] = rAh[1];
    *(short8*)&Al[sr][sc]     = rAl[0];
    *(short8*)&Al[sr][sc + 8] = rAl[1];
    *(short8*)&Bh[sr][sc]     = rBh[0];
    *(short8*)&Bh[sr][sc + 8] = rBh[1];
    *(short8*)&Bl[sr][sc]     = rBl[0];
    *(short8*)&Bl[sr][sc + 8] = rBl[1];
    __syncthreads();
    if (kt + 64 < K) stage(kt + 64);
    int ar = wr * 32 + (lane & 15);
    int br = wc * 32 + (lane & 15);
#pragma unroll
    for (int kk = 0; kk < 2; ++kk) {
      int kof = kk * 32 + (lane >> 4) * 8;
      short8 a_h[2], a_l[2], b_h[2], b_l[2];
#pragma unroll
      for (int t = 0; t < 2; ++t) {
        a_h[t] = *(const short8*)&Ah[ar + t * 16][kof];
        a_l[t] = *(const short8*)&Al[ar + t * 16][kof];
        b_h[t] = *(const short8*)&Bh[br + t * 16][kof];
        b_l[t] = *(const short8*)&Bl[br + t * 16][kof];
      }
#pragma unroll
      for (int mt = 0; mt < 2; ++mt)
#pragma unroll
        for (int nt = 0; nt < 2; ++nt) {
          acc[mt][nt] = __builtin_amdgcn_mfma_f32_16x16x32_bf16(a_h[mt], b_h[nt], acc[mt][nt], 0, 0, 0);
          acc[mt][nt] = __builtin_amdgcn_mfma_f32_16x16x32_bf16(a_h[mt], b_l[nt], acc[mt][nt], 0, 0, 0);
          acc[mt][nt] = __builtin_amdgcn_mfma_f32_16x16x32_bf16(a_l[mt], b_h[nt], acc[mt][nt], 0, 0, 0);
        }
    }
    __syncthreads();
  }

  // ---- TILEMIN epilogue (flag 128): per-row min key over this tile ----
  if (flags & 128) {
    unsigned* tm = (unsigned*)ssum;
    if (tid < 64) tm[tid] = 0xFFFFFFFFu;
    __syncthreads();
#pragma unroll
    for (int mt = 0; mt < 2; ++mt)
#pragma unroll
      for (int i = 0; i < 4; ++i) {
        int lr = wr * 32 + mt * 16 + (lane >> 4) * 4 + i;
        int gr = r0 + lr;
        unsigned kmin = 0xFFFFFFFFu;
#pragma unroll
        for (int nt = 0; nt < 2; ++nt) {
          int gc = n0 + wc * 32 + nt * 16 + (lane & 15);
          float v = acc[mt][nt][i];
          unsigned kk2 = (gr == gc) ? 0xFFFFFFFFu : ordf(src[gr] + src[gc] - 2.f * v);
          kmin = kmin < kk2 ? kmin : kk2;
        }
#pragma unroll
        for (int off = 1; off < 16; off <<= 1) {
          unsigned o = (unsigned)__shfl_xor((int)kmin, off, 64);
          kmin = kmin < o ? kmin : o;
        }
        if ((lane & 15) == 0) atomicMin(&tm[lr], kmin);
      }
    __syncthreads();
    if (tid < 64)
      ((unsigned*)C)[(size_t)(r0 + tid) * ldc + blockIdx.y] = tm[tid];
    return;
  }
  // ---- KEYPUSH epilogue (flag 256): push survivors key<=Trow[gr] ----
  if (flags & 256) {
    const unsigned* Trow = (const unsigned*)gidx;
    unsigned* cntp = (unsigned*)mxp;
    ull* bufp = (ull*)mnp;
#pragma unroll
    for (int mt = 0; mt < 2; ++mt)
#pragma unroll
      for (int nt = 0; nt < 2; ++nt)
#pragma unroll
        for (int i = 0; i < 4; ++i) {
          int gr = r0 + wr * 32 + mt * 16 + (lane >> 4) * 4 + i;
          int gc = n0 + wc * 32 + nt * 16 + (lane & 15);
          float v = acc[mt][nt][i];
          unsigned kk2 = (gr == gc) ? 0xFFFFFFFFu : ordf(src[gr] + src[gc] - 2.f * v);
          if (kk2 <= Trow[gr]) {
            unsigned s = atomicAdd(&cntp[gr], 1u);
            if (s < (unsigned)KPCAP)
              bufp[(size_t)gr * KPCAP + s] = (((ull)kk2) << 32) | (unsigned)gc;
          }
        }
    return;
  }

  bool dostat = (flags & 8) != 0, domx = (flags & 16) != 0;
  float lsum[2] = {0.f, 0.f}, lsq[2] = {0.f, 0.f};
  float lmx[2] = {-3.4e38f, -3.4e38f}, lmn[2] = {3.4e38f, 3.4e38f};
#pragma unroll
  for (int nt = 0; nt < 2; ++nt) {
    int gc = n0 + wc * 32 + nt * 16 + (lane & 15);
#pragma unroll
    for (int mt = 0; mt < 2; ++mt)
#pragma unroll
      for (int i = 0; i < 4; ++i) {
        int gr = r0 + wr * 32 + mt * 16 + (lane >> 4) * 4 + i;
        float v = acc[mt][nt][i];
        if (bias) v += bias[gc];
        if (flags & 1) v += C[(size_t)gr * ldc + gc];
        if (flags & 2) v = fmaxf(v, 0.f);
        if (!domx) {
          if (flags & 64) {
            unsigned short hh = f2bf(v);
            Ch[(size_t)gr * ldc + gc] = (short)hh;
            Cl[(size_t)gr * ldc + gc] = (short)f2bf(v - bf2f(hh));
          } else {
            C[(size_t)gr * ldc + gc] = v;
          }
        }
        lsum[nt] += v; lsq[nt] = fmaf(v, v, lsq[nt]);
        lmx[nt] = fmaxf(lmx[nt], v); lmn[nt] = fminf(lmn[nt], v);
      }
  }
  if (dostat || domx) {
#pragma unroll
    for (int nt = 0; nt < 2; ++nt) {
#pragma unroll
      for (int m = 16; m <= 32; m <<= 1) {
        lsum[nt] += __shfl_xor(lsum[nt], m, 64);
        lsq[nt] += __shfl_xor(lsq[nt], m, 64);
        lmx[nt] = fmaxf(lmx[nt], __shfl_xor(lmx[nt], m, 64));
        lmn[nt] = fminf(lmn[nt], __shfl_xor(lmn[nt], m, 64));
      }
    }
    if (domx && lane < 16) {
      int node = blockIdx.x * 2 + wr;
#pragma unroll
      for (int nt = 0; nt < 2; ++nt) {
        int gc = n0 + wc * 32 + nt * 16 + lane;
        mxp[(size_t)node * N + gc] = lmx[nt];
        mnp[(size_t)node * N + gc] = lmn[nt];
      }
    }
    if (dostat) {
      if (tid < 64) { ssum[tid] = 0.f; ssq[tid] = 0.f; }
      __syncthreads();
      if (lane < 16) {
#pragma unroll
        for (int nt = 0; nt < 2; ++nt) {
          int ct = wc * 32 + nt * 16 + lane;
          atomicAdd(&ssum[ct], lsum[nt]);
          atomicAdd(&ssq[ct], lsq[nt]);
        }
      }
      __syncthreads();
      if (tid < 64) {
        int slot = blockIdx.x & 63;
        int gc = n0 + tid;
        atomicAdd(&statsP[(size_t)slot * 1024 + gc], ssum[tid]);
        atomicAdd(&statsP[(size_t)slot * 1024 + 512 + gc], ssq[tid]);
      }
    }
  }
}

// ---------------- weight conversion ----------------
__global__ void mk_wcvt(const float* __restrict__ W, short* __restrict__ Wh,
                        short* __restrict__ Wl, int K, int N) {
  int g = blockIdx.x * 256 + threadIdx.x;
  if (g >= K * N) return;
  int k = g / N, n = g - k * N;
  float v = W[g];
  unsigned short h = f2bf(v);
  Wh[(size_t)n * K + k] = (short)h;
  Wl[(size_t)n * K + k] = (short)f2bf(v - bf2f(h));
}
__global__ void mk_wcvts(const float* __restrict__ W, const float* __restrict__ a,
                         short* __restrict__ Wh, short* __restrict__ Wl, int K, int N) {
  int g = blockIdx.x * 256 + threadIdx.x;
  if (g >= K * N) return;
  int k = g / N, n = g - k * N;
  float v = a[k] * W[g];
  unsigned short h = f2bf(v);
  Wh[(size_t)n * K + k] = (short)h;
  Wl[(size_t)n * K + k] = (short)f2bf(v - bf2f(h));
}
__global__ void mk_biasfold(const float* __restrict__ W, const float* __restrict__ bv,
                            const float* __restrict__ b0, float* __restrict__ bo,
                            int K, int N) {
  int col = blockIdx.x * 4 + (threadIdx.x >> 6);
  int lane = threadIdx.x & 63;
  if (col >= N) return;
  float s = 0.f;
  for (int k = lane; k < K; k += 64) s = fmaf(bv[k], W[(size_t)k * N + col], s);
#pragma unroll
  for (int off = 32; off; off >>= 1) s += __shfl_xor(s, off, 64);
  if (lane == 0) bo[col] = b0[col] + s;
}
__global__ void mk_wcvt2(const float* __restrict__ W, short* __restrict__ Dh,
                         short* __restrict__ Dl, short* __restrict__ Vh,
                         short* __restrict__ Vl) {
  int g = blockIdx.x * 256 + threadIdx.x;
  if (g >= 64 * 128) return;
  int k = g >> 7, n = g & 127;
  float u = W[k * 128 + n], vv = W[(64 + k) * 128 + n];
  float d = u - vv;
  unsigned short h = f2bf(d);
  Dh[n * 64 + k] = (short)h; Dl[n * 64 + k] = (short)f2bf(d - bf2f(h));
  h = f2bf(vv);
  Vh[n * 64 + k] = (short)h; Vl[n * 64 + k] = (short)f2bf(vv - bf2f(h));
}

// ---------------- conv1 node tables ----------------
__global__ void mk_conv1nodes(const float* __restrict__ pos, const float* __restrict__ W1,
                              const float* __restrict__ b1, float* __restrict__ Pp,
                              float* __restrict__ Qn) {
  int g = blockIdx.x * 256 + threadIdx.x;
  if (g >= 8192 * 64) return;
  int i = g >> 6, c = g & 63;
  float p0 = pos[i * 3], p1 = pos[i * 3 + 1], p2 = pos[i * 3 + 2];
  float q = p0 * W1[192 + c] + p1 * W1[256 + c] + p2 * W1[320 + c];
  Qn[g] = q;
  Pp[g] = p0 * W1[c] + p1 * W1[64 + c] + p2 * W1[128 + c] - q + b1[c];
}

__global__ __launch_bounds__(256)
void mk_stats1(const float* __restrict__ Pp, const float* __restrict__ Qn,
               const int* __restrict__ idx1, float* __restrict__ statsP) {
  __shared__ int sidx[512];
  int tid = threadIdx.x;
  int c = tid & 63, grp = tid >> 6;
  int nb = blockIdx.x * 16;
  if (tid < 256) {
    sidx[tid] = idx1[nb * 32 + tid];
    sidx[tid + 256] = idx1[nb * 32 + 256 + tid];
  }
  __syncthreads();
  float s = 0.f, q = 0.f;
  for (int ln = 0; ln < 16; ++ln) {
    float pv = Pp[(size_t)(nb + ln) * 64 + c];
    for (int e = grp; e < 32; e += 4) {
      int j = sidx[ln * 32 + e];
      float v = fmaxf(pv + Qn[(size_t)j * 64 + c], 0.f);
      s += v; q = fmaf(v, v, q);
    }
  }
  int slot = (blockIdx.x * 4 + grp) & 63;
  atomicAdd(&statsP[(size_t)slot * 1024 + c], s);
  atomicAdd(&statsP[(size_t)slot * 1024 + 512 + c], q);
}

__global__ __launch_bounds__(128)
void mk_econv2(const float* __restrict__ R, const float* __restrict__ T,
               const int* __restrict__ st_i, float* __restrict__ mxp,
               float* __restrict__ mnp, float* __restrict__ statsP) {
  __shared__ int sidx[256];
  int tid = threadIdx.x;
  int nb = blockIdx.x * 8;
  sidx[tid] = st_i[nb * 32 + tid];
  sidx[tid + 128] = st_i[nb * 32 + 128 + tid];
  __syncthreads();
  float s = 0.f, q = 0.f;
  for (int ln = 0; ln < 8; ++ln) {
    int i = nb + ln;
    float rv = R[(size_t)i * 128 + tid];
    float mx = -3.4e38f, mn = 3.4e38f;
    for (int e = 0; e < 32; ++e) {
      int j = sidx[ln * 32 + e];
      float v = fmaxf(rv + T[(size_t)j * 128 + tid], 0.f);
      mx = fmaxf(mx, v); mn = fminf(mn, v);
      s += v; q = fmaf(v, v, q);
    }
    mxp[(size_t)i * 128 + tid] = mx;
    mnp[(size_t)i * 128 + tid] = mn;
  }
  int slot = blockIdx.x & 63;
  atomicAdd(&statsP[(size_t)slot * 1024 + tid], s);
  atomicAdd(&statsP[(size_t)slot * 1024 + 512 + tid], q);
}

// slot stats (sum @ +0, sq @ +512 per 1024-slot) -> coef (a @ +0, b @ +1024)
__global__ void mk_bnfinS(const float* __restrict__ sb, const float* __restrict__ g,
                          const float* __restrict__ beta, float* __restrict__ bno,
                          float Minv, int Cdim) {
  int c = blockIdx.x * 256 + threadIdx.x;
  if (c >= Cdim) return;
  float s = 0.f, q = 0.f;
  for (int sl = 0; sl < 64; ++sl) {
    s += sb[(size_t)sl * 1024 + c];
    q += sb[(size_t)sl * 1024 + 512 + c];
  }
  float mu = s * Minv;
  float var = q * Minv - mu * mu;
  float a = g[c] * rsqrtf(var + BN_EPS);
  bno[c] = a;
  bno[1024 + c] = beta[c] - a * mu;
}

__global__ void mk_finx1(const float* __restrict__ mx, const float* __restrict__ mn,
                         const float* __restrict__ bn, float* __restrict__ xc,
                         short* __restrict__ x1h, short* __restrict__ x1l) {
  int g = blockIdx.x * 256 + threadIdx.x;
  if (g >= 8192 * 64) return;
  int i = g >> 6, c = g & 63;
  float a = bn[c], b = bn[1024 + c];
  float v = (a > 0.f) ? fmaf(a, mx[g], b) : fmaf(a, mn[g], b);
  xc[(size_t)i * 192 + c] = v;
  unsigned short h = f2bf(v);
  x1h[g] = (short)h;
  x1l[g] = (short)f2bf(v - bf2f(h));
}
__global__ void mk_finx2(const float* __restrict__ mx, const float* __restrict__ mn,
                         const float* __restrict__ bn, float* __restrict__ xcB) {
  int g = blockIdx.x * 256 + threadIdx.x;
  if (g >= 8192 * 128) return;
  int i = g >> 7, c = g & 127;
  float a = bn[c], b = bn[1024 + c];
  xcB[(size_t)i * 192 + c] = (a > 0.f) ? fmaf(a, mx[g], b) : fmaf(a, mn[g], b);
}

// ---------------- kNN ----------------
__global__ void mk_posq(const float* __restrict__ pos, float4* __restrict__ posq) {
  int i = blockIdx.x * 256 + threadIdx.x;
  if (i >= 8192) return;
  float x = pos[i * 3], y = pos[i * 3 + 1], z = pos[i * 3 + 2];
  float s = fmaf(z, z, fmaf(y, y, x * x));
  posq[i] = make_float4(x, y, z, s);
}

// per-wave 8th-smallest of 64 lane values via ballot binary search (constant k=8)
__device__ __forceinline__ unsigned wave_kth8(unsigned v) {
  unsigned T = 0;
#pragma unroll
  for (int b = 31; b >= 0; --b) {
    unsigned cand = T | (1u << b);
    int c = __popcll(__ballot(v < cand));
    if (c < 8) T = cand;
  }
  return T;
}

__global__ __launch_bounds__(256)
void mk_knn1(const float4* __restrict__ posq, int* __restrict__ idxout) {
  __shared__ ull buf[K1CAP];
  __shared__ unsigned Tw[4];
  __shared__ unsigned cnt;
  int q = blockIdx.x, tid = threadIdx.x;
  int lane = tid & 63, wid = tid >> 6;
  float4 pq = posq[q];
  if (tid == 0) cnt = 0;
  unsigned key[32];
  unsigned vmin = 0xFFFFFFFFu;
#pragma unroll
  for (int c = 0; c < 32; ++c) {
    int j = c * 256 + tid;
    float4 pj = posq[j];
    float d = pq.w + pj.w - 2.f * (pq.x * pj.x + pq.y * pj.y + pq.z * pj.z);
    unsigned k = (j == q) ? 0xFFFFFFFFu : ordf(d);
    key[c] = k;
    vmin = vmin < k ? vmin : k;
  }
  unsigned T = wave_kth8(vmin);
  if (lane == 0) Tw[wid] = T;
  __syncthreads();
  unsigned Tmax = max(max(Tw[0], Tw[1]), max(Tw[2], Tw[3]));
#pragma unroll
  for (int c = 0; c < 32; ++c) {
    if (key[c] <= Tmax) {
      int j = c * 256 + tid;
      unsigned s = atomicAdd(&cnt, 1u);
      if (s < K1CAP) buf[s] = (((ull)key[c]) << 32) | (unsigned)j;
    }
  }
  __syncthreads();
  int m = cnt < (unsigned)K1CAP ? (int)cnt : K1CAP;
  for (int e = tid; e < m; e += 256) {
    ull mine = buf[e];
    int rank = 0;
    for (int f = 0; f < m; ++f) rank += (buf[f] < mine) ? 1 : 0;
    if (rank < 32) idxout[q * 32 + rank] = (int)(unsigned)(mine & 0xFFFFFFFFu);
  }
}

// per-row threshold: T = 32nd smallest of 128 tile-minima; also zero cnt
__global__ __launch_bounds__(256)
void mk_thresh(const unsigned* __restrict__ Tmin, unsigned* __restrict__ Trow,
               unsigned* __restrict__ cnt) {
  int tid = threadIdx.x, lane = tid & 63, wid = tid >> 6;
  int row = blockIdx.x * 4 + wid;
  unsigned t0 = Tmin[(size_t)row * 128 + lane];
  unsigned t1 = Tmin[(size_t)row * 128 + 64 + lane];
  unsigned T = 0;
#pragma unroll
  for (int b = 31; b >= 0; --b) {
    unsigned cand = T | (1u << b);
    int c = __popcll(__ballot(t0 < cand)) + __popcll(__ballot(t1 < cand));
    if (c < 32) T = cand;
  }
  if (lane == 0) { Trow[row] = T; cnt[row] = 0u; }
}

// exact rank of survivors -> idx output
__global__ __launch_bounds__(256)
void mk_rank(const unsigned* __restrict__ cnt, const ull* __restrict__ buf,
             int* __restrict__ idxout) {
  int tid = threadIdx.x, lane = tid & 63, wid = tid >> 6;
  int row = blockIdx.x * 4 + wid;
  unsigned cm = cnt[row];
  int m = cm < (unsigned)KPCAP ? (int)cm : KPCAP;
  for (int e = lane; e < m; e += 64) {
    ull mine = buf[(size_t)row * KPCAP + e];
    int rank = 0;
    for (int f = 0; f < m; ++f) rank += (buf[(size_t)row * KPCAP + f] < mine) ? 1 : 0;
    if (rank < 32) idxout[row * 32 + rank] = (int)(unsigned)(mine & 0xFFFFFFFFu);
  }
}

// ---------------- fp32 GEMM (tag1, K=16) ----------------
#define GBM 64
#define GBN 64
#define GBK 16

__global__ __launch_bounds__(256)
void mk_gemm(const float* __restrict__ A, const float* __restrict__ W, int ldw,
             const float* __restrict__ bias, float* __restrict__ C, int ldc,
             int M, int N, int K, int flags) {
  __shared__ float As[GBK][GBM + 4];
  __shared__ float Ws[GBK][GBN];
  int tid = threadIdx.x;
  int r0 = blockIdx.x * GBM, n0 = blockIdx.y * GBN;
  int ty = tid >> 4, tx = tid & 15;
  float acc[4][4] = {};
  for (int kt = 0; kt < K; kt += GBK) {
#pragma unroll
    for (int it = 0; it < 4; ++it) {
      int l = it * 256 + tid;
      int r = l >> 4, kk = l & 15;
      int gr = r0 + r, gk = kt + kk;
      float v = 0.f;
      if (gk < K && gr < M) v = A[(size_t)gr * K + gk];
      As[kk][r] = v;
      int kw = l >> 6, nw = l & 63;
      int gkw = kt + kw;
      Ws[kw][nw] = (gkw < K && (n0 + nw) < N) ? W[(size_t)gkw * ldw + n0 + nw] : 0.f;
    }
    __syncthreads();
#pragma unroll
    for (int kk = 0; kk < GBK; ++kk) {
      float4 a4 = *(const float4*)&As[kk][ty * 4];
      float4 b4 = *(const float4*)&Ws[kk][tx * 4];
      float av[4] = {a4.x, a4.y, a4.z, a4.w};
      float bv[4] = {b4.x, b4.y, b4.z, b4.w};
#pragma unroll
      for (int i = 0; i < 4; ++i)
#pragma unroll
        for (int j = 0; j < 4; ++j)
          acc[i][j] = fmaf(av[i], bv[j], acc[i][j]);
    }
    __syncthreads();
  }
#pragma unroll
  for (int i = 0; i < 4; ++i) {
    int gr = r0 + ty * 4 + i;
    if (gr >= M) continue;
#pragma unroll
    for (int j = 0; j < 4; ++j) {
      int gc = n0 + tx * 4 + j;
      if (gc >= N) continue;
      float v = acc[i][j];
      if (bias) v += bias[gc];
      if (flags & 1) v += C[(size_t)gr * ldc + gc];
      if (flags & 2) v = fmaxf(v, 0.f);
      C[(size_t)gr * ldc + gc] = v;
    }
  }
}

// ---------------- small utility kernels ----------------
__global__ void mk_sqnorm(const float* __restrict__ x, int ld, float* __restrict__ sq,
                          int Npts, int Cdim) {
  int i = blockIdx.x * blockDim.x + threadIdx.x;
  if (i >= Npts) return;
  float s = 0.f;
  for (int c = 0; c < Cdim; ++c) { float v = x[(size_t)i * ld + c]; s = fmaf(v, v, s); }
  sq[i] = s;
}

// ---------------- CSR build + props ----------------
__global__ void mk_count(const int* __restrict__ col, int* __restrict__ cnt, int E) {
  int e = blockIdx.x * 256 + threadIdx.x;
  if (e < E) atomicAdd(&cnt[col[e]], 1);
}
__global__ __launch_bounds__(1024)
void mk_scan(const int* __restrict__ cnt, int* __restrict__ offp,
             int* __restrict__ cur, float* __restrict__ dinvf) {
  __shared__ int wsum[16];
  __shared__ int wexc[16];
  int t = threadIdx.x, lane = t & 63, w = t >> 6;
  int v[8]; int s = 0;
  int base = t * 8;
#pragma unroll
  for (int k = 0; k < 8; ++k) { v[k] = s; s += cnt[base + k]; }
  int sc = s;
#pragma unroll
  for (int off2 = 1; off2 < 64; off2 <<= 1) {
    int n = __shfl_up(sc, off2, 64);
    if (lane >= off2) sc += n;
  }
  if (lane == 63) wsum[w] = sc;
  __syncthreads();
  if (w == 0) {
    int x = (lane < 16) ? wsum[lane] : 0;
    int scx = x;
#pragma unroll
    for (int off2 = 1; off2 < 16; off2 <<= 1) {
      int n = __shfl_up(scx, off2, 64);
      if (lane >= off2) scx += n;
    }
    if (lane < 16) wexc[lane] = scx - x;
  }
  __syncthreads();
  int texc = wexc[w] + (sc - s);
#pragma unroll
  for (int k = 0; k < 8; ++k) {
    int o = texc + v[k];
    offp[base + k] = o;
    cur[base + k] = o;
    int d = cnt[base + k];
    dinvf[base + k] = (d > 0) ? rsqrtf((float)(d < 1 ? 1 : d)) : 0.f;
  }
  if (t == 1023) offp[8192] = texc + s;
}
__global__ void mk_fill(const int* __restrict__ row, const int* __restrict__ col,
                        const float* __restrict__ dinvf, int* __restrict__ cur,
                        int* __restrict__ crow, float* __restrict__ cw, int E) {
  int e = blockIdx.x * 256 + threadIdx.x;
  if (e >= E) return;
  int c = col[e], r = row[e];
  int s = atomicAdd(&cur[c], 1);
  crow[s] = r;
  cw[s] = dinvf[r] * dinvf[c];
}
__global__ void mk_prop64(const float* __restrict__ in, int in_ld,
                          const int* __restrict__ offp, const int* __restrict__ crow,
                          const float* __restrict__ cw, float* __restrict__ out, int out_ld) {
  int gid = blockIdx.x * 256 + threadIdx.x;
  if (gid >= 8192 * 16) return;
  int col = gid >> 4, c4 = (gid & 15) * 4;
  int s0 = offp[col], s1 = offp[col + 1];
  float a0 = 0, a1 = 0, a2 = 0, a3 = 0;
  for (int s = s0; s < s1; ++s) {
    int r = crow[s]; float w = cw[s];
    float4 v = *(const float4*)&in[(size_t)r * in_ld + c4];
    a0 = fmaf(w, v.x, a0); a1 = fmaf(w, v.y, a1);
    a2 = fmaf(w, v.z, a2); a3 = fmaf(w, v.w, a3);
  }
  float4 o = {a0, a1, a2, a3};
  *(float4*)&out[(size_t)col * out_ld + c4] = o;
}
__global__ void mk_prop4(const float* __restrict__ in, int in_ld,
                         const int* __restrict__ offp, const int* __restrict__ crow,
                         const float* __restrict__ cw, float* __restrict__ out, int out_ld) {
  int col = blockIdx.x * 256 + threadIdx.x;
  if (col >= 8192) return;
  int s0 = offp[col], s1 = offp[col + 1];
  float a0 = 0, a1 = 0, a2 = 0, a3 = 0;
  for (int s = s0; s < s1; ++s) {
    int r = crow[s]; float w = cw[s];
    float4 v = *(const float4*)&in[(size_t)r * in_ld];
    a0 = fmaf(w, v.x, a0); a1 = fmaf(w, v.y, a1);
    a2 = fmaf(w, v.z, a2); a3 = fmaf(w, v.w, a3);
  }
  float4 o = {a0, a1, a2, a3};
  *(float4*)&out[(size_t)col * out_ld] = o;
}
__global__ void mk_pack4(const float* __restrict__ xin, float* __restrict__ H1) {
  int g = blockIdx.x * 256 + threadIdx.x;
  if (g >= 8192 * 4) return;
  H1[(size_t)(g >> 2) * 16 + (g & 3)] = xin[g];
}
__global__ void mk_copy64(const float* __restrict__ gcv, float* __restrict__ H2) {
  int g = blockIdx.x * 256 + threadIdx.x;
  if (g >= 8192 * 64) return;
  H2[(size_t)(g >> 6) * 256 + (g & 63)] = gcv[(size_t)(g >> 6) * 192 + (g & 63)];
}

__global__ __launch_bounds__(256)
void mk_gemv_out(const float* __restrict__ h, const float* __restrict__ bn,
                 const float* __restrict__ w, const float* __restrict__ b,
                 float* __restrict__ out, int Npts) {
  int row = blockIdx.x * 4 + (threadIdx.x >> 6);
  int lane = threadIdx.x & 63;
  if (row >= Npts) return;
  int c = lane * 4;
  float4 v = *(const float4*)&h[(size_t)row * 256 + c];
  float s = (bn[c] * v.x + bn[1024 + c]) * w[c]
          + (bn[c + 1] * v.y + bn[1024 + c + 1]) * w[c + 1]
          + (bn[c + 2] * v.z + bn[1024 + c + 2]) * w[c + 2]
          + (bn[c + 3] * v.w + bn[1024 + c + 3]) * w[c + 3];
#pragma unroll
  for (int off = 32; off; off >>= 1) s += __shfl_xor(s, off, 64);
  if (lane == 0) out[row] = s + b[0];
}

// ---------------- host ----------------
extern "C" void kernel_launch(void* const* d_in, const int* in_sizes, int n_in,
                              void* d_out, int out_size, void* d_ws, size_t ws_size,
                              hipStream_t stream) {
  const int N = 8192;
  const int NE = N * 32;
  const float* pos = (const float*)d_in[0];
  const float* xin = (const float*)d_in[1];
  const int* ei = (const int*)d_in[2];
  const int E = in_sizes[2] / 2;
  const int* erow = ei;
  const int* ecol = ei + E;
  const float* mlp1_W1  = (const float*)d_in[3];
  const float* mlp1_W23 = (const float*)d_in[4];
  const float* mlp1_b   = (const float*)d_in[5];
  const float* mlp1_g   = (const float*)d_in[6];
  const float* mlp1_be  = (const float*)d_in[7];
  const float* mlp2_W   = (const float*)d_in[8];
  const float* mlp2_b   = (const float*)d_in[9];
  const float* mlp2_g   = (const float*)d_in[10];
  const float* mlp2_be  = (const float*)d_in[11];
  const float* lin1_W   = (const float*)d_in[12];
  const float* lin1_b   = (const float*)d_in[13];
  const float* lin1_g   = (const float*)d_in[14];
  const float* lin1_be  = (const float*)d_in[15];
  const float* tag1_W   = (const float*)d_in[16];
  const float* tag1_b   = (const float*)d_in[17];
  const float* tag2_W   = (const float*)d_in[18];
  const float* tag2_b   = (const float*)d_in[19];
  const float* lin2_W   = (const float*)d_in[20];
  const float* lin2_b   = (const float*)d_in[21];
  const float* lin2_g   = (const float*)d_in[22];
  const float* lin2_be  = (const float*)d_in[23];
  const float* mix1_W   = (const float*)d_in[24];
  const float* mix1_b   = (const float*)d_in[25];
  const float* mix1_g   = (const float*)d_in[26];
  const float* mix1_be  = (const float*)d_in[27];
  const float* mix2_W   = (const float*)d_in[28];
  const float* mix2_b   = (const float*)d_in[29];
  const float* mix2_g   = (const float*)d_in[30];
  const float* mix2_be  = (const float*)d_in[31];
  const float* outW     = (const float*)d_in[32];
  const float* outB     = (const float*)d_in[33];

  char* base = (char*)d_ws;
  size_t off = 0;
  auto alloc = [&](size_t b) -> void* {
    void* p = base + off;
    off += (b + 255) & ~(size_t)255;
    return p;
  };
  float* BIG = (float*)alloc(134217728ull);   // 128 MB phase-shared
  short* h2_h  = (short*)BIG;                            // conv1 L2 out hi (32 MB)
  short* h2_l  = (short*)((char*)BIG + 33554432);        // lo (32 MB)
  ull*   kbuf  = (ull*)BIG;                              // knn2 survivor buf [8192][512] (32 MB)
  unsigned* Tmin = (unsigned*)((char*)BIG + 33554432);   // [8192][128] (4 MB)
  short* mhcat_h = (short*)BIG;                          // [8192][1024] hi (16 MB)
  short* mhcat_l = (short*)((char*)BIG + 16777216);      // lo (16 MB)
  short* mh1_h   = (short*)((char*)BIG + 33554432);      // [8192][512] hi (8 MB)
  short* mh1_l   = (short*)((char*)BIG + 41943040);      // lo (8 MB)
  float* mh2     = (float*)((char*)BIG + 50331648);      // [8192][256] fp32 (8 MB)
  float* H2      = BIG + 16777216;                       // byte 64M+: tag2 hop-concat
  int*   idx1 = (int*)alloc((size_t)NE * 4);
  int*   st_i = (int*)alloc((size_t)NE * 4);
  unsigned* Trow = (unsigned*)alloc((size_t)N * 4);
  unsigned* kcnt = (unsigned*)alloc((size_t)N * 4);
  float* xc  = (float*)alloc((size_t)N * 192 * 4);   // [x1 | x2]
  float* gc  = (float*)alloc((size_t)N * 192 * 4);   // [g1 | g2]
  float4* posq = (float4*)alloc((size_t)N * 16);
  float* sqx = (float*)alloc((size_t)N * 4);
  float* Pp  = (float*)alloc((size_t)N * 64 * 4);
  float* Qn  = (float*)alloc((size_t)N * 64 * 4);
  float* Rb  = (float*)alloc((size_t)N * 128 * 4);
  float* Tb  = (float*)alloc((size_t)N * 128 * 4);
  float* mx1 = (float*)alloc((size_t)N * 64 * 4);
  float* mn1 = (float*)alloc((size_t)N * 64 * 4);
  float* mx2 = (float*)alloc((size_t)N * 128 * 4);
  float* mn2 = (float*)alloc((size_t)N * 128 * 4);
  float* H1  = (float*)alloc((size_t)N * 16 * 4);
  float* dinvf = (float*)alloc((size_t)N * 4);
  int* cnt     = (int*)alloc((size_t)N * 4);
  int* csr_off = (int*)alloc((size_t)(N + 1) * 4);
  int* cursor  = (int*)alloc((size_t)N * 4);
  int* csr_row = (int*)alloc((size_t)E * 4);
  float* csr_w = (float*)alloc((size_t)E * 4);
  float* slotAll = (float*)alloc((size_t)8 * 64 * 1024 * 4);
  auto slot = [&](int i) { return slotAll + (size_t)i * 64 * 1024; };
  float* bnb = (float*)alloc(8 * 2048 * 4);           // coef: a @ +0, b @ +1024
  auto bnp = [&](int i) { return bnb + (size_t)i * 2048; };
  float* bnM = bnp(4);                                // lin1 a cols 0-511, lin2 at +512
  float* bias1f = (float*)alloc(512 * 4);
  float* bias2f = (float*)alloc(256 * 4);
  float* biasA  = (float*)alloc(64 * 4);
  float* biasB  = (float*)alloc(64 * 4);
  auto salloc = [&](size_t n) { return (short*)alloc(n * 2); };
  short* w23a_h = salloc(4096);   short* w23a_l = salloc(4096);
  short* w23b_h = salloc(4096);   short* w23b_l = salloc(4096);
  short* wd2_h  = salloc(8192);   short* wd2_l  = salloc(8192);
  short* wv2_h  = salloc(8192);   short* wv2_l  = salloc(8192);
  short* wl1_h  = salloc(98304);  short* wl1_l  = salloc(98304);
  short* wt2_h  = salloc(32768);  short* wt2_l  = salloc(32768);
  short* wl2_h  = salloc(98304);  short* wl2_l  = salloc(98304);
  short* wx1_h  = salloc(524288); short* wx1_l  = salloc(524288);
  short* wx2_h  = salloc(131072); short* wx2_l  = salloc(131072);
  short* x1h    = salloc(524288); short* x1l    = salloc(524288);

  auto gemmF = [&](const float* A, const short* A8h, const short* A8l,
                   const float* src, const int* gidx, int srcC, const float* bnA,
                   const short* Wh_, const short* Wl_, int ldk, int koff, int lda,
                   const float* bias, float* Cp, short* Chp, short* Clp, int ldc,
                   int M, int Nn, int Kk, int flags,
                   float* stP = nullptr, float* mxP = nullptr, float* mnP = nullptr) {
    dim3 g(M / 64, Nn / 64);
    mk_gemm_mfma<<<g, 256, 0, stream>>>(A, A8h, A8l, src, gidx, srcC, bnA,
                                        Wh_, Wl_, ldk, koff, lda, bias, Cp, Chp, Clp, ldc,
                                        M, Nn, Kk, flags, stP, mxP, mnP);
  };
  auto wcvt = [&](const float* W, short* Wh_, short* Wl_, int Kk, int Nn) {
    mk_wcvt<<<(Kk * Nn + 255) / 256, 256, 0, stream>>>(W, Wh_, Wl_, Kk, Nn);
  };

  // ---- init + weight conversion ----
  hipMemsetAsync(slotAll, 0, (size_t)8 * 64 * 1024 * 4, stream);
  hipMemsetAsync(cnt, 0, (size_t)N * 4, stream);
  mk_wcvt2<<<(64 * 128 + 255) / 256, 256, 0, stream>>>(mlp2_W, wd2_h, wd2_l, wv2_h, wv2_l);
  wcvt(lin1_W, wl1_h, wl1_l, 192, 512);
  wcvt(tag2_W, wt2_h, wt2_l, 256, 128);
  wcvt(lin2_W, wl2_h, wl2_l, 192, 512);

  // ---- kNN-1 on pos ----
  mk_posq<<<32, 256, 0, stream>>>(pos, posq);
  mk_knn1<<<N, 256, 0, stream>>>(posq, idx1);

  // ---- conv1 ----
  mk_conv1nodes<<<(N * 64 + 255) / 256, 256, 0, stream>>>(pos, mlp1_W1, mlp1_b, Pp, Qn);
  mk_stats1<<<512, 256, 0, stream>>>(Pp, Qn, idx1, slot(0));
  mk_bnfinS<<<1, 256, 0, stream>>>(slot(0), mlp1_g, mlp1_be, bnp(0), 1.f / NE, 64);
  mk_wcvts<<<(64 * 64 + 255) / 256, 256, 0, stream>>>(mlp1_W23, bnp(0), w23a_h, w23a_l, 64, 64);
  mk_biasfold<<<16, 256, 0, stream>>>(mlp1_W23, bnp(0) + 1024, mlp1_b + 64, biasA, 64, 64);
  gemmF(Pp, nullptr, nullptr, Qn, idx1, 64, nullptr,
        w23a_h, w23a_l, 64, 0, 64, biasA, nullptr, h2_h, h2_l, 64,
        NE, 64, 64, 2 | 8 | 32 | 64, slot(1));
  mk_bnfinS<<<1, 256, 0, stream>>>(slot(1), mlp1_g + 64, mlp1_be + 64, bnp(1), 1.f / NE, 64);
  mk_wcvts<<<(64 * 64 + 255) / 256, 256, 0, stream>>>(mlp1_W23 + 4096, bnp(1), w23b_h, w23b_l, 64, 64);
  mk_biasfold<<<16, 256, 0, stream>>>(mlp1_W23 + 4096, bnp(1) + 1024, mlp1_b + 128, biasB, 64, 64);
  gemmF(nullptr, h2_h, h2_l, nullptr, nullptr, 0, nullptr,
        w23b_h, w23b_l, 64, 0, 64, biasB, nullptr, nullptr, nullptr, 64,
        NE, 64, 64, 2 | 8 | 16, slot(2), mx1, mn1);
  mk_bnfinS<<<1, 256, 0, stream>>>(slot(2), mlp1_g + 128, mlp1_be + 128, bnp(2), 1.f / NE, 64);
  mk_finx1<<<(N * 64 + 255) / 256, 256, 0, stream>>>(mx1, mn1, bnp(2), xc, x1h, x1l);

  // ---- kNN-2 on x1: tile-min threshold, no key matrix ----
  mk_sqnorm<<<32, 256, 0, stream>>>(xc, 192, sqx, N, 64);
  // pass A: per-row tile minima -> Tmin[8192][128]
  gemmF(nullptr, x1h, x1l, sqx, nullptr, 0, nullptr,
        x1h, x1l, 64, 0, 64,
        nullptr, (float*)Tmin, nullptr, nullptr, 128, N, N, 64, 128);
  // per-row threshold (32nd smallest tile-min) + zero counters
  mk_thresh<<<N / 4, 256, 0, stream>>>(Tmin, Trow, kcnt);
  // pass B: push survivors
  gemmF(nullptr, x1h, x1l, sqx, (const int*)Trow, 0, nullptr,
        x1h, x1l, 64, 0, 64,
        nullptr, nullptr, nullptr, nullptr, 0, N, N, 64, 256,
        nullptr, (float*)kcnt, (float*)kbuf);
  // exact rank -> neighbor indices
  mk_rank<<<N / 4, 256, 0, stream>>>(kcnt, kbuf, st_i);

  // ---- conv2 ----
  gemmF(nullptr, x1h, x1l, nullptr, nullptr, 0, nullptr,
        wd2_h, wd2_l, 64, 0, 64, mlp2_b, Rb, nullptr, nullptr, 128, N, 128, 64, 0);
  gemmF(nullptr, x1h, x1l, nullptr, nullptr, 0, nullptr,
        wv2_h, wv2_l, 64, 0, 64, nullptr, Tb, nullptr, nullptr, 128, N, 128, 64, 0);
  mk_econv2<<<N / 8, 128, 0, stream>>>(Rb, Tb, st_i, mx2, mn2, slot(3));
  mk_bnfinS<<<1, 256, 0, stream>>>(slot(3), mlp2_g, mlp2_be, bnp(3), 1.f / NE, 128);
  mk_finx2<<<(N * 128 + 255) / 256, 256, 0, stream>>>(mx2, mn2, bnp(3), xc + 64);

  // ---- lin1: K=192 GEMM -> mhcat (bf16 hi/lo) cols 0-511 ----
  gemmF(xc, nullptr, nullptr, nullptr, nullptr, 0, nullptr,
        wl1_h, wl1_l, 192, 0, 192, lin1_b, nullptr, mhcat_h, mhcat_l, 1024,
        N, 512, 192, 2 | 8 | 64, slot(4));
  mk_bnfinS<<<2, 256, 0, stream>>>(slot(4), lin1_g, lin1_be, bnM, 1.f / N, 512);

  // ---- TAG branch: CSR ----
  mk_count<<<(E + 255) / 256, 256, 0, stream>>>(ecol, cnt, E);
  mk_scan<<<1, 1024, 0, stream>>>(cnt, csr_off, cursor, dinvf);
  mk_fill<<<(E + 255) / 256, 256, 0, stream>>>(erow, ecol, dinvf, cursor, csr_row, csr_w, E);
  // tag1 -> gc cols 0-63
  mk_pack4<<<(N * 4 + 255) / 256, 256, 0, stream>>>(xin, H1);
  mk_prop4<<<32, 256, 0, stream>>>(xin, 4, csr_off, csr_row, csr_w, H1 + 4, 16);
  mk_prop4<<<32, 256, 0, stream>>>(H1 + 4, 16, csr_off, csr_row, csr_w, H1 + 8, 16);
  mk_prop4<<<32, 256, 0, stream>>>(H1 + 8, 16, csr_off, csr_row, csr_w, H1 + 12, 16);
  mk_gemm<<<dim3(128, 1), 256, 0, stream>>>(H1, tag1_W, 64, tag1_b, gc, 192, N, 64, 16, 2);
  // tag2: hop-concat H2 -> one K=256 gemmF -> gc cols 64-191
  mk_copy64<<<(N * 64 + 255) / 256, 256, 0, stream>>>(gc, H2);
  mk_prop64<<<512, 256, 0, stream>>>(gc, 192, csr_off, csr_row, csr_w, H2 + 64, 256);
  mk_prop64<<<512, 256, 0, stream>>>(H2 + 64, 256, csr_off, csr_row, csr_w, H2 + 128, 256);
  mk_prop64<<<512, 256, 0, stream>>>(H2 + 128, 256, csr_off, csr_row, csr_w, H2 + 192, 256);
  gemmF(H2, nullptr, nullptr, nullptr, nullptr, 0, nullptr,
        wt2_h, wt2_l, 256, 0, 256, tag2_b, gc + 64, nullptr, nullptr, 192,
        N, 128, 256, 2);
  // lin2: K=192 GEMM -> mhcat (bf16 hi/lo) cols 512-1023
  gemmF(gc, nullptr, nullptr, nullptr, nullptr, 0, nullptr,
        wl2_h, wl2_l, 192, 0, 192, lin2_b, nullptr, mhcat_h + 512, mhcat_l + 512, 1024,
        N, 512, 192, 2 | 8 | 64, slot(5));
  mk_bnfinS<<<2, 256, 0, stream>>>(slot(5), lin2_g, lin2_be, bnM + 512, 1.f / N, 512);

  // ---- fold lin BN into mix1 weights; mix head on fast A8 path ----
  mk_wcvts<<<(1024 * 512 + 255) / 256, 256, 0, stream>>>(mix1_W, bnM, wx1_h, wx1_l, 1024, 512);
  mk_biasfold<<<128, 256, 0, stream>>>(mix1_W, bnM + 1024, mix1_b, bias1f, 1024, 512);
  gemmF(nullptr, mhcat_h, mhcat_l, nullptr, nullptr, 0, nullptr,
        wx1_h, wx1_l, 1024, 0, 1024, bias1f, nullptr, mh1_h, mh1_l, 512,
        N, 512, 1024, 2 | 8 | 64, slot(6));
  mk_bnfinS<<<2, 256, 0, stream>>>(slot(6), mix1_g, mix1_be, bnp(6), 1.f / N, 512);
  mk_wcvts<<<(512 * 256 + 255) / 256, 256, 0, stream>>>(mix2_W, bnp(6), wx2_h, wx2_l, 512, 256);
  mk_biasfold<<<64, 256, 0, stream>>>(mix2_W, bnp(6) + 1024, mix2_b, bias2f, 512, 256);
  gemmF(nullptr, mh1_h, mh1_l, nullptr, nullptr, 0, nullptr,
        wx2_h, wx2_l, 512, 0, 512, bias2f, mh2, nullptr, nullptr, 256,
        N, 256, 512, 2 | 8, slot(7));
  mk_bnfinS<<<1, 256, 0, stream>>>(slot(7), mix2_g, mix2_be, bnp(7), 1.f / N, 256);
  mk_gemv_out<<<N / 4, 256, 0, stream>>>(mh2, bnp(7), outW, outB, (float*)d_out, N);
}

// Round 19
// 686.486 us; speedup vs baseline: 1.1532x; 1.1532x over previous
//
#include <hip/hip_runtime.h>
#include <cstdint>
#include <cstddef>

#define BN_EPS 1e-5f
#define K1CAP 1024
#define K2CAP 640

typedef short short8 __attribute__((ext_vector_type(8)));
typedef float f32x4 __attribute__((ext_vector_type(4)));
typedef unsigned long long ull;

// ---------------- helpers ----------------
__device__ __forceinline__ unsigned int ordf(float d) {
  unsigned int u = __float_as_uint(d);
  return (u >> 31) ? ~u : (u | 0x80000000u);
}
__device__ __forceinline__ unsigned short f2bf(float f) {
  unsigned u = __float_as_uint(f);
  u += 0x7fffu + ((u >> 16) & 1u);
  return (unsigned short)(u >> 16);
}
__device__ __forceinline__ float bf2f(unsigned short h) {
  return __uint_as_float(((unsigned)h) << 16);
}

// ---------------- MFMA bf16x3 GEMM (K_STEP=64, reg-staged pipeline) ----------------
// flags: 1=ACC, 2=RELU, 8=stats epilogue (slotted), 16=maxmin epilogue (NO C
// write), 32=EDGE1-A (v=relu(A[i][k]+src[j][k])), 64=BF16OUT (write Ch/Cl),
// 128=KEYOUT (write ordf(src[gr]+src[srcC+gc]-2v) as u32 into C; diagonal
// gr==srcC+gc -> ~0u; src=sq table, srcC=column offset).
// A-source priority: A8h/A8l (bf16 hi/lo [M][lda]) -> flags&32 -> fp32 A [M][lda]
// (+optional bnA affine: bnA[k]*v + bnA[1024+k]). W: bf16 hi/lo n-major
// [N][ldk], k index = koff+k. Requires M%64==0, N%64==0, K%64==0.
#define BPAD 72

__global__ __launch_bounds__(256)
void mk_gemm_mfma(const float* __restrict__ A,
                  const short* __restrict__ A8h, const short* __restrict__ A8l,
                  const float* __restrict__ src, const int* __restrict__ gidx, int srcC,
                  const float* __restrict__ bnA,
                  const short* __restrict__ Wh, const short* __restrict__ Wl,
                  int ldk, int koff, int lda,
                  const float* __restrict__ bias,
                  float* __restrict__ C, short* __restrict__ Ch, short* __restrict__ Cl,
                  int ldc,
                  int M, int N, int K, int flags,
                  float* __restrict__ statsP,
                  float* __restrict__ mxp, float* __restrict__ mnp) {
  __shared__ short Ah[64][BPAD], Al[64][BPAD], Bh[64][BPAD], Bl[64][BPAD];
  __shared__ float ssum[64], ssq[64];
  int tid = threadIdx.x, lane = tid & 63, wid = tid >> 6;
  int wr = wid >> 1, wc = wid & 1;
  int r0 = blockIdx.x * 64, n0 = blockIdx.y * 64;
  int sr = tid >> 2, sc = (tid & 3) * 16;
  f32x4 zero4 = {0.f, 0.f, 0.f, 0.f};
  f32x4 acc[2][2] = {{zero4, zero4}, {zero4, zero4}};
  short8 rAh[2], rAl[2], rBh[2], rBl[2];

  auto stage = [&](int kt) {
    const short* bh = &Wh[(size_t)(n0 + sr) * ldk + koff + kt + sc];
    const short* bl = &Wl[(size_t)(n0 + sr) * ldk + koff + kt + sc];
    rBh[0] = *(const short8*)bh; rBh[1] = *(const short8*)(bh + 8);
    rBl[0] = *(const short8*)bl; rBl[1] = *(const short8*)(bl + 8);
    if (A8h) {
      const short* ah = &A8h[(size_t)(r0 + sr) * lda + kt + sc];
      const short* al = &A8l[(size_t)(r0 + sr) * lda + kt + sc];
      rAh[0] = *(const short8*)ah; rAh[1] = *(const short8*)(ah + 8);
      rAl[0] = *(const short8*)al; rAl[1] = *(const short8*)(al + 8);
    } else {
      float v[16];
      if (flags & 32) {
        int gr = r0 + sr;
        int i = gr >> 5; int j = gidx[gr];
        const float* pi = &A[(size_t)i * srcC + kt + sc];
        const float* pj = &src[(size_t)j * srcC + kt + sc];
        float va[16], vb[16];
        *(float4*)&va[0]  = *(const float4*)&pi[0];
        *(float4*)&va[4]  = *(const float4*)&pi[4];
        *(float4*)&va[8]  = *(const float4*)&pi[8];
        *(float4*)&va[12] = *(const float4*)&pi[12];
        *(float4*)&vb[0]  = *(const float4*)&pj[0];
        *(float4*)&vb[4]  = *(const float4*)&pj[4];
        *(float4*)&vb[8]  = *(const float4*)&pj[8];
        *(float4*)&vb[12] = *(const float4*)&pj[12];
#pragma unroll
        for (int e = 0; e < 16; ++e) v[e] = fmaxf(va[e] + vb[e], 0.f);
      } else {
        const float* ap = &A[(size_t)(r0 + sr) * lda + kt + sc];
        *(float4*)&v[0]  = *(const float4*)&ap[0];
        *(float4*)&v[4]  = *(const float4*)&ap[4];
        *(float4*)&v[8]  = *(const float4*)&ap[8];
        *(float4*)&v[12] = *(const float4*)&ap[12];
      }
      if (bnA) {
#pragma unroll
        for (int e = 0; e < 16; ++e) {
          int gk = kt + sc + e;
          v[e] = fmaf(bnA[gk], v[e], bnA[1024 + gk]);
        }
      }
#pragma unroll
      for (int e = 0; e < 16; ++e) {
        unsigned short h = f2bf(v[e]);
        rAh[e >> 3][e & 7] = (short)h;
        rAl[e >> 3][e & 7] = (short)f2bf(v[e] - bf2f(h));
      }
    }
  };

  stage(0);
  for (int kt = 0; kt < K; kt += 64) {
    *(short8*)&Ah[sr][sc]     = rAh[0];
    *(short8*)&Ah[sr][sc + 8] = rAh[1];
    *(short8*)&Al[sr][sc]     = rAl[0];
    *(short8*)&Al[sr][sc + 8] = rAl[1];
    *(short8*)&Bh[sr][sc]     = rBh[0];
    *(short8*)&Bh[sr][sc + 8] = rBh[1];
    *(short8*)&Bl[sr][sc]     = rBl[0];
    *(short8*)&Bl[sr][sc + 8] = rBl[1];
    __syncthreads();
    if (kt + 64 < K) stage(kt + 64);
    int ar = wr * 32 + (lane & 15);
    int br = wc * 32 + (lane & 15);
#pragma unroll
    for (int kk = 0; kk < 2; ++kk) {
      int kof = kk * 32 + (lane >> 4) * 8;
      short8 a_h[2], a_l[2], b_h[2], b_l[2];
#pragma unroll
      for (int t = 0; t < 2; ++t) {
        a_h[t] = *(const short8*)&Ah[ar + t * 16][kof];
        a_l[t] = *(const short8*)&Al[ar + t * 16][kof];
        b_h[t] = *(const short8*)&Bh[br + t * 16][kof];
        b_l[t] = *(const short8*)&Bl[br + t * 16][kof];
      }
#pragma unroll
      for (int mt = 0; mt < 2; ++mt)
#pragma unroll
        for (int nt = 0; nt < 2; ++nt) {
          acc[mt][nt] = __builtin_amdgcn_mfma_f32_16x16x32_bf16(a_h[mt], b_h[nt], acc[mt][nt], 0, 0, 0);
          acc[mt][nt] = __builtin_amdgcn_mfma_f32_16x16x32_bf16(a_h[mt], b_l[nt], acc[mt][nt], 0, 0, 0);
          acc[mt][nt] = __builtin_amdgcn_mfma_f32_16x16x32_bf16(a_l[mt], b_h[nt], acc[mt][nt], 0, 0, 0);
        }
    }
    __syncthreads();
  }
  bool dostat = (flags & 8) != 0, domx = (flags & 16) != 0;
  float lsum[2] = {0.f, 0.f}, lsq[2] = {0.f, 0.f};
  float lmx[2] = {-3.4e38f, -3.4e38f}, lmn[2] = {3.4e38f, 3.4e38f};
#pragma unroll
  for (int nt = 0; nt < 2; ++nt) {
    int gc = n0 + wc * 32 + nt * 16 + (lane & 15);
#pragma unroll
    for (int mt = 0; mt < 2; ++mt)
#pragma unroll
      for (int i = 0; i < 4; ++i) {
        int gr = r0 + wr * 32 + mt * 16 + (lane >> 4) * 4 + i;
        float v = acc[mt][nt][i];
        if (bias) v += bias[gc];
        if (flags & 1) v += C[(size_t)gr * ldc + gc];
        if (flags & 2) v = fmaxf(v, 0.f);
        if (!domx) {
          if (flags & 128) {
            int gj = srcC + gc;
            unsigned kk2 = (gr == gj) ? 0xFFFFFFFFu
                                      : ordf(src[gr] + src[gj] - 2.f * v);
            ((unsigned*)C)[(size_t)gr * ldc + gc] = kk2;
          } else if (flags & 64) {
            unsigned short hh = f2bf(v);
            Ch[(size_t)gr * ldc + gc] = (short)hh;
            Cl[(size_t)gr * ldc + gc] = (short)f2bf(v - bf2f(hh));
          } else {
            C[(size_t)gr * ldc + gc] = v;
          }
        }
        lsum[nt] += v; lsq[nt] = fmaf(v, v, lsq[nt]);
        lmx[nt] = fmaxf(lmx[nt], v); lmn[nt] = fminf(lmn[nt], v);
      }
  }
  if (dostat || domx) {
#pragma unroll
    for (int nt = 0; nt < 2; ++nt) {
#pragma unroll
      for (int m = 16; m <= 32; m <<= 1) {
        lsum[nt] += __shfl_xor(lsum[nt], m, 64);
        lsq[nt] += __shfl_xor(lsq[nt], m, 64);
        lmx[nt] = fmaxf(lmx[nt], __shfl_xor(lmx[nt], m, 64));
        lmn[nt] = fminf(lmn[nt], __shfl_xor(lmn[nt], m, 64));
      }
    }
    if (domx && lane < 16) {
      int node = blockIdx.x * 2 + wr;
#pragma unroll
      for (int nt = 0; nt < 2; ++nt) {
        int gc = n0 + wc * 32 + nt * 16 + lane;
        mxp[(size_t)node * N + gc] = lmx[nt];
        mnp[(size_t)node * N + gc] = lmn[nt];
      }
    }
    if (dostat) {
      if (tid < 64) { ssum[tid] = 0.f; ssq[tid] = 0.f; }
      __syncthreads();
      if (lane < 16) {
#pragma unroll
        for (int nt = 0; nt < 2; ++nt) {
          int ct = wc * 32 + nt * 16 + lane;
          atomicAdd(&ssum[ct], lsum[nt]);
          atomicAdd(&ssq[ct], lsq[nt]);
        }
      }
      __syncthreads();
      if (tid < 64) {
        int slot = blockIdx.x & 63;
        int gc = n0 + tid;
        atomicAdd(&statsP[(size_t)slot * 1024 + gc], ssum[tid]);
        atomicAdd(&statsP[(size_t)slot * 1024 + 512 + gc], ssq[tid]);
      }
    }
  }
}

// ---------------- weight conversion ----------------
__global__ void mk_wcvt(const float* __restrict__ W, short* __restrict__ Wh,
                        short* __restrict__ Wl, int K, int N) {
  int g = blockIdx.x * 256 + threadIdx.x;
  if (g >= K * N) return;
  int k = g / N, n = g - k * N;
  float v = W[g];
  unsigned short h = f2bf(v);
  Wh[(size_t)n * K + k] = (short)h;
  Wl[(size_t)n * K + k] = (short)f2bf(v - bf2f(h));
}
__global__ void mk_wcvts(const float* __restrict__ W, const float* __restrict__ a,
                         short* __restrict__ Wh, short* __restrict__ Wl, int K, int N) {
  int g = blockIdx.x * 256 + threadIdx.x;
  if (g >= K * N) return;
  int k = g / N, n = g - k * N;
  float v = a[k] * W[g];
  unsigned short h = f2bf(v);
  Wh[(size_t)n * K + k] = (short)h;
  Wl[(size_t)n * K + k] = (short)f2bf(v - bf2f(h));
}
__global__ void mk_biasfold(const float* __restrict__ W, const float* __restrict__ bv,
                            const float* __restrict__ b0, float* __restrict__ bo,
                            int K, int N) {
  int col = blockIdx.x * 4 + (threadIdx.x >> 6);
  int lane = threadIdx.x & 63;
  if (col >= N) return;
  float s = 0.f;
  for (int k = lane; k < K; k += 64) s = fmaf(bv[k], W[(size_t)k * N + col], s);
#pragma unroll
  for (int off = 32; off; off >>= 1) s += __shfl_xor(s, off, 64);
  if (lane == 0) bo[col] = b0[col] + s;
}
__global__ void mk_wcvt2(const float* __restrict__ W, short* __restrict__ Dh,
                         short* __restrict__ Dl, short* __restrict__ Vh,
                         short* __restrict__ Vl) {
  int g = blockIdx.x * 256 + threadIdx.x;
  if (g >= 64 * 128) return;
  int k = g >> 7, n = g & 127;
  float u = W[k * 128 + n], vv = W[(64 + k) * 128 + n];
  float d = u - vv;
  unsigned short h = f2bf(d);
  Dh[n * 64 + k] = (short)h; Dl[n * 64 + k] = (short)f2bf(d - bf2f(h));
  h = f2bf(vv);
  Vh[n * 64 + k] = (short)h; Vl[n * 64 + k] = (short)f2bf(vv - bf2f(h));
}

// ---------------- conv1 node tables ----------------
__global__ void mk_conv1nodes(const float* __restrict__ pos, const float* __restrict__ W1,
                              const float* __restrict__ b1, float* __restrict__ Pp,
                              float* __restrict__ Qn) {
  int g = blockIdx.x * 256 + threadIdx.x;
  if (g >= 8192 * 64) return;
  int i = g >> 6, c = g & 63;
  float p0 = pos[i * 3], p1 = pos[i * 3 + 1], p2 = pos[i * 3 + 2];
  float q = p0 * W1[192 + c] + p1 * W1[256 + c] + p2 * W1[320 + c];
  Qn[g] = q;
  Pp[g] = p0 * W1[c] + p1 * W1[64 + c] + p2 * W1[128 + c] - q + b1[c];
}

__global__ __launch_bounds__(256)
void mk_stats1(const float* __restrict__ Pp, const float* __restrict__ Qn,
               const int* __restrict__ idx1, float* __restrict__ statsP) {
  __shared__ int sidx[512];
  int tid = threadIdx.x;
  int c = tid & 63, grp = tid >> 6;
  int nb = blockIdx.x * 16;
  if (tid < 256) {
    sidx[tid] = idx1[nb * 32 + tid];
    sidx[tid + 256] = idx1[nb * 32 + 256 + tid];
  }
  __syncthreads();
  float s = 0.f, q = 0.f;
  for (int ln = 0; ln < 16; ++ln) {
    float pv = Pp[(size_t)(nb + ln) * 64 + c];
    for (int e = grp; e < 32; e += 4) {
      int j = sidx[ln * 32 + e];
      float v = fmaxf(pv + Qn[(size_t)j * 64 + c], 0.f);
      s += v; q = fmaf(v, v, q);
    }
  }
  int slot = (blockIdx.x * 4 + grp) & 63;
  atomicAdd(&statsP[(size_t)slot * 1024 + c], s);
  atomicAdd(&statsP[(size_t)slot * 1024 + 512 + c], q);
}

__global__ __launch_bounds__(128)
void mk_econv2(const float* __restrict__ R, const float* __restrict__ T,
               const int* __restrict__ st_i, float* __restrict__ mxp,
               float* __restrict__ mnp, float* __restrict__ statsP) {
  __shared__ int sidx[256];
  int tid = threadIdx.x;
  int nb = blockIdx.x * 8;
  sidx[tid] = st_i[nb * 32 + tid];
  sidx[tid + 128] = st_i[nb * 32 + 128 + tid];
  __syncthreads();
  float s = 0.f, q = 0.f;
  for (int ln = 0; ln < 8; ++ln) {
    int i = nb + ln;
    float rv = R[(size_t)i * 128 + tid];
    float mx = -3.4e38f, mn = 3.4e38f;
    for (int e = 0; e < 32; ++e) {
      int j = sidx[ln * 32 + e];
      float v = fmaxf(rv + T[(size_t)j * 128 + tid], 0.f);
      mx = fmaxf(mx, v); mn = fminf(mn, v);
      s += v; q = fmaf(v, v, q);
    }
    mxp[(size_t)i * 128 + tid] = mx;
    mnp[(size_t)i * 128 + tid] = mn;
  }
  int slot = blockIdx.x & 63;
  atomicAdd(&statsP[(size_t)slot * 1024 + tid], s);
  atomicAdd(&statsP[(size_t)slot * 1024 + 512 + tid], q);
}

// slot stats (sum @ +0, sq @ +512 per 1024-slot) -> coef (a @ +0, b @ +1024)
__global__ void mk_bnfinS(const float* __restrict__ sb, const float* __restrict__ g,
                          const float* __restrict__ beta, float* __restrict__ bno,
                          float Minv, int Cdim) {
  int c = blockIdx.x * 256 + threadIdx.x;
  if (c >= Cdim) return;
  float s = 0.f, q = 0.f;
  for (int sl = 0; sl < 64; ++sl) {
    s += sb[(size_t)sl * 1024 + c];
    q += sb[(size_t)sl * 1024 + 512 + c];
  }
  float mu = s * Minv;
  float var = q * Minv - mu * mu;
  float a = g[c] * rsqrtf(var + BN_EPS);
  bno[c] = a;
  bno[1024 + c] = beta[c] - a * mu;
}

__global__ void mk_finx1(const float* __restrict__ mx, const float* __restrict__ mn,
                         const float* __restrict__ bn, float* __restrict__ xc,
                         short* __restrict__ x1h, short* __restrict__ x1l) {
  int g = blockIdx.x * 256 + threadIdx.x;
  if (g >= 8192 * 64) return;
  int i = g >> 6, c = g & 63;
  float a = bn[c], b = bn[1024 + c];
  float v = (a > 0.f) ? fmaf(a, mx[g], b) : fmaf(a, mn[g], b);
  xc[(size_t)i * 192 + c] = v;
  unsigned short h = f2bf(v);
  x1h[g] = (short)h;
  x1l[g] = (short)f2bf(v - bf2f(h));
}
__global__ void mk_finx2(const float* __restrict__ mx, const float* __restrict__ mn,
                         const float* __restrict__ bn, float* __restrict__ xcB) {
  int g = blockIdx.x * 256 + threadIdx.x;
  if (g >= 8192 * 128) return;
  int i = g >> 7, c = g & 127;
  float a = bn[c], b = bn[1024 + c];
  xcB[(size_t)i * 192 + c] = (a > 0.f) ? fmaf(a, mx[g], b) : fmaf(a, mn[g], b);
}

// ---------------- kNN: chunk-min threshold select (exact) ----------------
__global__ void mk_posq(const float* __restrict__ pos, float4* __restrict__ posq) {
  int i = blockIdx.x * 256 + threadIdx.x;
  if (i >= 8192) return;
  float x = pos[i * 3], y = pos[i * 3 + 1], z = pos[i * 3 + 2];
  float s = fmaf(z, z, fmaf(y, y, x * x));
  posq[i] = make_float4(x, y, z, s);
}

// per-wave 8th-smallest of 64 lane values via ballot binary search (constant k=8)
__device__ __forceinline__ unsigned wave_kth8(unsigned v) {
  unsigned T = 0;
#pragma unroll
  for (int b = 31; b >= 0; --b) {
    unsigned cand = T | (1u << b);
    int c = __popcll(__ballot(v < cand));
    if (c < 8) T = cand;
  }
  return T;
}

__global__ __launch_bounds__(256)
void mk_knn1(const float4* __restrict__ posq, int* __restrict__ idxout) {
  __shared__ ull buf[K1CAP];
  __shared__ unsigned Tw[4];
  __shared__ unsigned cnt;
  int q = blockIdx.x, tid = threadIdx.x;
  int lane = tid & 63, wid = tid >> 6;
  float4 pq = posq[q];
  if (tid == 0) cnt = 0;
  unsigned key[32];
  unsigned vmin = 0xFFFFFFFFu;
#pragma unroll
  for (int c = 0; c < 32; ++c) {
    int j = c * 256 + tid;
    float4 pj = posq[j];
    float d = pq.w + pj.w - 2.f * (pq.x * pj.x + pq.y * pj.y + pq.z * pj.z);
    unsigned k = (j == q) ? 0xFFFFFFFFu : ordf(d);
    key[c] = k;
    vmin = vmin < k ? vmin : k;
  }
  unsigned T = wave_kth8(vmin);
  if (lane == 0) Tw[wid] = T;
  __syncthreads();
  unsigned Tmax = max(max(Tw[0], Tw[1]), max(Tw[2], Tw[3]));
#pragma unroll
  for (int c = 0; c < 32; ++c) {
    if (key[c] <= Tmax) {
      int j = c * 256 + tid;
      unsigned s = atomicAdd(&cnt, 1u);
      if (s < K1CAP) buf[s] = (((ull)key[c]) << 32) | (unsigned)j;
    }
  }
  __syncthreads();
  int m = cnt < (unsigned)K1CAP ? (int)cnt : K1CAP;
  for (int e = tid; e < m; e += 256) {
    ull mine = buf[e];
    int rank = 0;
    for (int f = 0; f < m; ++f) rank += (buf[f] < mine) ? 1 : 0;
    if (rank < 32) idxout[q * 32 + rank] = (int)(unsigned)(mine & 0xFFFFFFFFu);
  }
}

// knn2: reads precomputed u32 key matrix Kb[q][0..4095] (diag already ~0)
__global__ __launch_bounds__(256)
void mk_knn2(const unsigned* __restrict__ Kb, int c0, int first,
             unsigned* __restrict__ st_k, int* __restrict__ st_i) {
  __shared__ ull buf[K2CAP];
  __shared__ unsigned Tw[4];
  __shared__ unsigned cnt;
  int q = blockIdx.x, tid = threadIdx.x;
  int lane = tid & 63, wid = tid >> 6;
  if (tid == 0) cnt = 0;
  unsigned key[16];
  unsigned vmin = 0xFFFFFFFFu;
#pragma unroll
  for (int c = 0; c < 16; ++c) {
    unsigned k = Kb[(size_t)q * 4096 + c * 256 + tid];
    key[c] = k;
    vmin = vmin < k ? vmin : k;
  }
  unsigned T = wave_kth8(vmin);
  if (lane == 0) Tw[wid] = T;
  __syncthreads();
  unsigned Tmax = max(max(Tw[0], Tw[1]), max(Tw[2], Tw[3]));
#pragma unroll
  for (int c = 0; c < 16; ++c) {
    if (key[c] <= Tmax) {
      int j = c0 + c * 256 + tid;
      unsigned s = atomicAdd(&cnt, 1u);
      if (s < K2CAP) buf[s] = (((ull)key[c]) << 32) | (unsigned)j;
    }
  }
  if (!first && tid < 32) {
    ull k = (((ull)st_k[q * 32 + tid]) << 32) | (unsigned)st_i[q * 32 + tid];
    unsigned s = atomicAdd(&cnt, 1u);
    if (s < K2CAP) buf[s] = k;
  }
  __syncthreads();
  int m = cnt < (unsigned)K2CAP ? (int)cnt : K2CAP;
  for (int e = tid; e < m; e += 256) {
    ull mine = buf[e];
    int rank = 0;
    for (int f = 0; f < m; ++f) rank += (buf[f] < mine) ? 1 : 0;
    if (rank < 32) {
      st_k[q * 32 + rank] = (unsigned)(mine >> 32);
      st_i[q * 32 + rank] = (int)(unsigned)(mine & 0xFFFFFFFFu);
    }
  }
}

// ---------------- fp32 GEMM (tag1, K=16) ----------------
#define GBM 64
#define GBN 64
#define GBK 16

__global__ __launch_bounds__(256)
void mk_gemm(const float* __restrict__ A, const float* __restrict__ W, int ldw,
             const float* __restrict__ bias, float* __restrict__ C, int ldc,
             int M, int N, int K, int flags) {
  __shared__ float As[GBK][GBM + 4];
  __shared__ float Ws[GBK][GBN];
  int tid = threadIdx.x;
  int r0 = blockIdx.x * GBM, n0 = blockIdx.y * GBN;
  int ty = tid >> 4, tx = tid & 15;
  float acc[4][4] = {};
  for (int kt = 0; kt < K; kt += GBK) {
#pragma unroll
    for (int it = 0; it < 4; ++it) {
      int l = it * 256 + tid;
      int r = l >> 4, kk = l & 15;
      int gr = r0 + r, gk = kt + kk;
      float v = 0.f;
      if (gk < K && gr < M) v = A[(size_t)gr * K + gk];
      As[kk][r] = v;
      int kw = l >> 6, nw = l & 63;
      int gkw = kt + kw;
      Ws[kw][nw] = (gkw < K && (n0 + nw) < N) ? W[(size_t)gkw * ldw + n0 + nw] : 0.f;
    }
    __syncthreads();
#pragma unroll
    for (int kk = 0; kk < GBK; ++kk) {
      float4 a4 = *(const float4*)&As[kk][ty * 4];
      float4 b4 = *(const float4*)&Ws[kk][tx * 4];
      float av[4] = {a4.x, a4.y, a4.z, a4.w};
      float bv[4] = {b4.x, b4.y, b4.z, b4.w};
#pragma unroll
      for (int i = 0; i < 4; ++i)
#pragma unroll
        for (int j = 0; j < 4; ++j)
          acc[i][j] = fmaf(av[i], bv[j], acc[i][j]);
    }
    __syncthreads();
  }
#pragma unroll
  for (int i = 0; i < 4; ++i) {
    int gr = r0 + ty * 4 + i;
    if (gr >= M) continue;
#pragma unroll
    for (int j = 0; j < 4; ++j) {
      int gc = n0 + tx * 4 + j;
      if (gc >= N) continue;
      float v = acc[i][j];
      if (bias) v += bias[gc];
      if (flags & 1) v += C[(size_t)gr * ldc + gc];
      if (flags & 2) v = fmaxf(v, 0.f);
      C[(size_t)gr * ldc + gc] = v;
    }
  }
}

// ---------------- small utility kernels ----------------
__global__ void mk_sqnorm(const float* __restrict__ x, int ld, float* __restrict__ sq,
                          int Npts, int Cdim) {
  int i = blockIdx.x * blockDim.x + threadIdx.x;
  if (i >= Npts) return;
  float s = 0.f;
  for (int c = 0; c < Cdim; ++c) { float v = x[(size_t)i * ld + c]; s = fmaf(v, v, s); }
  sq[i] = s;
}

// ---------------- CSR build + props ----------------
__global__ void mk_count(const int* __restrict__ col, int* __restrict__ cnt, int E) {
  int e = blockIdx.x * 256 + threadIdx.x;
  if (e < E) atomicAdd(&cnt[col[e]], 1);
}
__global__ __launch_bounds__(1024)
void mk_scan(const int* __restrict__ cnt, int* __restrict__ offp,
             int* __restrict__ cur, float* __restrict__ dinvf) {
  __shared__ int wsum[16];
  __shared__ int wexc[16];
  int t = threadIdx.x, lane = t & 63, w = t >> 6;
  int v[8]; int s = 0;
  int base = t * 8;
#pragma unroll
  for (int k = 0; k < 8; ++k) { v[k] = s; s += cnt[base + k]; }
  int sc = s;
#pragma unroll
  for (int off2 = 1; off2 < 64; off2 <<= 1) {
    int n = __shfl_up(sc, off2, 64);
    if (lane >= off2) sc += n;
  }
  if (lane == 63) wsum[w] = sc;
  __syncthreads();
  if (w == 0) {
    int x = (lane < 16) ? wsum[lane] : 0;
    int scx = x;
#pragma unroll
    for (int off2 = 1; off2 < 16; off2 <<= 1) {
      int n = __shfl_up(scx, off2, 64);
      if (lane >= off2) scx += n;
    }
    if (lane < 16) wexc[lane] = scx - x;
  }
  __syncthreads();
  int texc = wexc[w] + (sc - s);
#pragma unroll
  for (int k = 0; k < 8; ++k) {
    int o = texc + v[k];
    offp[base + k] = o;
    cur[base + k] = o;
    int d = cnt[base + k];
    dinvf[base + k] = (d > 0) ? rsqrtf((float)(d < 1 ? 1 : d)) : 0.f;
  }
  if (t == 1023) offp[8192] = texc + s;
}
__global__ void mk_fill(const int* __restrict__ row, const int* __restrict__ col,
                        const float* __restrict__ dinvf, int* __restrict__ cur,
                        int* __restrict__ crow, float* __restrict__ cw, int E) {
  int e = blockIdx.x * 256 + threadIdx.x;
  if (e >= E) return;
  int c = col[e], r = row[e];
  int s = atomicAdd(&cur[c], 1);
  crow[s] = r;
  cw[s] = dinvf[r] * dinvf[c];
}
__global__ void mk_prop64(const float* __restrict__ in, int in_ld,
                          const int* __restrict__ offp, const int* __restrict__ crow,
                          const float* __restrict__ cw, float* __restrict__ out, int out_ld) {
  int gid = blockIdx.x * 256 + threadIdx.x;
  if (gid >= 8192 * 16) return;
  int col = gid >> 4, c4 = (gid & 15) * 4;
  int s0 = offp[col], s1 = offp[col + 1];
  float a0 = 0, a1 = 0, a2 = 0, a3 = 0;
  for (int s = s0; s < s1; ++s) {
    int r = crow[s]; float w = cw[s];
    float4 v = *(const float4*)&in[(size_t)r * in_ld + c4];
    a0 = fmaf(w, v.x, a0); a1 = fmaf(w, v.y, a1);
    a2 = fmaf(w, v.z, a2); a3 = fmaf(w, v.w, a3);
  }
  float4 o = {a0, a1, a2, a3};
  *(float4*)&out[(size_t)col * out_ld + c4] = o;
}
__global__ void mk_prop4(const float* __restrict__ in, int in_ld,
                         const int* __restrict__ offp, const int* __restrict__ crow,
                         const float* __restrict__ cw, float* __restrict__ out, int out_ld) {
  int col = blockIdx.x * 256 + threadIdx.x;
  if (col >= 8192) return;
  int s0 = offp[col], s1 = offp[col + 1];
  float a0 = 0, a1 = 0, a2 = 0, a3 = 0;
  for (int s = s0; s < s1; ++s) {
    int r = crow[s]; float w = cw[s];
    float4 v = *(const float4*)&in[(size_t)r * in_ld];
    a0 = fmaf(w, v.x, a0); a1 = fmaf(w, v.y, a1);
    a2 = fmaf(w, v.z, a2); a3 = fmaf(w, v.w, a3);
  }
  float4 o = {a0, a1, a2, a3};
  *(float4*)&out[(size_t)col * out_ld] = o;
}
__global__ void mk_pack4(const float* __restrict__ xin, float* __restrict__ H1) {
  int g = blockIdx.x * 256 + threadIdx.x;
  if (g >= 8192 * 4) return;
  H1[(size_t)(g >> 2) * 16 + (g & 3)] = xin[g];
}
__global__ void mk_copy64(const float* __restrict__ gcv, float* __restrict__ H2) {
  int g = blockIdx.x * 256 + threadIdx.x;
  if (g >= 8192 * 64) return;
  H2[(size_t)(g >> 6) * 256 + (g & 63)] = gcv[(size_t)(g >> 6) * 192 + (g & 63)];
}

__global__ __launch_bounds__(256)
void mk_gemv_out(const float* __restrict__ h, const float* __restrict__ bn,
                 const float* __restrict__ w, const float* __restrict__ b,
                 float* __restrict__ out, int Npts) {
  int row = blockIdx.x * 4 + (threadIdx.x >> 6);
  int lane = threadIdx.x & 63;
  if (row >= Npts) return;
  int c = lane * 4;
  float4 v = *(const float4*)&h[(size_t)row * 256 + c];
  float s = (bn[c] * v.x + bn[1024 + c]) * w[c]
          + (bn[c + 1] * v.y + bn[1024 + c + 1]) * w[c + 1]
          + (bn[c + 2] * v.z + bn[1024 + c + 2]) * w[c + 2]
          + (bn[c + 3] * v.w + bn[1024 + c + 3]) * w[c + 3];
#pragma unroll
  for (int off = 32; off; off >>= 1) s += __shfl_xor(s, off, 64);
  if (lane == 0) out[row] = s + b[0];
}

// ---------------- host ----------------
extern "C" void kernel_launch(void* const* d_in, const int* in_sizes, int n_in,
                              void* d_out, int out_size, void* d_ws, size_t ws_size,
                              hipStream_t stream) {
  const int N = 8192;
  const int NE = N * 32;
  const float* pos = (const float*)d_in[0];
  const float* xin = (const float*)d_in[1];
  const int* ei = (const int*)d_in[2];
  const int E = in_sizes[2] / 2;
  const int* erow = ei;
  const int* ecol = ei + E;
  const float* mlp1_W1  = (const float*)d_in[3];
  const float* mlp1_W23 = (const float*)d_in[4];
  const float* mlp1_b   = (const float*)d_in[5];
  const float* mlp1_g   = (const float*)d_in[6];
  const float* mlp1_be  = (const float*)d_in[7];
  const float* mlp2_W   = (const float*)d_in[8];
  const float* mlp2_b   = (const float*)d_in[9];
  const float* mlp2_g   = (const float*)d_in[10];
  const float* mlp2_be  = (const float*)d_in[11];
  const float* lin1_W   = (const float*)d_in[12];
  const float* lin1_b   = (const float*)d_in[13];
  const float* lin1_g   = (const float*)d_in[14];
  const float* lin1_be  = (const float*)d_in[15];
  const float* tag1_W   = (const float*)d_in[16];
  const float* tag1_b   = (const float*)d_in[17];
  const float* tag2_W   = (const float*)d_in[18];
  const float* tag2_b   = (const float*)d_in[19];
  const float* lin2_W   = (const float*)d_in[20];
  const float* lin2_b   = (const float*)d_in[21];
  const float* lin2_g   = (const float*)d_in[22];
  const float* lin2_be  = (const float*)d_in[23];
  const float* mix1_W   = (const float*)d_in[24];
  const float* mix1_b   = (const float*)d_in[25];
  const float* mix1_g   = (const float*)d_in[26];
  const float* mix1_be  = (const float*)d_in[27];
  const float* mix2_W   = (const float*)d_in[28];
  const float* mix2_b   = (const float*)d_in[29];
  const float* mix2_g   = (const float*)d_in[30];
  const float* mix2_be  = (const float*)d_in[31];
  const float* outW     = (const float*)d_in[32];
  const float* outB     = (const float*)d_in[33];

  char* base = (char*)d_ws;
  size_t off = 0;
  auto alloc = [&](size_t b) -> void* {
    void* p = base + off;
    off += (b + 255) & ~(size_t)255;
    return p;
  };
  float* BIG = (float*)alloc(134217728ull);   // 128 MB phase-shared
  short* h2_h  = (short*)BIG;                            // conv1 L2 out hi (32 MB)
  short* h2_l  = (short*)((char*)BIG + 33554432);        // lo (32 MB)
  unsigned* Kb = (unsigned*)BIG;                         // knn2 key matrix [8192][4096] (128 MB)
  short* mhcat_h = (short*)BIG;                          // [8192][1024] hi (16 MB)
  short* mhcat_l = (short*)((char*)BIG + 16777216);      // lo (16 MB)
  short* mh1_h   = (short*)((char*)BIG + 33554432);      // [8192][512] hi (8 MB)
  short* mh1_l   = (short*)((char*)BIG + 41943040);      // lo (8 MB)
  float* mh2     = (float*)((char*)BIG + 50331648);      // [8192][256] fp32 (8 MB)
  float* H2      = BIG + 16777216;                       // byte 64M+: tag2 hop-concat
  int*   idx1 = (int*)alloc((size_t)NE * 4);
  unsigned* st_k = (unsigned*)alloc((size_t)NE * 4);
  int*   st_i = (int*)alloc((size_t)NE * 4);
  float* xc  = (float*)alloc((size_t)N * 192 * 4);   // [x1 | x2]
  float* gc  = (float*)alloc((size_t)N * 192 * 4);   // [g1 | g2]
  float4* posq = (float4*)alloc((size_t)N * 16);
  float* sqx = (float*)alloc((size_t)N * 4);
  float* Pp  = (float*)alloc((size_t)N * 64 * 4);
  float* Qn  = (float*)alloc((size_t)N * 64 * 4);
  float* Rb  = (float*)alloc((size_t)N * 128 * 4);
  float* Tb  = (float*)alloc((size_t)N * 128 * 4);
  float* mx1 = (float*)alloc((size_t)N * 64 * 4);
  float* mn1 = (float*)alloc((size_t)N * 64 * 4);
  float* mx2 = (float*)alloc((size_t)N * 128 * 4);
  float* mn2 = (float*)alloc((size_t)N * 128 * 4);
  float* H1  = (float*)alloc((size_t)N * 16 * 4);
  float* dinvf = (float*)alloc((size_t)N * 4);
  int* cnt     = (int*)alloc((size_t)N * 4);
  int* csr_off = (int*)alloc((size_t)(N + 1) * 4);
  int* cursor  = (int*)alloc((size_t)N * 4);
  int* csr_row = (int*)alloc((size_t)E * 4);
  float* csr_w = (float*)alloc((size_t)E * 4);
  float* slotAll = (float*)alloc((size_t)8 * 64 * 1024 * 4);
  auto slot = [&](int i) { return slotAll + (size_t)i * 64 * 1024; };
  float* bnb = (float*)alloc(8 * 2048 * 4);           // coef: a @ +0, b @ +1024
  auto bnp = [&](int i) { return bnb + (size_t)i * 2048; };
  float* bnM = bnp(4);                                // lin1 a cols 0-511, lin2 at +512
  float* bias1f = (float*)alloc(512 * 4);
  float* bias2f = (float*)alloc(256 * 4);
  float* biasA  = (float*)alloc(64 * 4);
  float* biasB  = (float*)alloc(64 * 4);
  auto salloc = [&](size_t n) { return (short*)alloc(n * 2); };
  short* w23a_h = salloc(4096);   short* w23a_l = salloc(4096);
  short* w23b_h = salloc(4096);   short* w23b_l = salloc(4096);
  short* wd2_h  = salloc(8192);   short* wd2_l  = salloc(8192);
  short* wv2_h  = salloc(8192);   short* wv2_l  = salloc(8192);
  short* wl1_h  = salloc(98304);  short* wl1_l  = salloc(98304);
  short* wt2_h  = salloc(32768);  short* wt2_l  = salloc(32768);
  short* wl2_h  = salloc(98304);  short* wl2_l  = salloc(98304);
  short* wx1_h  = salloc(524288); short* wx1_l  = salloc(524288);
  short* wx2_h  = salloc(131072); short* wx2_l  = salloc(131072);
  short* x1h    = salloc(524288); short* x1l    = salloc(524288);

  auto gemmF = [&](const float* A, const short* A8h, const short* A8l,
                   const float* src, const int* gidx, int srcC, const float* bnA,
                   const short* Wh_, const short* Wl_, int ldk, int koff, int lda,
                   const float* bias, float* Cp, short* Chp, short* Clp, int ldc,
                   int M, int Nn, int Kk, int flags,
                   float* stP = nullptr, float* mxP = nullptr, float* mnP = nullptr) {
    dim3 g(M / 64, Nn / 64);
    mk_gemm_mfma<<<g, 256, 0, stream>>>(A, A8h, A8l, src, gidx, srcC, bnA,
                                        Wh_, Wl_, ldk, koff, lda, bias, Cp, Chp, Clp, ldc,
                                        M, Nn, Kk, flags, stP, mxP, mnP);
  };
  auto wcvt = [&](const float* W, short* Wh_, short* Wl_, int Kk, int Nn) {
    mk_wcvt<<<(Kk * Nn + 255) / 256, 256, 0, stream>>>(W, Wh_, Wl_, Kk, Nn);
  };

  // ---- init + weight conversion ----
  hipMemsetAsync(slotAll, 0, (size_t)8 * 64 * 1024 * 4, stream);
  hipMemsetAsync(cnt, 0, (size_t)N * 4, stream);
  mk_wcvt2<<<(64 * 128 + 255) / 256, 256, 0, stream>>>(mlp2_W, wd2_h, wd2_l, wv2_h, wv2_l);
  wcvt(lin1_W, wl1_h, wl1_l, 192, 512);
  wcvt(tag2_W, wt2_h, wt2_l, 256, 128);
  wcvt(lin2_W, wl2_h, wl2_l, 192, 512);

  // ---- kNN-1 on pos ----
  mk_posq<<<32, 256, 0, stream>>>(pos, posq);
  mk_knn1<<<N, 256, 0, stream>>>(posq, idx1);

  // ---- conv1 ----
  mk_conv1nodes<<<(N * 64 + 255) / 256, 256, 0, stream>>>(pos, mlp1_W1, mlp1_b, Pp, Qn);
  mk_stats1<<<512, 256, 0, stream>>>(Pp, Qn, idx1, slot(0));
  mk_bnfinS<<<1, 256, 0, stream>>>(slot(0), mlp1_g, mlp1_be, bnp(0), 1.f / NE, 64);
  mk_wcvts<<<(64 * 64 + 255) / 256, 256, 0, stream>>>(mlp1_W23, bnp(0), w23a_h, w23a_l, 64, 64);
  mk_biasfold<<<16, 256, 0, stream>>>(mlp1_W23, bnp(0) + 1024, mlp1_b + 64, biasA, 64, 64);
  gemmF(Pp, nullptr, nullptr, Qn, idx1, 64, nullptr,
        w23a_h, w23a_l, 64, 0, 64, biasA, nullptr, h2_h, h2_l, 64,
        NE, 64, 64, 2 | 8 | 32 | 64, slot(1));
  mk_bnfinS<<<1, 256, 0, stream>>>(slot(1), mlp1_g + 64, mlp1_be + 64, bnp(1), 1.f / NE, 64);
  mk_wcvts<<<(64 * 64 + 255) / 256, 256, 0, stream>>>(mlp1_W23 + 4096, bnp(1), w23b_h, w23b_l, 64, 64);
  mk_biasfold<<<16, 256, 0, stream>>>(mlp1_W23 + 4096, bnp(1) + 1024, mlp1_b + 128, biasB, 64, 64);
  gemmF(nullptr, h2_h, h2_l, nullptr, nullptr, 0, nullptr,
        w23b_h, w23b_l, 64, 0, 64, biasB, nullptr, nullptr, nullptr, 64,
        NE, 64, 64, 2 | 8 | 16, slot(2), mx1, mn1);
  mk_bnfinS<<<1, 256, 0, stream>>>(slot(2), mlp1_g + 128, mlp1_be + 128, bnp(2), 1.f / NE, 64);
  mk_finx1<<<(N * 64 + 255) / 256, 256, 0, stream>>>(mx1, mn1, bnp(2), xc, x1h, x1l);

  // ---- kNN-2 on x1: 2 chunks of 4096, keys computed in GEMM epilogue ----
  mk_sqnorm<<<32, 256, 0, stream>>>(xc, 192, sqx, N, 64);
  for (int c = 0; c < 2; ++c) {
    gemmF(nullptr, x1h, x1l, sqx, nullptr, c * 4096, nullptr,
          x1h + (size_t)c * 4096 * 64, x1l + (size_t)c * 4096 * 64, 64, 0, 64,
          nullptr, (float*)Kb, nullptr, nullptr, 4096, N, 4096, 64, 128);
    mk_knn2<<<N, 256, 0, stream>>>(Kb, c * 4096, c == 0 ? 1 : 0, st_k, st_i);
  }

  // ---- conv2 ----
  gemmF(nullptr, x1h, x1l, nullptr, nullptr, 0, nullptr,
        wd2_h, wd2_l, 64, 0, 64, mlp2_b, Rb, nullptr, nullptr, 128, N, 128, 64, 0);
  gemmF(nullptr, x1h, x1l, nullptr, nullptr, 0, nullptr,
        wv2_h, wv2_l, 64, 0, 64, nullptr, Tb, nullptr, nullptr, 128, N, 128, 64, 0);
  mk_econv2<<<N / 8, 128, 0, stream>>>(Rb, Tb, st_i, mx2, mn2, slot(3));
  mk_bnfinS<<<1, 256, 0, stream>>>(slot(3), mlp2_g, mlp2_be, bnp(3), 1.f / NE, 128);
  mk_finx2<<<(N * 128 + 255) / 256, 256, 0, stream>>>(mx2, mn2, bnp(3), xc + 64);

  // ---- lin1: K=192 GEMM -> mhcat (bf16 hi/lo) cols 0-511 ----
  gemmF(xc, nullptr, nullptr, nullptr, nullptr, 0, nullptr,
        wl1_h, wl1_l, 192, 0, 192, lin1_b, nullptr, mhcat_h, mhcat_l, 1024,
        N, 512, 192, 2 | 8 | 64, slot(4));
  mk_bnfinS<<<2, 256, 0, stream>>>(slot(4), lin1_g, lin1_be, bnM, 1.f / N, 512);

  // ---- TAG branch: CSR ----
  mk_count<<<(E + 255) / 256, 256, 0, stream>>>(ecol, cnt, E);
  mk_scan<<<1, 1024, 0, stream>>>(cnt, csr_off, cursor, dinvf);
  mk_fill<<<(E + 255) / 256, 256, 0, stream>>>(erow, ecol, dinvf, cursor, csr_row, csr_w, E);
  // tag1 -> gc cols 0-63
  mk_pack4<<<(N * 4 + 255) / 256, 256, 0, stream>>>(xin, H1);
  mk_prop4<<<32, 256, 0, stream>>>(xin, 4, csr_off, csr_row, csr_w, H1 + 4, 16);
  mk_prop4<<<32, 256, 0, stream>>>(H1 + 4, 16, csr_off, csr_row, csr_w, H1 + 8, 16);
  mk_prop4<<<32, 256, 0, stream>>>(H1 + 8, 16, csr_off, csr_row, csr_w, H1 + 12, 16);
  mk_gemm<<<dim3(128, 1), 256, 0, stream>>>(H1, tag1_W, 64, tag1_b, gc, 192, N, 64, 16, 2);
  // tag2: hop-concat H2 -> one K=256 gemmF -> gc cols 64-191
  mk_copy64<<<(N * 64 + 255) / 256, 256, 0, stream>>>(gc, H2);
  mk_prop64<<<512, 256, 0, stream>>>(gc, 192, csr_off, csr_row, csr_w, H2 + 64, 256);
  mk_prop64<<<512, 256, 0, stream>>>(H2 + 64, 256, csr_off, csr_row, csr_w, H2 + 128, 256);
  mk_prop64<<<512, 256, 0, stream>>>(H2 + 128, 256, csr_off, csr_row, csr_w, H2 + 192, 256);
  gemmF(H2, nullptr, nullptr, nullptr, nullptr, 0, nullptr,
        wt2_h, wt2_l, 256, 0, 256, tag2_b, gc + 64, nullptr, nullptr, 192,
        N, 128, 256, 2);
  // lin2: K=192 GEMM -> mhcat (bf16 hi/lo) cols 512-1023
  gemmF(gc, nullptr, nullptr, nullptr, nullptr, 0, nullptr,
        wl2_h, wl2_l, 192, 0, 192, lin2_b, nullptr, mhcat_h + 512, mhcat_l + 512, 1024,
        N, 512, 192, 2 | 8 | 64, slot(5));
  mk_bnfinS<<<2, 256, 0, stream>>>(slot(5), lin2_g, lin2_be, bnM + 512, 1.f / N, 512);

  // ---- fold lin BN into mix1 weights; mix head on fast A8 path ----
  mk_wcvts<<<(1024 * 512 + 255) / 256, 256, 0, stream>>>(mix1_W, bnM, wx1_h, wx1_l, 1024, 512);
  mk_biasfold<<<128, 256, 0, stream>>>(mix1_W, bnM + 1024, mix1_b, bias1f, 1024, 512);
  gemmF(nullptr, mhcat_h, mhcat_l, nullptr, nullptr, 0, nullptr,
        wx1_h, wx1_l, 1024, 0, 1024, bias1f, nullptr, mh1_h, mh1_l, 512,
        N, 512, 1024, 2 | 8 | 64, slot(6));
  mk_bnfinS<<<2, 256, 0, stream>>>(slot(6), mix1_g, mix1_be, bnp(6), 1.f / N, 512);
  mk_wcvts<<<(512 * 256 + 255) / 256, 256, 0, stream>>>(mix2_W, bnp(6), wx2_h, wx2_l, 512, 256);
  mk_biasfold<<<64, 256, 0, stream>>>(mix2_W, bnp(6) + 1024, mix2_b, bias2f, 512, 256);
  gemmF(nullptr, mh1_h, mh1_l, nullptr, nullptr, 0, nullptr,
        wx2_h, wx2_l, 512, 0, 512, bias2f, mh2, nullptr, nullptr, 256,
        N, 256, 512, 2 | 8, slot(7));
  mk_bnfinS<<<1, 256, 0, stream>>>(slot(7), mix2_g, mix2_be, bnp(7), 1.f / N, 256);
  mk_gemv_out<<<N / 4, 256, 0, stream>>>(mh2, bnp(7), outW, outB, (float*)d_out, N);
}

// Round 21
// 638.876 us; speedup vs baseline: 1.2392x; 1.0745x over previous
//
#include <hip/hip_runtime.h>
#include <cstdint>
#include <cstddef>

#define BN_EPS 1e-5f
#define K1CAP 1024
#define K2CAP 640

typedef short short8 __attribute__((ext_vector_type(8)));
typedef float f32x4 __attribute__((ext_vector_type(4)));
typedef unsigned long long ull;

// ---------------- helpers ----------------
__device__ __forceinline__ unsigned int ordf(float d) {
  unsigned int u = __float_as_uint(d);
  return (u >> 31) ? ~u : (u | 0x80000000u);
}
__device__ __forceinline__ unsigned short f2bf(float f) {
  unsigned u = __float_as_uint(f);
  u += 0x7fffu + ((u >> 16) & 1u);
  return (unsigned short)(u >> 16);
}
__device__ __forceinline__ float bf2f(unsigned short h) {
  return __uint_as_float(((unsigned)h) << 16);
}

// ---------------- MFMA bf16x3 GEMM (K_STEP=64, reg-staged pipeline) ----------------
// flags: 1=ACC, 2=RELU, 8=stats epilogue (slotted), 16=maxmin epilogue (NO C
// write), 32=EDGE1-A (v=relu(A[i][k]+src[j][k])), 64=BF16OUT (write Ch/Cl),
// 128=KEYOUT (unused now; see mk_keyS).
// A-source priority: A8h/A8l (bf16 hi/lo [M][lda]) -> flags&32 -> fp32 A [M][lda]
// (+optional bnA affine: bnA[k]*v + bnA[1024+k]). W: bf16 hi/lo n-major
// [N][ldk], k index = koff+k. Requires M%64==0, N%64==0, K%64==0.
#define BPAD 72

__global__ __launch_bounds__(256)
void mk_gemm_mfma(const float* __restrict__ A,
                  const short* __restrict__ A8h, const short* __restrict__ A8l,
                  const float* __restrict__ src, const int* __restrict__ gidx, int srcC,
                  const float* __restrict__ bnA,
                  const short* __restrict__ Wh, const short* __restrict__ Wl,
                  int ldk, int koff, int lda,
                  const float* __restrict__ bias,
                  float* __restrict__ C, short* __restrict__ Ch, short* __restrict__ Cl,
                  int ldc,
                  int M, int N, int K, int flags,
                  float* __restrict__ statsP,
                  float* __restrict__ mxp, float* __restrict__ mnp) {
  __shared__ short Ah[64][BPAD], Al[64][BPAD], Bh[64][BPAD], Bl[64][BPAD];
  __shared__ float ssum[64], ssq[64];
  int tid = threadIdx.x, lane = tid & 63, wid = tid >> 6;
  int wr = wid >> 1, wc = wid & 1;
  int r0 = blockIdx.x * 64, n0 = blockIdx.y * 64;
  int sr = tid >> 2, sc = (tid & 3) * 16;
  f32x4 zero4 = {0.f, 0.f, 0.f, 0.f};
  f32x4 acc[2][2] = {{zero4, zero4}, {zero4, zero4}};
  short8 rAh[2], rAl[2], rBh[2], rBl[2];

  auto stage = [&](int kt) {
    const short* bh = &Wh[(size_t)(n0 + sr) * ldk + koff + kt + sc];
    const short* bl = &Wl[(size_t)(n0 + sr) * ldk + koff + kt + sc];
    rBh[0] = *(const short8*)bh; rBh[1] = *(const short8*)(bh + 8);
    rBl[0] = *(const short8*)bl; rBl[1] = *(const short8*)(bl + 8);
    if (A8h) {
      const short* ah = &A8h[(size_t)(r0 + sr) * lda + kt + sc];
      const short* al = &A8l[(size_t)(r0 + sr) * lda + kt + sc];
      rAh[0] = *(const short8*)ah; rAh[1] = *(const short8*)(ah + 8);
      rAl[0] = *(const short8*)al; rAl[1] = *(const short8*)(al + 8);
    } else {
      float v[16];
      if (flags & 32) {
        int gr = r0 + sr;
        int i = gr >> 5; int j = gidx[gr];
        const float* pi = &A[(size_t)i * srcC + kt + sc];
        const float* pj = &src[(size_t)j * srcC + kt + sc];
        float va[16], vb[16];
        *(float4*)&va[0]  = *(const float4*)&pi[0];
        *(float4*)&va[4]  = *(const float4*)&pi[4];
        *(float4*)&va[8]  = *(const float4*)&pi[8];
        *(float4*)&va[12] = *(const float4*)&pi[12];
        *(float4*)&vb[0]  = *(const float4*)&pj[0];
        *(float4*)&vb[4]  = *(const float4*)&pj[4];
        *(float4*)&vb[8]  = *(const float4*)&pj[8];
        *(float4*)&vb[12] = *(const float4*)&pj[12];
#pragma unroll
        for (int e = 0; e < 16; ++e) v[e] = fmaxf(va[e] + vb[e], 0.f);
      } else {
        const float* ap = &A[(size_t)(r0 + sr) * lda + kt + sc];
        *(float4*)&v[0]  = *(const float4*)&ap[0];
        *(float4*)&v[4]  = *(const float4*)&ap[4];
        *(float4*)&v[8]  = *(const float4*)&ap[8];
        *(float4*)&v[12] = *(const float4*)&ap[12];
      }
      if (bnA) {
#pragma unroll
        for (int e = 0; e < 16; ++e) {
          int gk = kt + sc + e;
          v[e] = fmaf(bnA[gk], v[e], bnA[1024 + gk]);
        }
      }
#pragma unroll
      for (int e = 0; e < 16; ++e) {
        unsigned short h = f2bf(v[e]);
        rAh[e >> 3][e & 7] = (short)h;
        rAl[e >> 3][e & 7] = (short)f2bf(v[e] - bf2f(h));
      }
    }
  };

  stage(0);
  for (int kt = 0; kt < K; kt += 64) {
    *(short8*)&Ah[sr][sc]     = rAh[0];
    *(short8*)&Ah[sr][sc + 8] = rAh[1];
    *(short8*)&Al[sr][sc]     = rAl[0];
    *(short8*)&Al[sr][sc + 8] = rAl[1];
    *(short8*)&Bh[sr][sc]     = rBh[0];
    *(short8*)&Bh[sr][sc + 8] = rBh[1];
    *(short8*)&Bl[sr][sc]     = rBl[0];
    *(short8*)&Bl[sr][sc + 8] = rBl[1];
    __syncthreads();
    if (kt + 64 < K) stage(kt + 64);
    int ar = wr * 32 + (lane & 15);
    int br = wc * 32 + (lane & 15);
#pragma unroll
    for (int kk = 0; kk < 2; ++kk) {
      int kof = kk * 32 + (lane >> 4) * 8;
      short8 a_h[2], a_l[2], b_h[2], b_l[2];
#pragma unroll
      for (int t = 0; t < 2; ++t) {
        a_h[t] = *(const short8*)&Ah[ar + t * 16][kof];
        a_l[t] = *(const short8*)&Al[ar + t * 16][kof];
        b_h[t] = *(const short8*)&Bh[br + t * 16][kof];
        b_l[t] = *(const short8*)&Bl[br + t * 16][kof];
      }
#pragma unroll
      for (int mt = 0; mt < 2; ++mt)
#pragma unroll
        for (int nt = 0; nt < 2; ++nt) {
          acc[mt][nt] = __builtin_amdgcn_mfma_f32_16x16x32_bf16(a_h[mt], b_h[nt], acc[mt][nt], 0, 0, 0);
          acc[mt][nt] = __builtin_amdgcn_mfma_f32_16x16x32_bf16(a_h[mt], b_l[nt], acc[mt][nt], 0, 0, 0);
          acc[mt][nt] = __builtin_amdgcn_mfma_f32_16x16x32_bf16(a_l[mt], b_h[nt], acc[mt][nt], 0, 0, 0);
        }
    }
    __syncthreads();
  }
  bool dostat = (flags & 8) != 0, domx = (flags & 16) != 0;
  float lsum[2] = {0.f, 0.f}, lsq[2] = {0.f, 0.f};
  float lmx[2] = {-3.4e38f, -3.4e38f}, lmn[2] = {3.4e38f, 3.4e38f};
#pragma unroll
  for (int nt = 0; nt < 2; ++nt) {
    int gc = n0 + wc * 32 + nt * 16 + (lane & 15);
#pragma unroll
    for (int mt = 0; mt < 2; ++mt)
#pragma unroll
      for (int i = 0; i < 4; ++i) {
        int gr = r0 + wr * 32 + mt * 16 + (lane >> 4) * 4 + i;
        float v = acc[mt][nt][i];
        if (bias) v += bias[gc];
        if (flags & 1) v += C[(size_t)gr * ldc + gc];
        if (flags & 2) v = fmaxf(v, 0.f);
        if (!domx) {
          if (flags & 128) {
            int gj = srcC + gc;
            unsigned kk2 = (gr == gj) ? 0xFFFFFFFFu
                                      : ordf(src[gr] + src[gj] - 2.f * v);
            ((unsigned*)C)[(size_t)gr * ldc + gc] = kk2;
          } else if (flags & 64) {
            unsigned short hh = f2bf(v);
            Ch[(size_t)gr * ldc + gc] = (short)hh;
            Cl[(size_t)gr * ldc + gc] = (short)f2bf(v - bf2f(hh));
          } else {
            C[(size_t)gr * ldc + gc] = v;
          }
        }
        lsum[nt] += v; lsq[nt] = fmaf(v, v, lsq[nt]);
        lmx[nt] = fmaxf(lmx[nt], v); lmn[nt] = fminf(lmn[nt], v);
      }
  }
  if (dostat || domx) {
#pragma unroll
    for (int nt = 0; nt < 2; ++nt) {
#pragma unroll
      for (int m = 16; m <= 32; m <<= 1) {
        lsum[nt] += __shfl_xor(lsum[nt], m, 64);
        lsq[nt] += __shfl_xor(lsq[nt], m, 64);
        lmx[nt] = fmaxf(lmx[nt], __shfl_xor(lmx[nt], m, 64));
        lmn[nt] = fminf(lmn[nt], __shfl_xor(lmn[nt], m, 64));
      }
    }
    if (domx && lane < 16) {
      int node = blockIdx.x * 2 + wr;
#pragma unroll
      for (int nt = 0; nt < 2; ++nt) {
        int gc = n0 + wc * 32 + nt * 16 + lane;
        mxp[(size_t)node * N + gc] = lmx[nt];
        mnp[(size_t)node * N + gc] = lmn[nt];
      }
    }
    if (dostat) {
      if (tid < 64) { ssum[tid] = 0.f; ssq[tid] = 0.f; }
      __syncthreads();
      if (lane < 16) {
#pragma unroll
        for (int nt = 0; nt < 2; ++nt) {
          int ct = wc * 32 + nt * 16 + lane;
          atomicAdd(&ssum[ct], lsum[nt]);
          atomicAdd(&ssq[ct], lsq[nt]);
        }
      }
      __syncthreads();
      if (tid < 64) {
        int slot = blockIdx.x & 63;
        int gc = n0 + tid;
        atomicAdd(&statsP[(size_t)slot * 1024 + gc], ssum[tid]);
        atomicAdd(&statsP[(size_t)slot * 1024 + 512 + gc], ssq[tid]);
      }
    }
  }
}

// ---------------- dedicated kNN-2 key kernel: 64 rows x 256 cols per block ----
// x1h/x1l are FULL-table pointers; c0 selects the column chunk (B rows are
// global node indices n0+sr). Bit-identical keys to the old flag-128 path.
__global__ __launch_bounds__(256)
void mk_keyS(const short* __restrict__ x1h, const short* __restrict__ x1l,
             const float* __restrict__ sq, unsigned* __restrict__ Kb, int c0) {
  __shared__ short Ah[64][BPAD], Al[64][BPAD], Bh[64][BPAD], Bl[64][BPAD];
  int tid = threadIdx.x, lane = tid & 63, wid = tid >> 6;
  int wr = wid >> 1, wc = wid & 1;
  int r0 = blockIdx.x * 64;
  int nb = c0 + blockIdx.y * 256;
  int sr = tid >> 2, sc = (tid & 3) * 16;
  {
    const short* ah = &x1h[(size_t)(r0 + sr) * 64 + sc];
    const short* al = &x1l[(size_t)(r0 + sr) * 64 + sc];
    *(short8*)&Ah[sr][sc]     = *(const short8*)ah;
    *(short8*)&Ah[sr][sc + 8] = *(const short8*)(ah + 8);
    *(short8*)&Al[sr][sc]     = *(const short8*)al;
    *(short8*)&Al[sr][sc + 8] = *(const short8*)(al + 8);
  }
  __syncthreads();
  short8 a_h[2][2], a_l[2][2];
  int ar = wr * 32 + (lane & 15);
#pragma unroll
  for (int kk = 0; kk < 2; ++kk) {
    int kof = kk * 32 + (lane >> 4) * 8;
#pragma unroll
    for (int mt = 0; mt < 2; ++mt) {
      a_h[mt][kk] = *(const short8*)&Ah[ar + mt * 16][kof];
      a_l[mt][kk] = *(const short8*)&Al[ar + mt * 16][kof];
    }
  }
  float sqr[2][4];
#pragma unroll
  for (int mt = 0; mt < 2; ++mt)
#pragma unroll
    for (int i = 0; i < 4; ++i)
      sqr[mt][i] = sq[r0 + wr * 32 + mt * 16 + (lane >> 4) * 4 + i];

  f32x4 zero4 = {0.f, 0.f, 0.f, 0.f};
  for (int t = 0; t < 4; ++t) {
    int n0 = nb + t * 64;
    __syncthreads();
    {
      const short* bh2 = &x1h[(size_t)(n0 + sr) * 64 + sc];
      const short* bl2 = &x1l[(size_t)(n0 + sr) * 64 + sc];
      *(short8*)&Bh[sr][sc]     = *(const short8*)bh2;
      *(short8*)&Bh[sr][sc + 8] = *(const short8*)(bh2 + 8);
      *(short8*)&Bl[sr][sc]     = *(const short8*)bl2;
      *(short8*)&Bl[sr][sc + 8] = *(const short8*)(bl2 + 8);
    }
    __syncthreads();
    f32x4 acc[2][2] = {{zero4, zero4}, {zero4, zero4}};
    int br = wc * 32 + (lane & 15);
#pragma unroll
    for (int kk = 0; kk < 2; ++kk) {
      int kof = kk * 32 + (lane >> 4) * 8;
      short8 b_h[2], b_l[2];
#pragma unroll
      for (int nt = 0; nt < 2; ++nt) {
        b_h[nt] = *(const short8*)&Bh[br + nt * 16][kof];
        b_l[nt] = *(const short8*)&Bl[br + nt * 16][kof];
      }
#pragma unroll
      for (int mt = 0; mt < 2; ++mt)
#pragma unroll
        for (int nt = 0; nt < 2; ++nt) {
          acc[mt][nt] = __builtin_amdgcn_mfma_f32_16x16x32_bf16(a_h[mt][kk], b_h[nt], acc[mt][nt], 0, 0, 0);
          acc[mt][nt] = __builtin_amdgcn_mfma_f32_16x16x32_bf16(a_h[mt][kk], b_l[nt], acc[mt][nt], 0, 0, 0);
          acc[mt][nt] = __builtin_amdgcn_mfma_f32_16x16x32_bf16(a_l[mt][kk], b_h[nt], acc[mt][nt], 0, 0, 0);
        }
    }
#pragma unroll
    for (int nt = 0; nt < 2; ++nt) {
      int gc = n0 + wc * 32 + nt * 16 + (lane & 15);
      float sqc = sq[gc];
#pragma unroll
      for (int mt = 0; mt < 2; ++mt)
#pragma unroll
        for (int i = 0; i < 4; ++i) {
          int gr = r0 + wr * 32 + mt * 16 + (lane >> 4) * 4 + i;
          float v = acc[mt][nt][i];
          unsigned kk2 = (gr == gc) ? 0xFFFFFFFFu
                                    : ordf(sqr[mt][i] + sqc - 2.f * v);
          Kb[(size_t)gr * 4096 + (gc - c0)] = kk2;
        }
    }
  }
}

// ---------------- weight conversion ----------------
__global__ void mk_wcvt(const float* __restrict__ W, short* __restrict__ Wh,
                        short* __restrict__ Wl, int K, int N) {
  int g = blockIdx.x * 256 + threadIdx.x;
  if (g >= K * N) return;
  int k = g / N, n = g - k * N;
  float v = W[g];
  unsigned short h = f2bf(v);
  Wh[(size_t)n * K + k] = (short)h;
  Wl[(size_t)n * K + k] = (short)f2bf(v - bf2f(h));
}
__global__ void mk_wcvts(const float* __restrict__ W, const float* __restrict__ a,
                         short* __restrict__ Wh, short* __restrict__ Wl, int K, int N) {
  int g = blockIdx.x * 256 + threadIdx.x;
  if (g >= K * N) return;
  int k = g / N, n = g - k * N;
  float v = a[k] * W[g];
  unsigned short h = f2bf(v);
  Wh[(size_t)n * K + k] = (short)h;
  Wl[(size_t)n * K + k] = (short)f2bf(v - bf2f(h));
}
__global__ void mk_biasfold(const float* __restrict__ W, const float* __restrict__ bv,
                            const float* __restrict__ b0, float* __restrict__ bo,
                            int K, int N) {
  int col = blockIdx.x * 4 + (threadIdx.x >> 6);
  int lane = threadIdx.x & 63;
  if (col >= N) return;
  float s = 0.f;
  for (int k = lane; k < K; k += 64) s = fmaf(bv[k], W[(size_t)k * N + col], s);
#pragma unroll
  for (int off = 32; off; off >>= 1) s += __shfl_xor(s, off, 64);
  if (lane == 0) bo[col] = b0[col] + s;
}
__global__ void mk_wcvt2(const float* __restrict__ W, short* __restrict__ Dh,
                         short* __restrict__ Dl, short* __restrict__ Vh,
                         short* __restrict__ Vl) {
  int g = blockIdx.x * 256 + threadIdx.x;
  if (g >= 64 * 128) return;
  int k = g >> 7, n = g & 127;
  float u = W[k * 128 + n], vv = W[(64 + k) * 128 + n];
  float d = u - vv;
  unsigned short h = f2bf(d);
  Dh[n * 64 + k] = (short)h; Dl[n * 64 + k] = (short)f2bf(d - bf2f(h));
  h = f2bf(vv);
  Vh[n * 64 + k] = (short)h; Vl[n * 64 + k] = (short)f2bf(vv - bf2f(h));
}

// ---------------- conv1 node tables ----------------
__global__ void mk_conv1nodes(const float* __restrict__ pos, const float* __restrict__ W1,
                              const float* __restrict__ b1, float* __restrict__ Pp,
                              float* __restrict__ Qn) {
  int g = blockIdx.x * 256 + threadIdx.x;
  if (g >= 8192 * 64) return;
  int i = g >> 6, c = g & 63;
  float p0 = pos[i * 3], p1 = pos[i * 3 + 1], p2 = pos[i * 3 + 2];
  float q = p0 * W1[192 + c] + p1 * W1[256 + c] + p2 * W1[320 + c];
  Qn[g] = q;
  Pp[g] = p0 * W1[c] + p1 * W1[64 + c] + p2 * W1[128 + c] - q + b1[c];
}

__global__ __launch_bounds__(256)
void mk_stats1(const float* __restrict__ Pp, const float* __restrict__ Qn,
               const int* __restrict__ idx1, float* __restrict__ statsP) {
  __shared__ int sidx[512];
  int tid = threadIdx.x;
  int c = tid & 63, grp = tid >> 6;
  int nb = blockIdx.x * 16;
  if (tid < 256) {
    sidx[tid] = idx1[nb * 32 + tid];
    sidx[tid + 256] = idx1[nb * 32 + 256 + tid];
  }
  __syncthreads();
  float s = 0.f, q = 0.f;
  for (int ln = 0; ln < 16; ++ln) {
    float pv = Pp[(size_t)(nb + ln) * 64 + c];
    for (int e = grp; e < 32; e += 4) {
      int j = sidx[ln * 32 + e];
      float v = fmaxf(pv + Qn[(size_t)j * 64 + c], 0.f);
      s += v; q = fmaf(v, v, q);
    }
  }
  int slot = (blockIdx.x * 4 + grp) & 63;
  atomicAdd(&statsP[(size_t)slot * 1024 + c], s);
  atomicAdd(&statsP[(size_t)slot * 1024 + 512 + c], q);
}

__global__ __launch_bounds__(128)
void mk_econv2(const float* __restrict__ R, const float* __restrict__ T,
               const int* __restrict__ st_i, float* __restrict__ mxp,
               float* __restrict__ mnp, float* __restrict__ statsP) {
  __shared__ int sidx[256];
  int tid = threadIdx.x;
  int nb = blockIdx.x * 8;
  sidx[tid] = st_i[nb * 32 + tid];
  sidx[tid + 128] = st_i[nb * 32 + 128 + tid];
  __syncthreads();
  float s = 0.f, q = 0.f;
  for (int ln = 0; ln < 8; ++ln) {
    int i = nb + ln;
    float rv = R[(size_t)i * 128 + tid];
    float mx = -3.4e38f, mn = 3.4e38f;
    for (int e = 0; e < 32; ++e) {
      int j = sidx[ln * 32 + e];
      float v = fmaxf(rv + T[(size_t)j * 128 + tid], 0.f);
      mx = fmaxf(mx, v); mn = fminf(mn, v);
      s += v; q = fmaf(v, v, q);
    }
    mxp[(size_t)i * 128 + tid] = mx;
    mnp[(size_t)i * 128 + tid] = mn;
  }
  int slot = blockIdx.x & 63;
  atomicAdd(&statsP[(size_t)slot * 1024 + tid], s);
  atomicAdd(&statsP[(size_t)slot * 1024 + 512 + tid], q);
}

// slot stats (sum @ +0, sq @ +512 per 1024-slot) -> coef (a @ +0, b @ +1024)
__global__ void mk_bnfinS(const float* __restrict__ sb, const float* __restrict__ g,
                          const float* __restrict__ beta, float* __restrict__ bno,
                          float Minv, int Cdim) {
  int c = blockIdx.x * 256 + threadIdx.x;
  if (c >= Cdim) return;
  float s = 0.f, q = 0.f;
  for (int sl = 0; sl < 64; ++sl) {
    s += sb[(size_t)sl * 1024 + c];
    q += sb[(size_t)sl * 1024 + 512 + c];
  }
  float mu = s * Minv;
  float var = q * Minv - mu * mu;
  float a = g[c] * rsqrtf(var + BN_EPS);
  bno[c] = a;
  bno[1024 + c] = beta[c] - a * mu;
}

__global__ void mk_finx1(const float* __restrict__ mx, const float* __restrict__ mn,
                         const float* __restrict__ bn, float* __restrict__ xc,
                         short* __restrict__ x1h, short* __restrict__ x1l) {
  int g = blockIdx.x * 256 + threadIdx.x;
  if (g >= 8192 * 64) return;
  int i = g >> 6, c = g & 63;
  float a = bn[c], b = bn[1024 + c];
  float v = (a > 0.f) ? fmaf(a, mx[g], b) : fmaf(a, mn[g], b);
  xc[(size_t)i * 192 + c] = v;
  unsigned short h = f2bf(v);
  x1h[g] = (short)h;
  x1l[g] = (short)f2bf(v - bf2f(h));
}
__global__ void mk_finx2(const float* __restrict__ mx, const float* __restrict__ mn,
                         const float* __restrict__ bn, float* __restrict__ xcB) {
  int g = blockIdx.x * 256 + threadIdx.x;
  if (g >= 8192 * 128) return;
  int i = g >> 7, c = g & 127;
  float a = bn[c], b = bn[1024 + c];
  xcB[(size_t)i * 192 + c] = (a > 0.f) ? fmaf(a, mx[g], b) : fmaf(a, mn[g], b);
}

// ---------------- kNN: chunk-min threshold select (exact) ----------------
__global__ void mk_posq(const float* __restrict__ pos, float4* __restrict__ posq) {
  int i = blockIdx.x * 256 + threadIdx.x;
  if (i >= 8192) return;
  float x = pos[i * 3], y = pos[i * 3 + 1], z = pos[i * 3 + 2];
  float s = fmaf(z, z, fmaf(y, y, x * x));
  posq[i] = make_float4(x, y, z, s);
}

// per-wave 8th-smallest of 64 lane values via ballot binary search (constant k=8)
__device__ __forceinline__ unsigned wave_kth8(unsigned v) {
  unsigned T = 0;
#pragma unroll
  for (int b = 31; b >= 0; --b) {
    unsigned cand = T | (1u << b);
    int c = __popcll(__ballot(v < cand));
    if (c < 8) T = cand;
  }
  return T;
}

__global__ __launch_bounds__(256)
void mk_knn1(const float4* __restrict__ posq, int* __restrict__ idxout) {
  __shared__ ull buf[K1CAP];
  __shared__ unsigned Tw[4];
  __shared__ unsigned cnt;
  int q = blockIdx.x, tid = threadIdx.x;
  int lane = tid & 63, wid = tid >> 6;
  float4 pq = posq[q];
  if (tid == 0) cnt = 0;
  unsigned key[32];
  unsigned vmin = 0xFFFFFFFFu;
#pragma unroll
  for (int c = 0; c < 32; ++c) {
    int j = c * 256 + tid;
    float4 pj = posq[j];
    float d = pq.w + pj.w - 2.f * (pq.x * pj.x + pq.y * pj.y + pq.z * pj.z);
    unsigned k = (j == q) ? 0xFFFFFFFFu : ordf(d);
    key[c] = k;
    vmin = vmin < k ? vmin : k;
  }
  unsigned T = wave_kth8(vmin);
  if (lane == 0) Tw[wid] = T;
  __syncthreads();
  unsigned Tmax = max(max(Tw[0], Tw[1]), max(Tw[2], Tw[3]));
#pragma unroll
  for (int c = 0; c < 32; ++c) {
    if (key[c] <= Tmax) {
      int j = c * 256 + tid;
      unsigned s = atomicAdd(&cnt, 1u);
      if (s < K1CAP) buf[s] = (((ull)key[c]) << 32) | (unsigned)j;
    }
  }
  __syncthreads();
  int m = cnt < (unsigned)K1CAP ? (int)cnt : K1CAP;
  for (int e = tid; e < m; e += 256) {
    ull mine = buf[e];
    int rank = 0;
    for (int f = 0; f < m; ++f) rank += (buf[f] < mine) ? 1 : 0;
    if (rank < 32) idxout[q * 32 + rank] = (int)(unsigned)(mine & 0xFFFFFFFFu);
  }
}

// knn2: reads precomputed u32 key matrix Kb[q][0..4095] (diag already ~0)
__global__ __launch_bounds__(256)
void mk_knn2(const unsigned* __restrict__ Kb, int c0, int first,
             unsigned* __restrict__ st_k, int* __restrict__ st_i) {
  __shared__ ull buf[K2CAP];
  __shared__ unsigned Tw[4];
  __shared__ unsigned cnt;
  int q = blockIdx.x, tid = threadIdx.x;
  int lane = tid & 63, wid = tid >> 6;
  if (tid == 0) cnt = 0;
  unsigned key[16];
  unsigned vmin = 0xFFFFFFFFu;
#pragma unroll
  for (int c = 0; c < 16; ++c) {
    unsigned k = Kb[(size_t)q * 4096 + c * 256 + tid];
    key[c] = k;
    vmin = vmin < k ? vmin : k;
  }
  unsigned T = wave_kth8(vmin);
  if (lane == 0) Tw[wid] = T;
  __syncthreads();
  unsigned Tmax = max(max(Tw[0], Tw[1]), max(Tw[2], Tw[3]));
#pragma unroll
  for (int c = 0; c < 16; ++c) {
    if (key[c] <= Tmax) {
      int j = c0 + c * 256 + tid;
      unsigned s = atomicAdd(&cnt, 1u);
      if (s < K2CAP) buf[s] = (((ull)key[c]) << 32) | (unsigned)j;
    }
  }
  if (!first && tid < 32) {
    ull k = (((ull)st_k[q * 32 + tid]) << 32) | (unsigned)st_i[q * 32 + tid];
    unsigned s = atomicAdd(&cnt, 1u);
    if (s < K2CAP) buf[s] = k;
  }
  __syncthreads();
  int m = cnt < (unsigned)K2CAP ? (int)cnt : K2CAP;
  for (int e = tid; e < m; e += 256) {
    ull mine = buf[e];
    int rank = 0;
    for (int f = 0; f < m; ++f) rank += (buf[f] < mine) ? 1 : 0;
    if (rank < 32) {
      st_k[q * 32 + rank] = (unsigned)(mine >> 32);
      st_i[q * 32 + rank] = (int)(unsigned)(mine & 0xFFFFFFFFu);
    }
  }
}

// ---------------- fp32 GEMM (tag1, K=16) ----------------
#define GBM 64
#define GBN 64
#define GBK 16

__global__ __launch_bounds__(256)
void mk_gemm(const float* __restrict__ A, const float* __restrict__ W, int ldw,
             const float* __restrict__ bias, float* __restrict__ C, int ldc,
             int M, int N, int K, int flags) {
  __shared__ float As[GBK][GBM + 4];
  __shared__ float Ws[GBK][GBN];
  int tid = threadIdx.x;
  int r0 = blockIdx.x * GBM, n0 = blockIdx.y * GBN;
  int ty = tid >> 4, tx = tid & 15;
  float acc[4][4] = {};
  for (int kt = 0; kt < K; kt += GBK) {
#pragma unroll
    for (int it = 0; it < 4; ++it) {
      int l = it * 256 + tid;
      int r = l >> 4, kk = l & 15;
      int gr = r0 + r, gk = kt + kk;
      float v = 0.f;
      if (gk < K && gr < M) v = A[(size_t)gr * K + gk];
      As[kk][r] = v;
      int kw = l >> 6, nw = l & 63;
      int gkw = kt + kw;
      Ws[kw][nw] = (gkw < K && (n0 + nw) < N) ? W[(size_t)gkw * ldw + n0 + nw] : 0.f;
    }
    __syncthreads();
#pragma unroll
    for (int kk = 0; kk < GBK; ++kk) {
      float4 a4 = *(const float4*)&As[kk][ty * 4];
      float4 b4 = *(const float4*)&Ws[kk][tx * 4];
      float av[4] = {a4.x, a4.y, a4.z, a4.w};
      float bv[4] = {b4.x, b4.y, b4.z, b4.w};
#pragma unroll
      for (int i = 0; i < 4; ++i)
#pragma unroll
        for (int j = 0; j < 4; ++j)
          acc[i][j] = fmaf(av[i], bv[j], acc[i][j]);
    }
    __syncthreads();
  }
#pragma unroll
  for (int i = 0; i < 4; ++i) {
    int gr = r0 + ty * 4 + i;
    if (gr >= M) continue;
#pragma unroll
    for (int j = 0; j < 4; ++j) {
      int gc = n0 + tx * 4 + j;
      if (gc >= N) continue;
      float v = acc[i][j];
      if (bias) v += bias[gc];
      if (flags & 1) v += C[(size_t)gr * ldc + gc];
      if (flags & 2) v = fmaxf(v, 0.f);
      C[(size_t)gr * ldc + gc] = v;
    }
  }
}

// ---------------- small utility kernels ----------------
__global__ void mk_sqnorm(const float* __restrict__ x, int ld, float* __restrict__ sq,
                          int Npts, int Cdim) {
  int i = blockIdx.x * blockDim.x + threadIdx.x;
  if (i >= Npts) return;
  float s = 0.f;
  for (int c = 0; c < Cdim; ++c) { float v = x[(size_t)i * ld + c]; s = fmaf(v, v, s); }
  sq[i] = s;
}

// ---------------- CSR build + props ----------------
__global__ void mk_count(const int* __restrict__ col, int* __restrict__ cnt, int E) {
  int e = blockIdx.x * 256 + threadIdx.x;
  if (e < E) atomicAdd(&cnt[col[e]], 1);
}
__global__ __launch_bounds__(1024)
void mk_scan(const int* __restrict__ cnt, int* __restrict__ offp,
             int* __restrict__ cur, float* __restrict__ dinvf) {
  __shared__ int wsum[16];
  __shared__ int wexc[16];
  int t = threadIdx.x, lane = t & 63, w = t >> 6;
  int v[8]; int s = 0;
  int base = t * 8;
#pragma unroll
  for (int k = 0; k < 8; ++k) { v[k] = s; s += cnt[base + k]; }
  int sc = s;
#pragma unroll
  for (int off2 = 1; off2 < 64; off2 <<= 1) {
    int n = __shfl_up(sc, off2, 64);
    if (lane >= off2) sc += n;
  }
  if (lane == 63) wsum[w] = sc;
  __syncthreads();
  if (w == 0) {
    int x = (lane < 16) ? wsum[lane] : 0;
    int scx = x;
#pragma unroll
    for (int off2 = 1; off2 < 16; off2 <<= 1) {
      int n = __shfl_up(scx, off2, 64);
      if (lane >= off2) scx += n;
    }
    if (lane < 16) wexc[lane] = scx - x;
  }
  __syncthreads();
  int texc = wexc[w] + (sc - s);
#pragma unroll
  for (int k = 0; k < 8; ++k) {
    int o = texc + v[k];
    offp[base + k] = o;
    cur[base + k] = o;
    int d = cnt[base + k];
    dinvf[base + k] = (d > 0) ? rsqrtf((float)(d < 1 ? 1 : d)) : 0.f;
  }
  if (t == 1023) offp[8192] = texc + s;
}
__global__ void mk_fill(const int* __restrict__ row, const int* __restrict__ col,
                        const float* __restrict__ dinvf, int* __restrict__ cur,
                        int* __restrict__ crow, float* __restrict__ cw, int E) {
  int e = blockIdx.x * 256 + threadIdx.x;
  if (e >= E) return;
  int c = col[e], r = row[e];
  int s = atomicAdd(&cur[c], 1);
  crow[s] = r;
  cw[s] = dinvf[r] * dinvf[c];
}
__global__ void mk_prop64(const float* __restrict__ in, int in_ld,
                          const int* __restrict__ offp, const int* __restrict__ crow,
                          const float* __restrict__ cw, float* __restrict__ out, int out_ld) {
  int gid = blockIdx.x * 256 + threadIdx.x;
  if (gid >= 8192 * 16) return;
  int col = gid >> 4, c4 = (gid & 15) * 4;
  int s0 = offp[col], s1 = offp[col + 1];
  float a0 = 0, a1 = 0, a2 = 0, a3 = 0;
  for (int s = s0; s < s1; ++s) {
    int r = crow[s]; float w = cw[s];
    float4 v = *(const float4*)&in[(size_t)r * in_ld + c4];
    a0 = fmaf(w, v.x, a0); a1 = fmaf(w, v.y, a1);
    a2 = fmaf(w, v.z, a2); a3 = fmaf(w, v.w, a3);
  }
  float4 o = {a0, a1, a2, a3};
  *(float4*)&out[(size_t)col * out_ld + c4] = o;
}
__global__ void mk_prop4(const float* __restrict__ in, int in_ld,
                         const int* __restrict__ offp, const int* __restrict__ crow,
                         const float* __restrict__ cw, float* __restrict__ out, int out_ld) {
  int col = blockIdx.x * 256 + threadIdx.x;
  if (col >= 8192) return;
  int s0 = offp[col], s1 = offp[col + 1];
  float a0 = 0, a1 = 0, a2 = 0, a3 = 0;
  for (int s = s0; s < s1; ++s) {
    int r = crow[s]; float w = cw[s];
    float4 v = *(const float4*)&in[(size_t)r * in_ld];
    a0 = fmaf(w, v.x, a0); a1 = fmaf(w, v.y, a1);
    a2 = fmaf(w, v.z, a2); a3 = fmaf(w, v.w, a3);
  }
  float4 o = {a0, a1, a2, a3};
  *(float4*)&out[(size_t)col * out_ld] = o;
}
__global__ void mk_pack4(const float* __restrict__ xin, float* __restrict__ H1) {
  int g = blockIdx.x * 256 + threadIdx.x;
  if (g >= 8192 * 4) return;
  H1[(size_t)(g >> 2) * 16 + (g & 3)] = xin[g];
}
__global__ void mk_copy64(const float* __restrict__ gcv, float* __restrict__ H2) {
  int g = blockIdx.x * 256 + threadIdx.x;
  if (g >= 8192 * 64) return;
  H2[(size_t)(g >> 6) * 256 + (g & 63)] = gcv[(size_t)(g >> 6) * 192 + (g & 63)];
}

__global__ __launch_bounds__(256)
void mk_gemv_out(const float* __restrict__ h, const float* __restrict__ bn,
                 const float* __restrict__ w, const float* __restrict__ b,
                 float* __restrict__ out, int Npts) {
  int row = blockIdx.x * 4 + (threadIdx.x >> 6);
  int lane = threadIdx.x & 63;
  if (row >= Npts) return;
  int c = lane * 4;
  float4 v = *(const float4*)&h[(size_t)row * 256 + c];
  float s = (bn[c] * v.x + bn[1024 + c]) * w[c]
          + (bn[c + 1] * v.y + bn[1024 + c + 1]) * w[c + 1]
          + (bn[c + 2] * v.z + bn[1024 + c + 2]) * w[c + 2]
          + (bn[c + 3] * v.w + bn[1024 + c + 3]) * w[c + 3];
#pragma unroll
  for (int off = 32; off; off >>= 1) s += __shfl_xor(s, off, 64);
  if (lane == 0) out[row] = s + b[0];
}

// ---------------- host ----------------
extern "C" void kernel_launch(void* const* d_in, const int* in_sizes, int n_in,
                              void* d_out, int out_size, void* d_ws, size_t ws_size,
                              hipStream_t stream) {
  const int N = 8192;
  const int NE = N * 32;
  const float* pos = (const float*)d_in[0];
  const float* xin = (const float*)d_in[1];
  const int* ei = (const int*)d_in[2];
  const int E = in_sizes[2] / 2;
  const int* erow = ei;
  const int* ecol = ei + E;
  const float* mlp1_W1  = (const float*)d_in[3];
  const float* mlp1_W23 = (const float*)d_in[4];
  const float* mlp1_b   = (const float*)d_in[5];
  const float* mlp1_g   = (const float*)d_in[6];
  const float* mlp1_be  = (const float*)d_in[7];
  const float* mlp2_W   = (const float*)d_in[8];
  const float* mlp2_b   = (const float*)d_in[9];
  const float* mlp2_g   = (const float*)d_in[10];
  const float* mlp2_be  = (const float*)d_in[11];
  const float* lin1_W   = (const float*)d_in[12];
  const float* lin1_b   = (const float*)d_in[13];
  const float* lin1_g   = (const float*)d_in[14];
  const float* lin1_be  = (const float*)d_in[15];
  const float* tag1_W   = (const float*)d_in[16];
  const float* tag1_b   = (const float*)d_in[17];
  const float* tag2_W   = (const float*)d_in[18];
  const float* tag2_b   = (const float*)d_in[19];
  const float* lin2_W   = (const float*)d_in[20];
  const float* lin2_b   = (const float*)d_in[21];
  const float* lin2_g   = (const float*)d_in[22];
  const float* lin2_be  = (const float*)d_in[23];
  const float* mix1_W   = (const float*)d_in[24];
  const float* mix1_b   = (const float*)d_in[25];
  const float* mix1_g   = (const float*)d_in[26];
  const float* mix1_be  = (const float*)d_in[27];
  const float* mix2_W   = (const float*)d_in[28];
  const float* mix2_b   = (const float*)d_in[29];
  const float* mix2_g   = (const float*)d_in[30];
  const float* mix2_be  = (const float*)d_in[31];
  const float* outW     = (const float*)d_in[32];
  const float* outB     = (const float*)d_in[33];

  char* base = (char*)d_ws;
  size_t off = 0;
  auto alloc = [&](size_t b) -> void* {
    void* p = base + off;
    off += (b + 255) & ~(size_t)255;
    return p;
  };
  float* BIG = (float*)alloc(134217728ull);   // 128 MB phase-shared
  short* h2_h  = (short*)BIG;                            // conv1 L2 out hi (32 MB)
  short* h2_l  = (short*)((char*)BIG + 33554432);        // lo (32 MB)
  unsigned* Kb = (unsigned*)BIG;                         // knn2 key matrix [8192][4096] (128 MB)
  short* mhcat_h = (short*)BIG;                          // [8192][1024] hi (16 MB)
  short* mhcat_l = (short*)((char*)BIG + 16777216);      // lo (16 MB)
  short* mh1_h   = (short*)((char*)BIG + 33554432);      // [8192][512] hi (8 MB)
  short* mh1_l   = (short*)((char*)BIG + 41943040);      // lo (8 MB)
  float* mh2     = (float*)((char*)BIG + 50331648);      // [8192][256] fp32 (8 MB)
  float* H2      = BIG + 16777216;                       // byte 64M+: tag2 hop-concat
  int*   idx1 = (int*)alloc((size_t)NE * 4);
  unsigned* st_k = (unsigned*)alloc((size_t)NE * 4);
  int*   st_i = (int*)alloc((size_t)NE * 4);
  float* xc  = (float*)alloc((size_t)N * 192 * 4);   // [x1 | x2]
  float* gc  = (float*)alloc((size_t)N * 192 * 4);   // [g1 | g2]
  float4* posq = (float4*)alloc((size_t)N * 16);
  float* sqx = (float*)alloc((size_t)N * 4);
  float* Pp  = (float*)alloc((size_t)N * 64 * 4);
  float* Qn  = (float*)alloc((size_t)N * 64 * 4);
  float* Rb  = (float*)alloc((size_t)N * 128 * 4);
  float* Tb  = (float*)alloc((size_t)N * 128 * 4);
  float* mx1 = (float*)alloc((size_t)N * 64 * 4);
  float* mn1 = (float*)alloc((size_t)N * 64 * 4);
  float* mx2 = (float*)alloc((size_t)N * 128 * 4);
  float* mn2 = (float*)alloc((size_t)N * 128 * 4);
  float* H1  = (float*)alloc((size_t)N * 16 * 4);
  float* dinvf = (float*)alloc((size_t)N * 4);
  int* cnt     = (int*)alloc((size_t)N * 4);
  int* csr_off = (int*)alloc((size_t)(N + 1) * 4);
  int* cursor  = (int*)alloc((size_t)N * 4);
  int* csr_row = (int*)alloc((size_t)E * 4);
  float* csr_w = (float*)alloc((size_t)E * 4);
  float* slotAll = (float*)alloc((size_t)8 * 64 * 1024 * 4);
  auto slot = [&](int i) { return slotAll + (size_t)i * 64 * 1024; };
  float* bnb = (float*)alloc(8 * 2048 * 4);           // coef: a @ +0, b @ +1024
  auto bnp = [&](int i) { return bnb + (size_t)i * 2048; };
  float* bnM = bnp(4);                                // lin1 a cols 0-511, lin2 at +512
  float* bias1f = (float*)alloc(512 * 4);
  float* bias2f = (float*)alloc(256 * 4);
  float* biasA  = (float*)alloc(64 * 4);
  float* biasB  = (float*)alloc(64 * 4);
  auto salloc = [&](size_t n) { return (short*)alloc(n * 2); };
  short* w23a_h = salloc(4096);   short* w23a_l = salloc(4096);
  short* w23b_h = salloc(4096);   short* w23b_l = salloc(4096);
  short* wd2_h  = salloc(8192);   short* wd2_l  = salloc(8192);
  short* wv2_h  = salloc(8192);   short* wv2_l  = salloc(8192);
  short* wl1_h  = salloc(98304);  short* wl1_l  = salloc(98304);
  short* wt2_h  = salloc(32768);  short* wt2_l  = salloc(32768);
  short* wl2_h  = salloc(98304);  short* wl2_l  = salloc(98304);
  short* wx1_h  = salloc(524288); short* wx1_l  = salloc(524288);
  short* wx2_h  = salloc(131072); short* wx2_l  = salloc(131072);
  short* x1h    = salloc(524288); short* x1l    = salloc(524288);

  auto gemmF = [&](const float* A, const short* A8h, const short* A8l,
                   const float* src, const int* gidx, int srcC, const float* bnA,
                   const short* Wh_, const short* Wl_, int ldk, int koff, int lda,
                   const float* bias, float* Cp, short* Chp, short* Clp, int ldc,
                   int M, int Nn, int Kk, int flags,
                   float* stP = nullptr, float* mxP = nullptr, float* mnP = nullptr) {
    dim3 g(M / 64, Nn / 64);
    mk_gemm_mfma<<<g, 256, 0, stream>>>(A, A8h, A8l, src, gidx, srcC, bnA,
                                        Wh_, Wl_, ldk, koff, lda, bias, Cp, Chp, Clp, ldc,
                                        M, Nn, Kk, flags, stP, mxP, mnP);
  };
  auto wcvt = [&](const float* W, short* Wh_, short* Wl_, int Kk, int Nn) {
    mk_wcvt<<<(Kk * Nn + 255) / 256, 256, 0, stream>>>(W, Wh_, Wl_, Kk, Nn);
  };

  // ---- init + weight conversion ----
  hipMemsetAsync(slotAll, 0, (size_t)8 * 64 * 1024 * 4, stream);
  hipMemsetAsync(cnt, 0, (size_t)N * 4, stream);
  mk_wcvt2<<<(64 * 128 + 255) / 256, 256, 0, stream>>>(mlp2_W, wd2_h, wd2_l, wv2_h, wv2_l);
  wcvt(lin1_W, wl1_h, wl1_l, 192, 512);
  wcvt(tag2_W, wt2_h, wt2_l, 256, 128);
  wcvt(lin2_W, wl2_h, wl2_l, 192, 512);

  // ---- kNN-1 on pos ----
  mk_posq<<<32, 256, 0, stream>>>(pos, posq);
  mk_knn1<<<N, 256, 0, stream>>>(posq, idx1);

  // ---- conv1 ----
  mk_conv1nodes<<<(N * 64 + 255) / 256, 256, 0, stream>>>(pos, mlp1_W1, mlp1_b, Pp, Qn);
  mk_stats1<<<512, 256, 0, stream>>>(Pp, Qn, idx1, slot(0));
  mk_bnfinS<<<1, 256, 0, stream>>>(slot(0), mlp1_g, mlp1_be, bnp(0), 1.f / NE, 64);
  mk_wcvts<<<(64 * 64 + 255) / 256, 256, 0, stream>>>(mlp1_W23, bnp(0), w23a_h, w23a_l, 64, 64);
  mk_biasfold<<<16, 256, 0, stream>>>(mlp1_W23, bnp(0) + 1024, mlp1_b + 64, biasA, 64, 64);
  gemmF(Pp, nullptr, nullptr, Qn, idx1, 64, nullptr,
        w23a_h, w23a_l, 64, 0, 64, biasA, nullptr, h2_h, h2_l, 64,
        NE, 64, 64, 2 | 8 | 32 | 64, slot(1));
  mk_bnfinS<<<1, 256, 0, stream>>>(slot(1), mlp1_g + 64, mlp1_be + 64, bnp(1), 1.f / NE, 64);
  mk_wcvts<<<(64 * 64 + 255) / 256, 256, 0, stream>>>(mlp1_W23 + 4096, bnp(1), w23b_h, w23b_l, 64, 64);
  mk_biasfold<<<16, 256, 0, stream>>>(mlp1_W23 + 4096, bnp(1) + 1024, mlp1_b + 128, biasB, 64, 64);
  gemmF(nullptr, h2_h, h2_l, nullptr, nullptr, 0, nullptr,
        w23b_h, w23b_l, 64, 0, 64, biasB, nullptr, nullptr, nullptr, 64,
        NE, 64, 64, 2 | 8 | 16, slot(2), mx1, mn1);
  mk_bnfinS<<<1, 256, 0, stream>>>(slot(2), mlp1_g + 128, mlp1_be + 128, bnp(2), 1.f / NE, 64);
  mk_finx1<<<(N * 64 + 255) / 256, 256, 0, stream>>>(mx1, mn1, bnp(2), xc, x1h, x1l);

  // ---- kNN-2 on x1: 2 chunks of 4096, keys via dedicated NTILE-4 kernel ----
  mk_sqnorm<<<32, 256, 0, stream>>>(xc, 192, sqx, N, 64);
  for (int c = 0; c < 2; ++c) {
    mk_keyS<<<dim3(128, 16), 256, 0, stream>>>(x1h, x1l, sqx, Kb, c * 4096);
    mk_knn2<<<N, 256, 0, stream>>>(Kb, c * 4096, c == 0 ? 1 : 0, st_k, st_i);
  }

  // ---- conv2 ----
  gemmF(nullptr, x1h, x1l, nullptr, nullptr, 0, nullptr,
        wd2_h, wd2_l, 64, 0, 64, mlp2_b, Rb, nullptr, nullptr, 128, N, 128, 64, 0);
  gemmF(nullptr, x1h, x1l, nullptr, nullptr, 0, nullptr,
        wv2_h, wv2_l, 64, 0, 64, nullptr, Tb, nullptr, nullptr, 128, N, 128, 64, 0);
  mk_econv2<<<N / 8, 128, 0, stream>>>(Rb, Tb, st_i, mx2, mn2, slot(3));
  mk_bnfinS<<<1, 256, 0, stream>>>(slot(3), mlp2_g, mlp2_be, bnp(3), 1.f / NE, 128);
  mk_finx2<<<(N * 128 + 255) / 256, 256, 0, stream>>>(mx2, mn2, bnp(3), xc + 64);

  // ---- lin1: K=192 GEMM -> mhcat (bf16 hi/lo) cols 0-511 ----
  gemmF(xc, nullptr, nullptr, nullptr, nullptr, 0, nullptr,
        wl1_h, wl1_l, 192, 0, 192, lin1_b, nullptr, mhcat_h, mhcat_l, 1024,
        N, 512, 192, 2 | 8 | 64, slot(4));
  mk_bnfinS<<<2, 256, 0, stream>>>(slot(4), lin1_g, lin1_be, bnM, 1.f / N, 512);

  // ---- TAG branch: CSR ----
  mk_count<<<(E + 255) / 256, 256, 0, stream>>>(ecol, cnt, E);
  mk_scan<<<1, 1024, 0, stream>>>(cnt, csr_off, cursor, dinvf);
  mk_fill<<<(E + 255) / 256, 256, 0, stream>>>(erow, ecol, dinvf, cursor, csr_row, csr_w, E);
  // tag1 -> gc cols 0-63
  mk_pack4<<<(N * 4 + 255) / 256, 256, 0, stream>>>(xin, H1);
  mk_prop4<<<32, 256, 0, stream>>>(xin, 4, csr_off, csr_row, csr_w, H1 + 4, 16);
  mk_prop4<<<32, 256, 0, stream>>>(H1 + 4, 16, csr_off, csr_row, csr_w, H1 + 8, 16);
  mk_prop4<<<32, 256, 0, stream>>>(H1 + 8, 16, csr_off, csr_row, csr_w, H1 + 12, 16);
  mk_gemm<<<dim3(128, 1), 256, 0, stream>>>(H1, tag1_W, 64, tag1_b, gc, 192, N, 64, 16, 2);
  // tag2: hop-concat H2 -> one K=256 gemmF -> gc cols 64-191
  mk_copy64<<<(N * 64 + 255) / 256, 256, 0, stream>>>(gc, H2);
  mk_prop64<<<512, 256, 0, stream>>>(gc, 192, csr_off, csr_row, csr_w, H2 + 64, 256);
  mk_prop64<<<512, 256, 0, stream>>>(H2 + 64, 256, csr_off, csr_row, csr_w, H2 + 128, 256);
  mk_prop64<<<512, 256, 0, stream>>>(H2 + 128, 256, csr_off, csr_row, csr_w, H2 + 192, 256);
  gemmF(H2, nullptr, nullptr, nullptr, nullptr, 0, nullptr,
        wt2_h, wt2_l, 256, 0, 256, tag2_b, gc + 64, nullptr, nullptr, 192,
        N, 128, 256, 2);
  // lin2: K=192 GEMM -> mhcat (bf16 hi/lo) cols 512-1023
  gemmF(gc, nullptr, nullptr, nullptr, nullptr, 0, nullptr,
        wl2_h, wl2_l, 192, 0, 192, lin2_b, nullptr, mhcat_h + 512, mhcat_l + 512, 1024,
        N, 512, 192, 2 | 8 | 64, slot(5));
  mk_bnfinS<<<2, 256, 0, stream>>>(slot(5), lin2_g, lin2_be, bnM + 512, 1.f / N, 512);

  // ---- fold lin BN into mix1 weights; mix head on fast A8 path ----
  mk_wcvts<<<(1024 * 512 + 255) / 256, 256, 0, stream>>>(mix1_W, bnM, wx1_h, wx1_l, 1024, 512);
  mk_biasfold<<<128, 256, 0, stream>>>(mix1_W, bnM + 1024, mix1_b, bias1f, 1024, 512);
  gemmF(nullptr, mhcat_h, mhcat_l, nullptr, nullptr, 0, nullptr,
        wx1_h, wx1_l, 1024, 0, 1024, bias1f, nullptr, mh1_h, mh1_l, 512,
        N, 512, 1024, 2 | 8 | 64, slot(6));
  mk_bnfinS<<<2, 256, 0, stream>>>(slot(6), mix1_g, mix1_be, bnp(6), 1.f / N, 512);
  mk_wcvts<<<(512 * 256 + 255) / 256, 256, 0, stream>>>(mix2_W, bnp(6), wx2_h, wx2_l, 512, 256);
  mk_biasfold<<<64, 256, 0, stream>>>(mix2_W, bnp(6) + 1024, mix2_b, bias2f, 512, 256);
  gemmF(nullptr, mh1_h, mh1_l, nullptr, nullptr, 0, nullptr,
        wx2_h, wx2_l, 512, 0, 512, bias2f, mh2, nullptr, nullptr, 256,
        N, 256, 512, 2 | 8, slot(7));
  mk_bnfinS<<<1, 256, 0, stream>>>(slot(7), mix2_g, mix2_be, bnp(7), 1.f / N, 256);
  mk_gemv_out<<<N / 4, 256, 0, stream>>>(mh2, bnp(7), outW, outB, (float*)d_out, N);
}

// Round 22
// 610.541 us; speedup vs baseline: 1.2967x; 1.0464x over previous
//
#include <hip/hip_runtime.h>
#include <cstdint>
#include <cstddef>

#define BN_EPS 1e-5f
#define K1CAP 1024
#define K2CAP 640

typedef short short8 __attribute__((ext_vector_type(8)));
typedef float f32x4 __attribute__((ext_vector_type(4)));
typedef unsigned long long ull;

// ---------------- helpers ----------------
__device__ __forceinline__ unsigned int ordf(float d) {
  unsigned int u = __float_as_uint(d);
  return (u >> 31) ? ~u : (u | 0x80000000u);
}
__device__ __forceinline__ unsigned short f2bf(float f) {
  unsigned u = __float_as_uint(f);
  u += 0x7fffu + ((u >> 16) & 1u);
  return (unsigned short)(u >> 16);
}
__device__ __forceinline__ float bf2f(unsigned short h) {
  return __uint_as_float(((unsigned)h) << 16);
}

// ---------------- MFMA bf16x3 GEMM (K_STEP=64, reg-staged pipeline) ----------------
// flags: 1=ACC, 2=RELU, 8=stats epilogue (slotted), 16=maxmin epilogue (NO C
// write), 32=EDGE1-A (v=relu(A[i][k]+src[j][k])), 64=BF16OUT (write Ch/Cl).
// A-source priority: A8h/A8l (bf16 hi/lo [M][lda]) -> flags&32 -> fp32 A [M][lda]
// (+optional bnA affine: bnA[k]*v + bnA[1024+k]). W: bf16 hi/lo n-major
// [N][ldk], k index = koff+k. Requires M%64==0, N%64==0, K%64==0.
#define BPAD 72

__global__ __launch_bounds__(256)
void mk_gemm_mfma(const float* __restrict__ A,
                  const short* __restrict__ A8h, const short* __restrict__ A8l,
                  const float* __restrict__ src, const int* __restrict__ gidx, int srcC,
                  const float* __restrict__ bnA,
                  const short* __restrict__ Wh, const short* __restrict__ Wl,
                  int ldk, int koff, int lda,
                  const float* __restrict__ bias,
                  float* __restrict__ C, short* __restrict__ Ch, short* __restrict__ Cl,
                  int ldc,
                  int M, int N, int K, int flags,
                  float* __restrict__ statsP,
                  float* __restrict__ mxp, float* __restrict__ mnp) {
  __shared__ short Ah[64][BPAD], Al[64][BPAD], Bh[64][BPAD], Bl[64][BPAD];
  __shared__ float ssum[64], ssq[64];
  int tid = threadIdx.x, lane = tid & 63, wid = tid >> 6;
  int wr = wid >> 1, wc = wid & 1;
  int r0 = blockIdx.x * 64, n0 = blockIdx.y * 64;
  int sr = tid >> 2, sc = (tid & 3) * 16;
  f32x4 zero4 = {0.f, 0.f, 0.f, 0.f};
  f32x4 acc[2][2] = {{zero4, zero4}, {zero4, zero4}};
  short8 rAh[2], rAl[2], rBh[2], rBl[2];

  auto stage = [&](int kt) {
    const short* bh = &Wh[(size_t)(n0 + sr) * ldk + koff + kt + sc];
    const short* bl = &Wl[(size_t)(n0 + sr) * ldk + koff + kt + sc];
    rBh[0] = *(const short8*)bh; rBh[1] = *(const short8*)(bh + 8);
    rBl[0] = *(const short8*)bl; rBl[1] = *(const short8*)(bl + 8);
    if (A8h) {
      const short* ah = &A8h[(size_t)(r0 + sr) * lda + kt + sc];
      const short* al = &A8l[(size_t)(r0 + sr) * lda + kt + sc];
      rAh[0] = *(const short8*)ah; rAh[1] = *(const short8*)(ah + 8);
      rAl[0] = *(const short8*)al; rAl[1] = *(const short8*)(al + 8);
    } else {
      float v[16];
      if (flags & 32) {
        int gr = r0 + sr;
        int i = gr >> 5; int j = gidx[gr];
        const float* pi = &A[(size_t)i * srcC + kt + sc];
        const float* pj = &src[(size_t)j * srcC + kt + sc];
        float va[16], vb[16];
        *(float4*)&va[0]  = *(const float4*)&pi[0];
        *(float4*)&va[4]  = *(const float4*)&pi[4];
        *(float4*)&va[8]  = *(const float4*)&pi[8];
        *(float4*)&va[12] = *(const float4*)&pi[12];
        *(float4*)&vb[0]  = *(const float4*)&pj[0];
        *(float4*)&vb[4]  = *(const float4*)&pj[4];
        *(float4*)&vb[8]  = *(const float4*)&pj[8];
        *(float4*)&vb[12] = *(const float4*)&pj[12];
#pragma unroll
        for (int e = 0; e < 16; ++e) v[e] = fmaxf(va[e] + vb[e], 0.f);
      } else {
        const float* ap = &A[(size_t)(r0 + sr) * lda + kt + sc];
        *(float4*)&v[0]  = *(const float4*)&ap[0];
        *(float4*)&v[4]  = *(const float4*)&ap[4];
        *(float4*)&v[8]  = *(const float4*)&ap[8];
        *(float4*)&v[12] = *(const float4*)&ap[12];
      }
      if (bnA) {
#pragma unroll
        for (int e = 0; e < 16; ++e) {
          int gk = kt + sc + e;
          v[e] = fmaf(bnA[gk], v[e], bnA[1024 + gk]);
        }
      }
#pragma unroll
      for (int e = 0; e < 16; ++e) {
        unsigned short h = f2bf(v[e]);
        rAh[e >> 3][e & 7] = (short)h;
        rAl[e >> 3][e & 7] = (short)f2bf(v[e] - bf2f(h));
      }
    }
  };

  stage(0);
  for (int kt = 0; kt < K; kt += 64) {
    *(short8*)&Ah[sr][sc]     = rAh[0];
    *(short8*)&Ah[sr][sc + 8] = rAh[1];
    *(short8*)&Al[sr][sc]     = rAl[0];
    *(short8*)&Al[sr][sc + 8] = rAl[1];
    *(short8*)&Bh[sr][sc]     = rBh[0];
    *(short8*)&Bh[sr][sc + 8] = rBh[1];
    *(short8*)&Bl[sr][sc]     = rBl[0];
    *(short8*)&Bl[sr][sc + 8] = rBl[1];
    __syncthreads();
    if (kt + 64 < K) stage(kt + 64);
    int ar = wr * 32 + (lane & 15);
    int br = wc * 32 + (lane & 15);
#pragma unroll
    for (int kk = 0; kk < 2; ++kk) {
      int kof = kk * 32 + (lane >> 4) * 8;
      short8 a_h[2], a_l[2], b_h[2], b_l[2];
#pragma unroll
      for (int t = 0; t < 2; ++t) {
        a_h[t] = *(const short8*)&Ah[ar + t * 16][kof];
        a_l[t] = *(const short8*)&Al[ar + t * 16][kof];
        b_h[t] = *(const short8*)&Bh[br + t * 16][kof];
        b_l[t] = *(const short8*)&Bl[br + t * 16][kof];
      }
#pragma unroll
      for (int mt = 0; mt < 2; ++mt)
#pragma unroll
        for (int nt = 0; nt < 2; ++nt) {
          acc[mt][nt] = __builtin_amdgcn_mfma_f32_16x16x32_bf16(a_h[mt], b_h[nt], acc[mt][nt], 0, 0, 0);
          acc[mt][nt] = __builtin_amdgcn_mfma_f32_16x16x32_bf16(a_h[mt], b_l[nt], acc[mt][nt], 0, 0, 0);
          acc[mt][nt] = __builtin_amdgcn_mfma_f32_16x16x32_bf16(a_l[mt], b_h[nt], acc[mt][nt], 0, 0, 0);
        }
    }
    __syncthreads();
  }
  bool dostat = (flags & 8) != 0, domx = (flags & 16) != 0;
  float lsum[2] = {0.f, 0.f}, lsq[2] = {0.f, 0.f};
  float lmx[2] = {-3.4e38f, -3.4e38f}, lmn[2] = {3.4e38f, 3.4e38f};
#pragma unroll
  for (int nt = 0; nt < 2; ++nt) {
    int gc = n0 + wc * 32 + nt * 16 + (lane & 15);
#pragma unroll
    for (int mt = 0; mt < 2; ++mt)
#pragma unroll
      for (int i = 0; i < 4; ++i) {
        int gr = r0 + wr * 32 + mt * 16 + (lane >> 4) * 4 + i;
        float v = acc[mt][nt][i];
        if (bias) v += bias[gc];
        if (flags & 1) v += C[(size_t)gr * ldc + gc];
        if (flags & 2) v = fmaxf(v, 0.f);
        if (!domx) {
          if (flags & 64) {
            unsigned short hh = f2bf(v);
            Ch[(size_t)gr * ldc + gc] = (short)hh;
            Cl[(size_t)gr * ldc + gc] = (short)f2bf(v - bf2f(hh));
          } else {
            C[(size_t)gr * ldc + gc] = v;
          }
        }
        lsum[nt] += v; lsq[nt] = fmaf(v, v, lsq[nt]);
        lmx[nt] = fmaxf(lmx[nt], v); lmn[nt] = fminf(lmn[nt], v);
      }
  }
  if (dostat || domx) {
#pragma unroll
    for (int nt = 0; nt < 2; ++nt) {
#pragma unroll
      for (int m = 16; m <= 32; m <<= 1) {
        lsum[nt] += __shfl_xor(lsum[nt], m, 64);
        lsq[nt] += __shfl_xor(lsq[nt], m, 64);
        lmx[nt] = fmaxf(lmx[nt], __shfl_xor(lmx[nt], m, 64));
        lmn[nt] = fminf(lmn[nt], __shfl_xor(lmn[nt], m, 64));
      }
    }
    if (domx && lane < 16) {
      int node = blockIdx.x * 2 + wr;
#pragma unroll
      for (int nt = 0; nt < 2; ++nt) {
        int gc = n0 + wc * 32 + nt * 16 + lane;
        mxp[(size_t)node * N + gc] = lmx[nt];
        mnp[(size_t)node * N + gc] = lmn[nt];
      }
    }
    if (dostat) {
      if (tid < 64) { ssum[tid] = 0.f; ssq[tid] = 0.f; }
      __syncthreads();
      if (lane < 16) {
#pragma unroll
        for (int nt = 0; nt < 2; ++nt) {
          int ct = wc * 32 + nt * 16 + lane;
          atomicAdd(&ssum[ct], lsum[nt]);
          atomicAdd(&ssq[ct], lsq[nt]);
        }
      }
      __syncthreads();
      if (tid < 64) {
        int slot = blockIdx.x & 63;
        int gc = n0 + tid;
        atomicAdd(&statsP[(size_t)slot * 1024 + gc], ssum[tid]);
        atomicAdd(&statsP[(size_t)slot * 1024 + 512 + gc], ssq[tid]);
      }
    }
  }
}

// ---------------- dedicated kNN-2 key kernel: 64 rows x 512 cols per block ----
// x1h/x1l are FULL-table pointers; c0 selects the column chunk (B rows are
// global node indices n0+sr). Bit-identical keys to the R21 version (same
// per-64x64-tile staging, MFMA order, and ordf math; NTILE 4->8 only).
__global__ __launch_bounds__(256)
void mk_keyS(const short* __restrict__ x1h, const short* __restrict__ x1l,
             const float* __restrict__ sq, unsigned* __restrict__ Kb, int c0) {
  __shared__ short Ah[64][BPAD], Al[64][BPAD], Bh[64][BPAD], Bl[64][BPAD];
  int tid = threadIdx.x, lane = tid & 63, wid = tid >> 6;
  int wr = wid >> 1, wc = wid & 1;
  int r0 = blockIdx.x * 64;
  int nb = c0 + blockIdx.y * 512;
  int sr = tid >> 2, sc = (tid & 3) * 16;
  {
    const short* ah = &x1h[(size_t)(r0 + sr) * 64 + sc];
    const short* al = &x1l[(size_t)(r0 + sr) * 64 + sc];
    *(short8*)&Ah[sr][sc]     = *(const short8*)ah;
    *(short8*)&Ah[sr][sc + 8] = *(const short8*)(ah + 8);
    *(short8*)&Al[sr][sc]     = *(const short8*)al;
    *(short8*)&Al[sr][sc + 8] = *(const short8*)(al + 8);
  }
  __syncthreads();
  short8 a_h[2][2], a_l[2][2];
  int ar = wr * 32 + (lane & 15);
#pragma unroll
  for (int kk = 0; kk < 2; ++kk) {
    int kof = kk * 32 + (lane >> 4) * 8;
#pragma unroll
    for (int mt = 0; mt < 2; ++mt) {
      a_h[mt][kk] = *(const short8*)&Ah[ar + mt * 16][kof];
      a_l[mt][kk] = *(const short8*)&Al[ar + mt * 16][kof];
    }
  }
  float sqr[2][4];
#pragma unroll
  for (int mt = 0; mt < 2; ++mt)
#pragma unroll
    for (int i = 0; i < 4; ++i)
      sqr[mt][i] = sq[r0 + wr * 32 + mt * 16 + (lane >> 4) * 4 + i];

  f32x4 zero4 = {0.f, 0.f, 0.f, 0.f};
  for (int t = 0; t < 8; ++t) {
    int n0 = nb + t * 64;
    __syncthreads();
    {
      const short* bh2 = &x1h[(size_t)(n0 + sr) * 64 + sc];
      const short* bl2 = &x1l[(size_t)(n0 + sr) * 64 + sc];
      *(short8*)&Bh[sr][sc]     = *(const short8*)bh2;
      *(short8*)&Bh[sr][sc + 8] = *(const short8*)(bh2 + 8);
      *(short8*)&Bl[sr][sc]     = *(const short8*)bl2;
      *(short8*)&Bl[sr][sc + 8] = *(const short8*)(bl2 + 8);
    }
    __syncthreads();
    f32x4 acc[2][2] = {{zero4, zero4}, {zero4, zero4}};
    int br = wc * 32 + (lane & 15);
#pragma unroll
    for (int kk = 0; kk < 2; ++kk) {
      int kof = kk * 32 + (lane >> 4) * 8;
      short8 b_h[2], b_l[2];
#pragma unroll
      for (int nt = 0; nt < 2; ++nt) {
        b_h[nt] = *(const short8*)&Bh[br + nt * 16][kof];
        b_l[nt] = *(const short8*)&Bl[br + nt * 16][kof];
      }
#pragma unroll
      for (int mt = 0; mt < 2; ++mt)
#pragma unroll
        for (int nt = 0; nt < 2; ++nt) {
          acc[mt][nt] = __builtin_amdgcn_mfma_f32_16x16x32_bf16(a_h[mt][kk], b_h[nt], acc[mt][nt], 0, 0, 0);
          acc[mt][nt] = __builtin_amdgcn_mfma_f32_16x16x32_bf16(a_h[mt][kk], b_l[nt], acc[mt][nt], 0, 0, 0);
          acc[mt][nt] = __builtin_amdgcn_mfma_f32_16x16x32_bf16(a_l[mt][kk], b_h[nt], acc[mt][nt], 0, 0, 0);
        }
    }
#pragma unroll
    for (int nt = 0; nt < 2; ++nt) {
      int gc = n0 + wc * 32 + nt * 16 + (lane & 15);
      float sqc = sq[gc];
#pragma unroll
      for (int mt = 0; mt < 2; ++mt)
#pragma unroll
        for (int i = 0; i < 4; ++i) {
          int gr = r0 + wr * 32 + mt * 16 + (lane >> 4) * 4 + i;
          float v = acc[mt][nt][i];
          unsigned kk2 = (gr == gc) ? 0xFFFFFFFFu
                                    : ordf(sqr[mt][i] + sqc - 2.f * v);
          Kb[(size_t)gr * 4096 + (gc - c0)] = kk2;
        }
    }
  }
}

// ---------------- weight conversion ----------------
__global__ void mk_wcvt(const float* __restrict__ W, short* __restrict__ Wh,
                        short* __restrict__ Wl, int K, int N) {
  int g = blockIdx.x * 256 + threadIdx.x;
  if (g >= K * N) return;
  int k = g / N, n = g - k * N;
  float v = W[g];
  unsigned short h = f2bf(v);
  Wh[(size_t)n * K + k] = (short)h;
  Wl[(size_t)n * K + k] = (short)f2bf(v - bf2f(h));
}
__global__ void mk_wcvts(const float* __restrict__ W, const float* __restrict__ a,
                         short* __restrict__ Wh, short* __restrict__ Wl, int K, int N) {
  int g = blockIdx.x * 256 + threadIdx.x;
  if (g >= K * N) return;
  int k = g / N, n = g - k * N;
  float v = a[k] * W[g];
  unsigned short h = f2bf(v);
  Wh[(size_t)n * K + k] = (short)h;
  Wl[(size_t)n * K + k] = (short)f2bf(v - bf2f(h));
}
__global__ void mk_biasfold(const float* __restrict__ W, const float* __restrict__ bv,
                            const float* __restrict__ b0, float* __restrict__ bo,
                            int K, int N) {
  int col = blockIdx.x * 4 + (threadIdx.x >> 6);
  int lane = threadIdx.x & 63;
  if (col >= N) return;
  float s = 0.f;
  for (int k = lane; k < K; k += 64) s = fmaf(bv[k], W[(size_t)k * N + col], s);
#pragma unroll
  for (int off = 32; off; off >>= 1) s += __shfl_xor(s, off, 64);
  if (lane == 0) bo[col] = b0[col] + s;
}
// mlp2 weights -> concatenated [D | V] n-major, 256 cols x 64 k
__global__ void mk_wcvt2(const float* __restrict__ W, short* __restrict__ DVh,
                         short* __restrict__ DVl) {
  int g = blockIdx.x * 256 + threadIdx.x;
  if (g >= 64 * 128) return;
  int k = g >> 7, n = g & 127;
  float u = W[k * 128 + n], vv = W[(64 + k) * 128 + n];
  float d = u - vv;
  unsigned short h = f2bf(d);
  DVh[n * 64 + k] = (short)h; DVl[n * 64 + k] = (short)f2bf(d - bf2f(h));
  h = f2bf(vv);
  DVh[(128 + n) * 64 + k] = (short)h; DVl[(128 + n) * 64 + k] = (short)f2bf(vv - bf2f(h));
}

// ---------------- conv1 node tables ----------------
__global__ void mk_conv1nodes(const float* __restrict__ pos, const float* __restrict__ W1,
                              const float* __restrict__ b1, float* __restrict__ Pp,
                              float* __restrict__ Qn) {
  int g = blockIdx.x * 256 + threadIdx.x;
  if (g >= 8192 * 64) return;
  int i = g >> 6, c = g & 63;
  float p0 = pos[i * 3], p1 = pos[i * 3 + 1], p2 = pos[i * 3 + 2];
  float q = p0 * W1[192 + c] + p1 * W1[256 + c] + p2 * W1[320 + c];
  Qn[g] = q;
  Pp[g] = p0 * W1[c] + p1 * W1[64 + c] + p2 * W1[128 + c] - q + b1[c];
}

__global__ __launch_bounds__(256)
void mk_stats1(const float* __restrict__ Pp, const float* __restrict__ Qn,
               const int* __restrict__ idx1, float* __restrict__ statsP) {
  __shared__ int sidx[512];
  int tid = threadIdx.x;
  int c = tid & 63, grp = tid >> 6;
  int nb = blockIdx.x * 16;
  if (tid < 256) {
    sidx[tid] = idx1[nb * 32 + tid];
    sidx[tid + 256] = idx1[nb * 32 + 256 + tid];
  }
  __syncthreads();
  float s = 0.f, q = 0.f;
  for (int ln = 0; ln < 16; ++ln) {
    float pv = Pp[(size_t)(nb + ln) * 64 + c];
    for (int e = grp; e < 32; e += 4) {
      int j = sidx[ln * 32 + e];
      float v = fmaxf(pv + Qn[(size_t)j * 64 + c], 0.f);
      s += v; q = fmaf(v, v, q);
    }
  }
  int slot = (blockIdx.x * 4 + grp) & 63;
  atomicAdd(&statsP[(size_t)slot * 1024 + c], s);
  atomicAdd(&statsP[(size_t)slot * 1024 + 512 + c], q);
}

// econv2 over merged RT buffer [8192][256]: D at +0 (bias b2 added here), V at +128
__global__ __launch_bounds__(128)
void mk_econv2(const float* __restrict__ RT, const float* __restrict__ b2,
               const int* __restrict__ st_i, float* __restrict__ mxp,
               float* __restrict__ mnp, float* __restrict__ statsP) {
  __shared__ int sidx[256];
  int tid = threadIdx.x;
  int nb = blockIdx.x * 8;
  sidx[tid] = st_i[nb * 32 + tid];
  sidx[tid + 128] = st_i[nb * 32 + 128 + tid];
  __syncthreads();
  float bb = b2[tid];
  float s = 0.f, q = 0.f;
  for (int ln = 0; ln < 8; ++ln) {
    int i = nb + ln;
    float rv = RT[(size_t)i * 256 + tid] + bb;
    float mx = -3.4e38f, mn = 3.4e38f;
    for (int e = 0; e < 32; ++e) {
      int j = sidx[ln * 32 + e];
      float v = fmaxf(rv + RT[(size_t)j * 256 + 128 + tid], 0.f);
      mx = fmaxf(mx, v); mn = fminf(mn, v);
      s += v; q = fmaf(v, v, q);
    }
    mxp[(size_t)i * 128 + tid] = mx;
    mnp[(size_t)i * 128 + tid] = mn;
  }
  int slot = blockIdx.x & 63;
  atomicAdd(&statsP[(size_t)slot * 1024 + tid], s);
  atomicAdd(&statsP[(size_t)slot * 1024 + 512 + tid], q);
}

// slot stats (sum @ +0, sq @ +512 per 1024-slot) -> coef (a @ +0, b @ +1024)
__global__ void mk_bnfinS(const float* __restrict__ sb, const float* __restrict__ g,
                          const float* __restrict__ beta, float* __restrict__ bno,
                          float Minv, int Cdim) {
  int c = blockIdx.x * 256 + threadIdx.x;
  if (c >= Cdim) return;
  float s = 0.f, q = 0.f;
  for (int sl = 0; sl < 64; ++sl) {
    s += sb[(size_t)sl * 1024 + c];
    q += sb[(size_t)sl * 1024 + 512 + c];
  }
  float mu = s * Minv;
  float var = q * Minv - mu * mu;
  float a = g[c] * rsqrtf(var + BN_EPS);
  bno[c] = a;
  bno[1024 + c] = beta[c] - a * mu;
}

__global__ void mk_finx1(const float* __restrict__ mx, const float* __restrict__ mn,
                         const float* __restrict__ bn, float* __restrict__ xc,
                         short* __restrict__ x1h, short* __restrict__ x1l) {
  int g = blockIdx.x * 256 + threadIdx.x;
  if (g >= 8192 * 64) return;
  int i = g >> 6, c = g & 63;
  float a = bn[c], b = bn[1024 + c];
  float v = (a > 0.f) ? fmaf(a, mx[g], b) : fmaf(a, mn[g], b);
  xc[(size_t)i * 192 + c] = v;
  unsigned short h = f2bf(v);
  x1h[g] = (short)h;
  x1l[g] = (short)f2bf(v - bf2f(h));
}
__global__ void mk_finx2(const float* __restrict__ mx, const float* __restrict__ mn,
                         const float* __restrict__ bn, float* __restrict__ xcB) {
  int g = blockIdx.x * 256 + threadIdx.x;
  if (g >= 8192 * 128) return;
  int i = g >> 7, c = g & 127;
  float a = bn[c], b = bn[1024 + c];
  xcB[(size_t)i * 192 + c] = (a > 0.f) ? fmaf(a, mx[g], b) : fmaf(a, mn[g], b);
}

// ---------------- kNN: chunk-min threshold select (exact) ----------------
__global__ void mk_posq(const float* __restrict__ pos, float4* __restrict__ posq) {
  int i = blockIdx.x * 256 + threadIdx.x;
  if (i >= 8192) return;
  float x = pos[i * 3], y = pos[i * 3 + 1], z = pos[i * 3 + 2];
  float s = fmaf(z, z, fmaf(y, y, x * x));
  posq[i] = make_float4(x, y, z, s);
}

// per-wave 8th-smallest of 64 lane values via ballot binary search (constant k=8)
__device__ __forceinline__ unsigned wave_kth8(unsigned v) {
  unsigned T = 0;
#pragma unroll
  for (int b = 31; b >= 0; --b) {
    unsigned cand = T | (1u << b);
    int c = __popcll(__ballot(v < cand));
    if (c < 8) T = cand;
  }
  return T;
}

__global__ __launch_bounds__(256)
void mk_knn1(const float4* __restrict__ posq, int* __restrict__ idxout) {
  __shared__ ull buf[K1CAP];
  __shared__ unsigned Tw[4];
  __shared__ unsigned cnt;
  int q = blockIdx.x, tid = threadIdx.x;
  int lane = tid & 63, wid = tid >> 6;
  float4 pq = posq[q];
  if (tid == 0) cnt = 0;
  unsigned key[32];
  unsigned vmin = 0xFFFFFFFFu;
#pragma unroll
  for (int c = 0; c < 32; ++c) {
    int j = c * 256 + tid;
    float4 pj = posq[j];
    float d = pq.w + pj.w - 2.f * (pq.x * pj.x + pq.y * pj.y + pq.z * pj.z);
    unsigned k = (j == q) ? 0xFFFFFFFFu : ordf(d);
    key[c] = k;
    vmin = vmin < k ? vmin : k;
  }
  unsigned T = wave_kth8(vmin);
  if (lane == 0) Tw[wid] = T;
  __syncthreads();
  unsigned Tmax = max(max(Tw[0], Tw[1]), max(Tw[2], Tw[3]));
#pragma unroll
  for (int c = 0; c < 32; ++c) {
    if (key[c] <= Tmax) {
      int j = c * 256 + tid;
      unsigned s = atomicAdd(&cnt, 1u);
      if (s < K1CAP) buf[s] = (((ull)key[c]) << 32) | (unsigned)j;
    }
  }
  __syncthreads();
  int m = cnt < (unsigned)K1CAP ? (int)cnt : K1CAP;
  for (int e = tid; e < m; e += 256) {
    ull mine = buf[e];
    int rank = 0;
    for (int f = 0; f < m; ++f) rank += (buf[f] < mine) ? 1 : 0;
    if (rank < 32) idxout[q * 32 + rank] = (int)(unsigned)(mine & 0xFFFFFFFFu);
  }
}

// knn2: reads precomputed u32 key matrix Kb[q][0..4095] (diag already ~0)
__global__ __launch_bounds__(256)
void mk_knn2(const unsigned* __restrict__ Kb, int c0, int first,
             unsigned* __restrict__ st_k, int* __restrict__ st_i) {
  __shared__ ull buf[K2CAP];
  __shared__ unsigned Tw[4];
  __shared__ unsigned cnt;
  int q = blockIdx.x, tid = threadIdx.x;
  int lane = tid & 63, wid = tid >> 6;
  if (tid == 0) cnt = 0;
  unsigned key[16];
  unsigned vmin = 0xFFFFFFFFu;
#pragma unroll
  for (int c = 0; c < 16; ++c) {
    unsigned k = Kb[(size_t)q * 4096 + c * 256 + tid];
    key[c] = k;
    vmin = vmin < k ? vmin : k;
  }
  unsigned T = wave_kth8(vmin);
  if (lane == 0) Tw[wid] = T;
  __syncthreads();
  unsigned Tmax = max(max(Tw[0], Tw[1]), max(Tw[2], Tw[3]));
#pragma unroll
  for (int c = 0; c < 16; ++c) {
    if (key[c] <= Tmax) {
      int j = c0 + c * 256 + tid;
      unsigned s = atomicAdd(&cnt, 1u);
      if (s < K2CAP) buf[s] = (((ull)key[c]) << 32) | (unsigned)j;
    }
  }
  if (!first && tid < 32) {
    ull k = (((ull)st_k[q * 32 + tid]) << 32) | (unsigned)st_i[q * 32 + tid];
    unsigned s = atomicAdd(&cnt, 1u);
    if (s < K2CAP) buf[s] = k;
  }
  __syncthreads();
  int m = cnt < (unsigned)K2CAP ? (int)cnt : K2CAP;
  for (int e = tid; e < m; e += 256) {
    ull mine = buf[e];
    int rank = 0;
    for (int f = 0; f < m; ++f) rank += (buf[f] < mine) ? 1 : 0;
    if (rank < 32) {
      st_k[q * 32 + rank] = (unsigned)(mine >> 32);
      st_i[q * 32 + rank] = (int)(unsigned)(mine & 0xFFFFFFFFu);
    }
  }
}

// ---------------- fp32 GEMM (tag1, K=16) ----------------
#define GBM 64
#define GBN 64
#define GBK 16

__global__ __launch_bounds__(256)
void mk_gemm(const float* __restrict__ A, const float* __restrict__ W, int ldw,
             const float* __restrict__ bias, float* __restrict__ C, int ldc,
             int M, int N, int K, int flags) {
  __shared__ float As[GBK][GBM + 4];
  __shared__ float Ws[GBK][GBN];
  int tid = threadIdx.x;
  int r0 = blockIdx.x * GBM, n0 = blockIdx.y * GBN;
  int ty = tid >> 4, tx = tid & 15;
  float acc[4][4] = {};
  for (int kt = 0; kt < K; kt += GBK) {
#pragma unroll
    for (int it = 0; it < 4; ++it) {
      int l = it * 256 + tid;
      int r = l >> 4, kk = l & 15;
      int gr = r0 + r, gk = kt + kk;
      float v = 0.f;
      if (gk < K && gr < M) v = A[(size_t)gr * K + gk];
      As[kk][r] = v;
      int kw = l >> 6, nw = l & 63;
      int gkw = kt + kw;
      Ws[kw][nw] = (gkw < K && (n0 + nw) < N) ? W[(size_t)gkw * ldw + n0 + nw] : 0.f;
    }
    __syncthreads();
#pragma unroll
    for (int kk = 0; kk < GBK; ++kk) {
      float4 a4 = *(const float4*)&As[kk][ty * 4];
      float4 b4 = *(const float4*)&Ws[kk][tx * 4];
      float av[4] = {a4.x, a4.y, a4.z, a4.w};
      float bv[4] = {b4.x, b4.y, b4.z, b4.w};
#pragma unroll
      for (int i = 0; i < 4; ++i)
#pragma unroll
        for (int j = 0; j < 4; ++j)
          acc[i][j] = fmaf(av[i], bv[j], acc[i][j]);
    }
    __syncthreads();
  }
#pragma unroll
  for (int i = 0; i < 4; ++i) {
    int gr = r0 + ty * 4 + i;
    if (gr >= M) continue;
#pragma unroll
    for (int j = 0; j < 4; ++j) {
      int gc = n0 + tx * 4 + j;
      if (gc >= N) continue;
      float v = acc[i][j];
      if (bias) v += bias[gc];
      if (flags & 1) v += C[(size_t)gr * ldc + gc];
      if (flags & 2) v = fmaxf(v, 0.f);
      C[(size_t)gr * ldc + gc] = v;
    }
  }
}

// ---------------- small utility kernels ----------------
__global__ void mk_sqnorm(const float* __restrict__ x, int ld, float* __restrict__ sq,
                          int Npts, int Cdim) {
  int i = blockIdx.x * blockDim.x + threadIdx.x;
  if (i >= Npts) return;
  float s = 0.f;
  for (int c = 0; c < Cdim; ++c) { float v = x[(size_t)i * ld + c]; s = fmaf(v, v, s); }
  sq[i] = s;
}

// ---------------- CSR build + props ----------------
__global__ void mk_count(const int* __restrict__ col, int* __restrict__ cnt, int E) {
  int e = blockIdx.x * 256 + threadIdx.x;
  if (e < E) atomicAdd(&cnt[col[e]], 1);
}
__global__ __launch_bounds__(1024)
void mk_scan(const int* __restrict__ cnt, int* __restrict__ offp,
             int* __restrict__ cur, float* __restrict__ dinvf) {
  __shared__ int wsum[16];
  __shared__ int wexc[16];
  int t = threadIdx.x, lane = t & 63, w = t >> 6;
  int v[8]; int s = 0;
  int base = t * 8;
#pragma unroll
  for (int k = 0; k < 8; ++k) { v[k] = s; s += cnt[base + k]; }
  int sc = s;
#pragma unroll
  for (int off2 = 1; off2 < 64; off2 <<= 1) {
    int n = __shfl_up(sc, off2, 64);
    if (lane >= off2) sc += n;
  }
  if (lane == 63) wsum[w] = sc;
  __syncthreads();
  if (w == 0) {
    int x = (lane < 16) ? wsum[lane] : 0;
    int scx = x;
#pragma unroll
    for (int off2 = 1; off2 < 16; off2 <<= 1) {
      int n = __shfl_up(scx, off2, 64);
      if (lane >= off2) scx += n;
    }
    if (lane < 16) wexc[lane] = scx - x;
  }
  __syncthreads();
  int texc = wexc[w] + (sc - s);
#pragma unroll
  for (int k = 0; k < 8; ++k) {
    int o = texc + v[k];
    offp[base + k] = o;
    cur[base + k] = o;
    int d = cnt[base + k];
    dinvf[base + k] = (d > 0) ? rsqrtf((float)(d < 1 ? 1 : d)) : 0.f;
  }
  if (t == 1023) offp[8192] = texc + s;
}
__global__ void mk_fill(const int* __restrict__ row, const int* __restrict__ col,
                        const float* __restrict__ dinvf, int* __restrict__ cur,
                        int* __restrict__ crow, float* __restrict__ cw, int E) {
  int e = blockIdx.x * 256 + threadIdx.x;
  if (e >= E) return;
  int c = col[e], r = row[e];
  int s = atomicAdd(&cur[c], 1);
  crow[s] = r;
  cw[s] = dinvf[r] * dinvf[c];
}
__global__ void mk_prop64(const float* __restrict__ in, int in_ld,
                          const int* __restrict__ offp, const int* __restrict__ crow,
                          const float* __restrict__ cw, float* __restrict__ out, int out_ld) {
  int gid = blockIdx.x * 256 + threadIdx.x;
  if (gid >= 8192 * 16) return;
  int col = gid >> 4, c4 = (gid & 15) * 4;
  int s0 = offp[col], s1 = offp[col + 1];
  float a0 = 0, a1 = 0, a2 = 0, a3 = 0;
  for (int s = s0; s < s1; ++s) {
    int r = crow[s]; float w = cw[s];
    float4 v = *(const float4*)&in[(size_t)r * in_ld + c4];
    a0 = fmaf(w, v.x, a0); a1 = fmaf(w, v.y, a1);
    a2 = fmaf(w, v.z, a2); a3 = fmaf(w, v.w, a3);
  }
  float4 o = {a0, a1, a2, a3};
  *(float4*)&out[(size_t)col * out_ld + c4] = o;
}
__global__ void mk_prop4(const float* __restrict__ in, int in_ld,
                         const int* __restrict__ offp, const int* __restrict__ crow,
                         const float* __restrict__ cw, float* __restrict__ out, int out_ld) {
  int col = blockIdx.x * 256 + threadIdx.x;
  if (col >= 8192) return;
  int s0 = offp[col], s1 = offp[col + 1];
  float a0 = 0, a1 = 0, a2 = 0, a3 = 0;
  for (int s = s0; s < s1; ++s) {
    int r = crow[s]; float w = cw[s];
    float4 v = *(const float4*)&in[(size_t)r * in_ld];
    a0 = fmaf(w, v.x, a0); a1 = fmaf(w, v.y, a1);
    a2 = fmaf(w, v.z, a2); a3 = fmaf(w, v.w, a3);
  }
  float4 o = {a0, a1, a2, a3};
  *(float4*)&out[(size_t)col * out_ld] = o;
}
__global__ void mk_pack4(const float* __restrict__ xin, float* __restrict__ H1) {
  int g = blockIdx.x * 256 + threadIdx.x;
  if (g >= 8192 * 4) return;
  H1[(size_t)(g >> 2) * 16 + (g & 3)] = xin[g];
}
__global__ void mk_copy64(const float* __restrict__ gcv, float* __restrict__ H2) {
  int g = blockIdx.x * 256 + threadIdx.x;
  if (g >= 8192 * 64) return;
  H2[(size_t)(g >> 6) * 256 + (g & 63)] = gcv[(size_t)(g >> 6) * 192 + (g & 63)];
}

__global__ __launch_bounds__(256)
void mk_gemv_out(const float* __restrict__ h, const float* __restrict__ bn,
                 const float* __restrict__ w, const float* __restrict__ b,
                 float* __restrict__ out, int Npts) {
  int row = blockIdx.x * 4 + (threadIdx.x >> 6);
  int lane = threadIdx.x & 63;
  if (row >= Npts) return;
  int c = lane * 4;
  float4 v = *(const float4*)&h[(size_t)row * 256 + c];
  float s = (bn[c] * v.x + bn[1024 + c]) * w[c]
          + (bn[c + 1] * v.y + bn[1024 + c + 1]) * w[c + 1]
          + (bn[c + 2] * v.z + bn[1024 + c + 2]) * w[c + 2]
          + (bn[c + 3] * v.w + bn[1024 + c + 3]) * w[c + 3];
#pragma unroll
  for (int off = 32; off; off >>= 1) s += __shfl_xor(s, off, 64);
  if (lane == 0) out[row] = s + b[0];
}

// ---------------- host ----------------
extern "C" void kernel_launch(void* const* d_in, const int* in_sizes, int n_in,
                              void* d_out, int out_size, void* d_ws, size_t ws_size,
                              hipStream_t stream) {
  const int N = 8192;
  const int NE = N * 32;
  const float* pos = (const float*)d_in[0];
  const float* xin = (const float*)d_in[1];
  const int* ei = (const int*)d_in[2];
  const int E = in_sizes[2] / 2;
  const int* erow = ei;
  const int* ecol = ei + E;
  const float* mlp1_W1  = (const float*)d_in[3];
  const float* mlp1_W23 = (const float*)d_in[4];
  const float* mlp1_b   = (const float*)d_in[5];
  const float* mlp1_g   = (const float*)d_in[6];
  const float* mlp1_be  = (const float*)d_in[7];
  const float* mlp2_W   = (const float*)d_in[8];
  const float* mlp2_b   = (const float*)d_in[9];
  const float* mlp2_g   = (const float*)d_in[10];
  const float* mlp2_be  = (const float*)d_in[11];
  const float* lin1_W   = (const float*)d_in[12];
  const float* lin1_b   = (const float*)d_in[13];
  const float* lin1_g   = (const float*)d_in[14];
  const float* lin1_be  = (const float*)d_in[15];
  const float* tag1_W   = (const float*)d_in[16];
  const float* tag1_b   = (const float*)d_in[17];
  const float* tag2_W   = (const float*)d_in[18];
  const float* tag2_b   = (const float*)d_in[19];
  const float* lin2_W   = (const float*)d_in[20];
  const float* lin2_b   = (const float*)d_in[21];
  const float* lin2_g   = (const float*)d_in[22];
  const float* lin2_be  = (const float*)d_in[23];
  const float* mix1_W   = (const float*)d_in[24];
  const float* mix1_b   = (const float*)d_in[25];
  const float* mix1_g   = (const float*)d_in[26];
  const float* mix1_be  = (const float*)d_in[27];
  const float* mix2_W   = (const float*)d_in[28];
  const float* mix2_b   = (const float*)d_in[29];
  const float* mix2_g   = (const float*)d_in[30];
  const float* mix2_be  = (const float*)d_in[31];
  const float* outW     = (const float*)d_in[32];
  const float* outB     = (const float*)d_in[33];

  char* base = (char*)d_ws;
  size_t off = 0;
  auto alloc = [&](size_t b) -> void* {
    void* p = base + off;
    off += (b + 255) & ~(size_t)255;
    return p;
  };
  float* BIG = (float*)alloc(134217728ull);   // 128 MB phase-shared
  short* h2_h  = (short*)BIG;                            // conv1 L2 out hi (32 MB)
  short* h2_l  = (short*)((char*)BIG + 33554432);        // lo (32 MB)
  unsigned* Kb = (unsigned*)BIG;                         // knn2 key matrix [8192][4096] (128 MB)
  short* mhcat_h = (short*)BIG;                          // [8192][1024] hi (16 MB)
  short* mhcat_l = (short*)((char*)BIG + 16777216);      // lo (16 MB)
  short* mh1_h   = (short*)((char*)BIG + 33554432);      // [8192][512] hi (8 MB)
  short* mh1_l   = (short*)((char*)BIG + 41943040);      // lo (8 MB)
  float* mh2     = (float*)((char*)BIG + 50331648);      // [8192][256] fp32 (8 MB)
  float* H2      = BIG + 16777216;                       // byte 64M+: tag2 hop-concat
  int*   idx1 = (int*)alloc((size_t)NE * 4);
  unsigned* st_k = (unsigned*)alloc((size_t)NE * 4);
  int*   st_i = (int*)alloc((size_t)NE * 4);
  float* xc  = (float*)alloc((size_t)N * 192 * 4);   // [x1 | x2]
  float* gc  = (float*)alloc((size_t)N * 192 * 4);   // [g1 | g2]
  float4* posq = (float4*)alloc((size_t)N * 16);
  float* sqx = (float*)alloc((size_t)N * 4);
  float* Pp  = (float*)alloc((size_t)N * 64 * 4);
  float* Qn  = (float*)alloc((size_t)N * 64 * 4);
  float* RT  = (float*)alloc((size_t)N * 256 * 4);   // conv2 merged [D|V]
  float* mx1 = (float*)alloc((size_t)N * 64 * 4);
  float* mn1 = (float*)alloc((size_t)N * 64 * 4);
  float* mx2 = (float*)alloc((size_t)N * 128 * 4);
  float* mn2 = (float*)alloc((size_t)N * 128 * 4);
  float* H1  = (float*)alloc((size_t)N * 16 * 4);
  float* dinvf = (float*)alloc((size_t)N * 4);
  int* cnt     = (int*)alloc((size_t)N * 4);
  int* csr_off = (int*)alloc((size_t)(N + 1) * 4);
  int* cursor  = (int*)alloc((size_t)N * 4);
  int* csr_row = (int*)alloc((size_t)E * 4);
  float* csr_w = (float*)alloc((size_t)E * 4);
  float* slotAll = (float*)alloc((size_t)8 * 64 * 1024 * 4);
  auto slot = [&](int i) { return slotAll + (size_t)i * 64 * 1024; };
  float* bnb = (float*)alloc(8 * 2048 * 4);           // coef: a @ +0, b @ +1024
  auto bnp = [&](int i) { return bnb + (size_t)i * 2048; };
  float* bnM = bnp(4);                                // lin1 a cols 0-511, lin2 at +512
  float* bias1f = (float*)alloc(512 * 4);
  float* bias2f = (float*)alloc(256 * 4);
  float* biasA  = (float*)alloc(64 * 4);
  float* biasB  = (float*)alloc(64 * 4);
  auto salloc = [&](size_t n) { return (short*)alloc(n * 2); };
  short* w23a_h = salloc(4096);   short* w23a_l = salloc(4096);
  short* w23b_h = salloc(4096);   short* w23b_l = salloc(4096);
  short* wdv_h  = salloc(16384);  short* wdv_l  = salloc(16384);
  short* wl1_h  = salloc(98304);  short* wl1_l  = salloc(98304);
  short* wt2_h  = salloc(32768);  short* wt2_l  = salloc(32768);
  short* wl2_h  = salloc(98304);  short* wl2_l  = salloc(98304);
  short* wx1_h  = salloc(524288); short* wx1_l  = salloc(524288);
  short* wx2_h  = salloc(131072); short* wx2_l  = salloc(131072);
  short* x1h    = salloc(524288); short* x1l    = salloc(524288);

  auto gemmF = [&](const float* A, const short* A8h, const short* A8l,
                   const float* src, const int* gidx, int srcC, const float* bnA,
                   const short* Wh_, const short* Wl_, int ldk, int koff, int lda,
                   const float* bias, float* Cp, short* Chp, short* Clp, int ldc,
                   int M, int Nn, int Kk, int flags,
                   float* stP = nullptr, float* mxP = nullptr, float* mnP = nullptr) {
    dim3 g(M / 64, Nn / 64);
    mk_gemm_mfma<<<g, 256, 0, stream>>>(A, A8h, A8l, src, gidx, srcC, bnA,
                                        Wh_, Wl_, ldk, koff, lda, bias, Cp, Chp, Clp, ldc,
                                        M, Nn, Kk, flags, stP, mxP, mnP);
  };
  auto wcvt = [&](const float* W, short* Wh_, short* Wl_, int Kk, int Nn) {
    mk_wcvt<<<(Kk * Nn + 255) / 256, 256, 0, stream>>>(W, Wh_, Wl_, Kk, Nn);
  };

  // ---- init + weight conversion ----
  hipMemsetAsync(slotAll, 0, (size_t)8 * 64 * 1024 * 4, stream);
  hipMemsetAsync(cnt, 0, (size_t)N * 4, stream);
  mk_wcvt2<<<(64 * 128 + 255) / 256, 256, 0, stream>>>(mlp2_W, wdv_h, wdv_l);
  wcvt(lin1_W, wl1_h, wl1_l, 192, 512);
  wcvt(tag2_W, wt2_h, wt2_l, 256, 128);
  wcvt(lin2_W, wl2_h, wl2_l, 192, 512);

  // ---- kNN-1 on pos ----
  mk_posq<<<32, 256, 0, stream>>>(pos, posq);
  mk_knn1<<<N, 256, 0, stream>>>(posq, idx1);

  // ---- conv1 ----
  mk_conv1nodes<<<(N * 64 + 255) / 256, 256, 0, stream>>>(pos, mlp1_W1, mlp1_b, Pp, Qn);
  mk_stats1<<<512, 256, 0, stream>>>(Pp, Qn, idx1, slot(0));
  mk_bnfinS<<<1, 256, 0, stream>>>(slot(0), mlp1_g, mlp1_be, bnp(0), 1.f / NE, 64);
  mk_wcvts<<<(64 * 64 + 255) / 256, 256, 0, stream>>>(mlp1_W23, bnp(0), w23a_h, w23a_l, 64, 64);
  mk_biasfold<<<16, 256, 0, stream>>>(mlp1_W23, bnp(0) + 1024, mlp1_b + 64, biasA, 64, 64);
  gemmF(Pp, nullptr, nullptr, Qn, idx1, 64, nullptr,
        w23a_h, w23a_l, 64, 0, 64, biasA, nullptr, h2_h, h2_l, 64,
        NE, 64, 64, 2 | 8 | 32 | 64, slot(1));
  mk_bnfinS<<<1, 256, 0, stream>>>(slot(1), mlp1_g + 64, mlp1_be + 64, bnp(1), 1.f / NE, 64);
  mk_wcvts<<<(64 * 64 + 255) / 256, 256, 0, stream>>>(mlp1_W23 + 4096, bnp(1), w23b_h, w23b_l, 64, 64);
  mk_biasfold<<<16, 256, 0, stream>>>(mlp1_W23 + 4096, bnp(1) + 1024, mlp1_b + 128, biasB, 64, 64);
  gemmF(nullptr, h2_h, h2_l, nullptr, nullptr, 0, nullptr,
        w23b_h, w23b_l, 64, 0, 64, biasB, nullptr, nullptr, nullptr, 64,
        NE, 64, 64, 2 | 8 | 16, slot(2), mx1, mn1);
  mk_bnfinS<<<1, 256, 0, stream>>>(slot(2), mlp1_g + 128, mlp1_be + 128, bnp(2), 1.f / NE, 64);
  mk_finx1<<<(N * 64 + 255) / 256, 256, 0, stream>>>(mx1, mn1, bnp(2), xc, x1h, x1l);

  // ---- kNN-2 on x1: 2 chunks of 4096, keys via dedicated NTILE-8 kernel ----
  mk_sqnorm<<<32, 256, 0, stream>>>(xc, 192, sqx, N, 64);
  for (int c = 0; c < 2; ++c) {
    mk_keyS<<<dim3(128, 8), 256, 0, stream>>>(x1h, x1l, sqx, Kb, c * 4096);
    mk_knn2<<<N, 256, 0, stream>>>(Kb, c * 4096, c == 0 ? 1 : 0, st_k, st_i);
  }

  // ---- conv2: single merged [D|V] GEMM (N=256), bias added in econv2 ----
  gemmF(nullptr, x1h, x1l, nullptr, nullptr, 0, nullptr,
        wdv_h, wdv_l, 64, 0, 64, nullptr, RT, nullptr, nullptr, 256, N, 256, 64, 0);
  mk_econv2<<<N / 8, 128, 0, stream>>>(RT, mlp2_b, st_i, mx2, mn2, slot(3));
  mk_bnfinS<<<1, 256, 0, stream>>>(slot(3), mlp2_g, mlp2_be, bnp(3), 1.f / NE, 128);
  mk_finx2<<<(N * 128 + 255) / 256, 256, 0, stream>>>(mx2, mn2, bnp(3), xc + 64);

  // ---- lin1: K=192 GEMM -> mhcat (bf16 hi/lo) cols 0-511 ----
  gemmF(xc, nullptr, nullptr, nullptr, nullptr, 0, nullptr,
        wl1_h, wl1_l, 192, 0, 192, lin1_b, nullptr, mhcat_h, mhcat_l, 1024,
        N, 512, 192, 2 | 8 | 64, slot(4));
  mk_bnfinS<<<2, 256, 0, stream>>>(slot(4), lin1_g, lin1_be, bnM, 1.f / N, 512);

  // ---- TAG branch: CSR ----
  mk_count<<<(E + 255) / 256, 256, 0, stream>>>(ecol, cnt, E);
  mk_scan<<<1, 1024, 0, stream>>>(cnt, csr_off, cursor, dinvf);
  mk_fill<<<(E + 255) / 256, 256, 0, stream>>>(erow, ecol, dinvf, cursor, csr_row, csr_w, E);
  // tag1 -> gc cols 0-63
  mk_pack4<<<(N * 4 + 255) / 256, 256, 0, stream>>>(xin, H1);
  mk_prop4<<<32, 256, 0, stream>>>(xin, 4, csr_off, csr_row, csr_w, H1 + 4, 16);
  mk_prop4<<<32, 256, 0, stream>>>(H1 + 4, 16, csr_off, csr_row, csr_w, H1 + 8, 16);
  mk_prop4<<<32, 256, 0, stream>>>(H1 + 8, 16, csr_off, csr_row, csr_w, H1 + 12, 16);
  mk_gemm<<<dim3(128, 1), 256, 0, stream>>>(H1, tag1_W, 64, tag1_b, gc, 192, N, 64, 16, 2);
  // tag2: hop-concat H2 -> one K=256 gemmF -> gc cols 64-191
  mk_copy64<<<(N * 64 + 255) / 256, 256, 0, stream>>>(gc, H2);
  mk_prop64<<<512, 256, 0, stream>>>(gc, 192, csr_off, csr_row, csr_w, H2 + 64, 256);
  mk_prop64<<<512, 256, 0, stream>>>(H2 + 64, 256, csr_off, csr_row, csr_w, H2 + 128, 256);
  mk_prop64<<<512, 256, 0, stream>>>(H2 + 128, 256, csr_off, csr_row, csr_w, H2 + 192, 256);
  gemmF(H2, nullptr, nullptr, nullptr, nullptr, 0, nullptr,
        wt2_h, wt2_l, 256, 0, 256, tag2_b, gc + 64, nullptr, nullptr, 192,
        N, 128, 256, 2);
  // lin2: K=192 GEMM -> mhcat (bf16 hi/lo) cols 512-1023
  gemmF(gc, nullptr, nullptr, nullptr, nullptr, 0, nullptr,
        wl2_h, wl2_l, 192, 0, 192, lin2_b, nullptr, mhcat_h + 512, mhcat_l + 512, 1024,
        N, 512, 192, 2 | 8 | 64, slot(5));
  mk_bnfinS<<<2, 256, 0, stream>>>(slot(5), lin2_g, lin2_be, bnM + 512, 1.f / N, 512);

  // ---- fold lin BN into mix1 weights; mix head on fast A8 path ----
  mk_wcvts<<<(1024 * 512 + 255) / 256, 256, 0, stream>>>(mix1_W, bnM, wx1_h, wx1_l, 1024, 512);
  mk_biasfold<<<128, 256, 0, stream>>>(mix1_W, bnM + 1024, mix1_b, bias1f, 1024, 512);
  gemmF(nullptr, mhcat_h, mhcat_l, nullptr, nullptr, 0, nullptr,
        wx1_h, wx1_l, 1024, 0, 1024, bias1f, nullptr, mh1_h, mh1_l, 512,
        N, 512, 1024, 2 | 8 | 64, slot(6));
  mk_bnfinS<<<2, 256, 0, stream>>>(slot(6), mix1_g, mix1_be, bnp(6), 1.f / N, 512);
  mk_wcvts<<<(512 * 256 + 255) / 256, 256, 0, stream>>>(mix2_W, bnp(6), wx2_h, wx2_l, 512, 256);
  mk_biasfold<<<64, 256, 0, stream>>>(mix2_W, bnp(6) + 1024, mix2_b, bias2f, 512, 256);
  gemmF(nullptr, mh1_h, mh1_l, nullptr, nullptr, 0, nullptr,
        wx2_h, wx2_l, 512, 0, 512, bias2f, mh2, nullptr, nullptr, 256,
        N, 256, 512, 2 | 8, slot(7));
  mk_bnfinS<<<1, 256, 0, stream>>>(slot(7), mix2_g, mix2_be, bnp(7), 1.f / N, 256);
  mk_gemv_out<<<N / 4, 256, 0, stream>>>(mh2, bnp(7), outW, outB, (float*)d_out, N);
}